// Round 5
// baseline (957.651 us; speedup 1.0000x reference)
//
#include <hip/hip_runtime.h>
#include <hip/hip_bf16.h>

typedef __bf16 bf16x8 __attribute__((ext_vector_type(8)));
typedef float f32x4 __attribute__((ext_vector_type(4)));
typedef unsigned short ushort4v __attribute__((ext_vector_type(4)));
typedef unsigned short ushort8v __attribute__((ext_vector_type(8)));

#define S_LEN 2048
#define DIM 1024
#define NH 16
#define NKV 8
#define HD 64
#define HID 2816

__device__ __forceinline__ unsigned short f2bf(float f) {
    union { float f; unsigned u; } v; v.f = f;
    unsigned r = v.u + 0x7fffu + ((v.u >> 16) & 1u);   // RNE
    return (unsigned short)(r >> 16);
}
__device__ __forceinline__ float bf2f(unsigned short u) {
    union { unsigned u; float f; } v; v.u = (unsigned)u << 16; return v.f;
}

__device__ __forceinline__ void gload16(const unsigned short* g, unsigned short* l) {
    __builtin_amdgcn_global_load_lds(
        (const __attribute__((address_space(1))) unsigned int*)g,
        (__attribute__((address_space(3))) unsigned int*)l,
        16, 0, 0);
}

union Frag { f32x4 f; bf16x8 h; };

__device__ __forceinline__ f32x4 lds_read_b128(unsigned addr) {
    f32x4 d;
    asm volatile("ds_read_b128 %0, %1" : "=v"(d) : "v"(addr));
    return d;
}

// ---------------- embedding gather ----------------
__global__ __launch_bounds__(256) void embed_kernel(const int* __restrict__ tokens,
                                                    const float* __restrict__ emb,
                                                    float* __restrict__ h) {
    int s = blockIdx.x;
    int t = tokens[s];
    float4 v = *(const float4*)&emb[(size_t)t * DIM + threadIdx.x * 4];
    *(float4*)&h[(size_t)s * DIM + threadIdx.x * 4] = v;
}

// ---------------- rmsnorm: f32 in -> bf16 out ----------------
__global__ __launch_bounds__(256) void rmsnorm_kernel(const float* __restrict__ x,
                                                      const float* __restrict__ w,
                                                      unsigned short* __restrict__ out) {
    __shared__ float sred[4];
    int s = blockIdx.x;
    int tid = threadIdx.x;
    float4 v = *(const float4*)&x[(size_t)s * DIM + tid * 4];
    float ss = v.x * v.x + v.y * v.y + v.z * v.z + v.w * v.w;
#pragma unroll
    for (int off = 32; off; off >>= 1) ss += __shfl_down(ss, off);
    if ((tid & 63) == 0) sred[tid >> 6] = ss;
    __syncthreads();
    float tot = sred[0] + sred[1] + sred[2] + sred[3];
    float scale = rsqrtf(tot * (1.0f / DIM) + 1e-5f);
    float4 wv = *(const float4*)&w[tid * 4];
    ushort4v o;
    o[0] = f2bf(v.x * scale * wv.x); o[1] = f2bf(v.y * scale * wv.y);
    o[2] = f2bf(v.z * scale * wv.z); o[3] = f2bf(v.w * scale * wv.w);
    *(ushort4v*)&out[(size_t)s * DIM + tid * 4] = o;
}

// ---------------- transpose + convert: f32 [K][N] -> bf16 [N][K] ----------------
__global__ __launch_bounds__(256) void transpose_w(const float* __restrict__ in,
                                                   unsigned short* __restrict__ out,
                                                   int K, int N) {
    __shared__ unsigned short t[64][68];
    int n0 = blockIdx.x * 64, k0 = blockIdx.y * 64;
    int tid = threadIdx.x;
    int tn = tid & 15, tk = tid >> 4;
#pragma unroll
    for (int p = 0; p < 4; ++p) {
        int k = tk + p * 16;
        float4 v = *(const float4*)&in[(size_t)(k0 + k) * N + n0 + tn * 4];
        t[tn * 4 + 0][k] = f2bf(v.x);
        t[tn * 4 + 1][k] = f2bf(v.y);
        t[tn * 4 + 2][k] = f2bf(v.z);
        t[tn * 4 + 3][k] = f2bf(v.w);
    }
    __syncthreads();
    int wk = tid & 15, wn = tid >> 4;
#pragma unroll
    for (int p = 0; p < 4; ++p) {
        int n = wn + p * 16;
        ushort4v v;
        v[0] = t[n][wk * 4]; v[1] = t[n][wk * 4 + 1];
        v[2] = t[n][wk * 4 + 2]; v[3] = t[n][wk * 4 + 3];
        *(ushort4v*)&out[(size_t)(n0 + n) * K + k0 + wk * 4] = v;
    }
}

// ---------------- bf16 transpose: [2048][512] -> [512][2048] (for V) ----------------
__global__ __launch_bounds__(256) void transpose_v(const unsigned short* __restrict__ in,
                                                   unsigned short* __restrict__ out) {
    __shared__ unsigned short t[64][72];
    int c0 = blockIdx.x * 64, s0 = blockIdx.y * 64;
    int tid = threadIdx.x;
    int tc = tid & 15, ts = tid >> 4;
#pragma unroll
    for (int p = 0; p < 4; ++p) {
        int s = ts + p * 16;
        ushort4v v = *(const ushort4v*)&in[(size_t)(s0 + s) * 512 + c0 + tc * 4];
        t[tc * 4 + 0][s] = v[0];
        t[tc * 4 + 1][s] = v[1];
        t[tc * 4 + 2][s] = v[2];
        t[tc * 4 + 3][s] = v[3];
    }
    __syncthreads();
    int ws_ = tid & 15, wc = tid >> 4;
#pragma unroll
    for (int p = 0; p < 4; ++p) {
        int c = wc + p * 16;
        ushort4v v;
        v[0] = t[c][ws_ * 4]; v[1] = t[c][ws_ * 4 + 1];
        v[2] = t[c][ws_ * 4 + 2]; v[3] = t[c][ws_ * 4 + 3];
        *(ushort4v*)&out[(size_t)(c0 + c) * 2048 + s0 + ws_ * 4] = v;
    }
}

// ---------------- GEMM (m97 structure, 128^2): A bf16 [M][lda], Bt bf16 [N][K] ----------------
__global__ __launch_bounds__(256) void gemm_tn(const unsigned short* __restrict__ A, int lda,
                                               const unsigned short* __restrict__ Bt,
                                               float* __restrict__ Cf,
                                               unsigned short* __restrict__ Cb,
                                               const float* __restrict__ addsrc,
                                               int N, int K) {
    __shared__ unsigned short As[128 * 64];
    __shared__ unsigned short Bs[128 * 64];
    int tid = threadIdx.x;
    int lane = tid & 63;
    int wid = tid >> 6;
    int wrow = wid >> 1, wcol = wid & 1;
    int lr = lane & 15, lg = lane >> 4;
    const int m0 = blockIdx.x * 128, n0 = blockIdx.y * 128;

    const unsigned short* aG = A + (size_t)(m0 + wid * 32 + (lane >> 3)) * lda + (lane & 7) * 8;
    const unsigned short* bG = Bt + (size_t)(n0 + wid * 32 + (lane >> 3)) * K + (lane & 7) * 8;
    unsigned short* aL = As + wid * 2048;
    unsigned short* bL = Bs + wid * 2048;

    f32x4 acc[4][4] = {};

    for (int k0 = 0; k0 < K; k0 += 64) {
#pragma unroll
        for (int i = 0; i < 4; ++i)
            gload16(aG + (size_t)(i * 8) * lda + k0, aL + i * 512);
#pragma unroll
        for (int i = 0; i < 4; ++i)
            gload16(bG + (size_t)(i * 8) * K + k0, bL + i * 512);
        __syncthreads();
#pragma unroll
        for (int kk = 0; kk < 2; ++kk) {
            bf16x8 aF[4], bF[4];
#pragma unroll
            for (int mi = 0; mi < 4; ++mi)
                aF[mi] = *(const bf16x8*)&As[(wrow * 64 + mi * 16 + lr) * 64 + kk * 32 + lg * 8];
#pragma unroll
            for (int ni = 0; ni < 4; ++ni)
                bF[ni] = *(const bf16x8*)&Bs[(wcol * 64 + ni * 16 + lr) * 64 + kk * 32 + lg * 8];
#pragma unroll
            for (int mi = 0; mi < 4; ++mi)
#pragma unroll
                for (int ni = 0; ni < 4; ++ni)
                    acc[mi][ni] = __builtin_amdgcn_mfma_f32_16x16x32_bf16(aF[mi], bF[ni], acc[mi][ni], 0, 0, 0);
        }
        __syncthreads();
    }
#pragma unroll
    for (int mi = 0; mi < 4; ++mi)
#pragma unroll
        for (int ni = 0; ni < 4; ++ni) {
            int row = m0 + wrow * 64 + mi * 16 + lg * 4;
            int col = n0 + wcol * 64 + ni * 16 + lr;
#pragma unroll
            for (int r = 0; r < 4; ++r) {
                size_t idx = (size_t)(row + r) * N + col;
                float v = acc[mi][ni][r];
                if (addsrc) v += addsrc[idx];
                if (Cb) Cb[idx] = f2bf(v);
                else    Cf[idx] = v;
            }
        }
}

// ---------------- GEMM 256^2 8-phase (T2+T3+T4+T5): A bf16 [M][K], Bt bf16 [N][K] ----------------
// 512 threads = 8 waves (2m x 4n). LDS 128 KiB = 2 buf x {A,B} x 2 kslice x [256][32].
// Swizzle: granule g' = g ^ ((row>>1)&3), applied on pre-swizzled global src + ds_read addr.
#define BAR()  asm volatile("s_barrier" ::: "memory")
#define WAITV(n) asm volatile("s_waitcnt vmcnt(" #n ")" ::: "memory")
#define LGKM0() do { asm volatile("s_waitcnt lgkmcnt(0)" ::: "memory"); __builtin_amdgcn_sched_barrier(0); } while (0)

__global__ __launch_bounds__(512) void gemm8(const unsigned short* __restrict__ A,
                                             const unsigned short* __restrict__ Bt,
                                             float* __restrict__ Cf,
                                             unsigned short* __restrict__ Cb,
                                             int N, int K) {
    __shared__ unsigned short ldsbuf[65536];
    const int NT = K >> 6;
    int tid = threadIdx.x;
    int lane = tid & 63;
    int wid = tid >> 6;
    int wm = wid >> 2, wn = wid & 3;
    int lr = lane & 15, lg = lane >> 4;
    const int m0 = blockIdx.x * 256, n0 = blockIdx.y * 256;

    unsigned lds0 = (unsigned)(size_t)(__attribute__((address_space(3))) unsigned short*)ldsbuf;
    const unsigned xoff = (unsigned)((lg ^ ((lr >> 1) & 3)) * 16);
    const int gsw = (lane & 3) ^ ((lane >> 3) & 3);
    const int srow = wid * 16 + (lane >> 2);

    // stage unit: (buf, ab, s) <- K-tile t. 2 x gload16/thread (rows srow, srow+128).
#define STAGE(buf, ab, s, t) do {                                                   \
        const unsigned short* _src = (ab) ? Bt : A;                                 \
        int _r0 = (ab) ? n0 : m0;                                                   \
        unsigned short* _l = ldsbuf + (((buf) * 2 + (ab)) * 2 + (s)) * 8192 + wid * 512; \
        const unsigned short* _g = _src + (size_t)(_r0 + srow) * K + (size_t)(t) * 64 + (s) * 32 + gsw * 8; \
        gload16(_g, _l);                                                            \
        gload16(_g + (size_t)128 * K, _l + 4096);                                   \
    } while (0)

    f32x4 acc[8][4] = {};

    // prologue: tile0 (buf0) fully + tile1 (buf1) slice0
    STAGE(0, 0, 0, 0); STAGE(0, 1, 0, 0);
    STAGE(0, 0, 1, 0); STAGE(0, 1, 1, 0);
    STAGE(1, 0, 0, 1); STAGE(1, 1, 0, 1);
    WAITV(8);
    BAR();

    for (int t = 0; t < NT; ++t) {
        int buf = t & 1;
        unsigned aBase = lds0 + (unsigned)(buf * 65536) + (unsigned)((wm * 128 + lr) * 64) + xoff;
        unsigned bBase = lds0 + (unsigned)(buf * 65536 + 32768) + (unsigned)((wn * 64 + lr) * 64) + xoff;
        Frag aF[4], bF[4];
#pragma unroll
        for (int s = 0; s < 2; ++s) {
            // ---- phase (s, mh=0): read B(s) + A(s, rows mh0) ----
#pragma unroll
            for (int ni = 0; ni < 4; ++ni)
                bF[ni].f = lds_read_b128(bBase + (unsigned)(s * 16384 + ni * 1024));
#pragma unroll
            for (int mi = 0; mi < 4; ++mi)
                aF[mi].f = lds_read_b128(aBase + (unsigned)(s * 16384 + mi * 1024));
            if (s == 0) { if (t + 1 < NT) STAGE(buf ^ 1, 0, 1, t + 1); }
            else        { if (t + 2 < NT) STAGE(buf,     0, 0, t + 2); }
            BAR();
            LGKM0();
            __builtin_amdgcn_s_setprio(1);
#pragma unroll
            for (int mi = 0; mi < 4; ++mi)
#pragma unroll
                for (int ni = 0; ni < 4; ++ni)
                    acc[mi][ni] = __builtin_amdgcn_mfma_f32_16x16x32_bf16(aF[mi].h, bF[ni].h, acc[mi][ni], 0, 0, 0);
            __builtin_amdgcn_s_setprio(0);
            BAR();
            // ---- phase (s, mh=1): read A(s, rows mh1); B kept in regs ----
#pragma unroll
            for (int mi = 0; mi < 4; ++mi)
                aF[mi].f = lds_read_b128(aBase + (unsigned)(4096 + s * 16384 + mi * 1024));
            if (s == 0) { if (t + 1 < NT) STAGE(buf ^ 1, 1, 1, t + 1); }
            else        { if (t + 2 < NT) STAGE(buf,     1, 0, t + 2); }
            BAR();
            LGKM0();
            __builtin_amdgcn_s_setprio(1);
#pragma unroll
            for (int mi = 0; mi < 4; ++mi)
#pragma unroll
                for (int ni = 0; ni < 4; ++ni)
                    acc[4 + mi][ni] = __builtin_amdgcn_mfma_f32_16x16x32_bf16(aF[mi].h, bF[ni].h, acc[4 + mi][ni], 0, 0, 0);
            __builtin_amdgcn_s_setprio(0);
            if (s == 0) {
                if (t + 1 < NT) { WAITV(8); } else { WAITV(0); }
            } else {
                if (t + 2 < NT)      { WAITV(8); }
                else if (t + 1 < NT) { WAITV(4); }
            }
            BAR();
        }
    }
#undef STAGE

#pragma unroll
    for (int mi = 0; mi < 8; ++mi)
#pragma unroll
        for (int ni = 0; ni < 4; ++ni) {
            int row = m0 + wm * 128 + mi * 16 + lg * 4;
            int col = n0 + wn * 64 + ni * 16 + lr;
#pragma unroll
            for (int r = 0; r < 4; ++r) {
                size_t idx = (size_t)(row + r) * N + col;
                float v = acc[mi][ni][r];
                if (Cb) Cb[idx] = f2bf(v);
                else    Cf[idx] = v;
            }
        }
}

// ---------------- RoPE on fused qkv f32 [S][2048]; writes bf16 qb/kb/vb + news ----------------
__global__ __launch_bounds__(64) void rope_kernel(const float* __restrict__ qkv,
                                                  const float* __restrict__ fc,
                                                  const float* __restrict__ fs,
                                                  unsigned short* __restrict__ qb,
                                                  unsigned short* __restrict__ kb,
                                                  unsigned short* __restrict__ vb,
                                                  float* __restrict__ out, int layer) {
    const size_t LOGITS = (size_t)S_LEN * 32000;
    int s = blockIdx.x;
    int hh = blockIdx.y;
    int lane = threadIdx.x;
    const float* base = qkv + (size_t)s * 2048;
    if (hh < NH) {
        if (lane < 32) {
            const float* row = base + hh * HD;
            float xr = row[2 * lane], xi = row[2 * lane + 1];
            float c = fc[s * 32 + lane], sn = fs[s * 32 + lane];
            size_t o = (size_t)s * (NH * HD) + hh * HD + lane;
            qb[o] = f2bf(xr * c - xi * sn);
            qb[o + 32] = f2bf(xr * sn + xi * c);
        }
    } else if (hh < NH + NKV) {
        int kh = hh - NH;
        if (lane < 32) {
            const float* row = base + 1024 + kh * HD;
            float xr = row[2 * lane], xi = row[2 * lane + 1];
            float c = fc[s * 32 + lane], sn = fs[s * 32 + lane];
            float o0 = xr * c - xi * sn, o1 = xr * sn + xi * c;
            size_t o = (size_t)s * (NKV * HD) + kh * HD + lane;
            kb[o] = f2bf(o0);
            kb[o + 32] = f2bf(o1);
            if (s == S_LEN - 1) {
                float* kn = out + LOGITS + (size_t)layer * (NKV * HD) + kh * HD;
                kn[lane] = o0; kn[lane + 32] = o1;
            }
        }
    } else {
        int vh = hh - NH - NKV;
        const float* row = base + 1536 + vh * HD;
        float val = row[lane];
        vb[(size_t)s * (NKV * HD) + vh * HD + lane] = f2bf(val);
        if (s == S_LEN - 1)
            out[LOGITS + (size_t)2 * (NKV * HD) + (size_t)layer * (NKV * HD) + vh * HD + lane] = val;
    }
}

// ---------------- flash attention: 1 wave per (16 q rows, head); KVBLK=64, V transposed ----------------
__global__ __launch_bounds__(64) void attn_kernel(const unsigned short* __restrict__ qb,
                                                  const unsigned short* __restrict__ kb,
                                                  const unsigned short* __restrict__ vT,
                                                  unsigned short* __restrict__ yb) {
    int qt = blockIdx.x;     // 0..127
    int h = blockIdx.y;      // 0..15
    int kvh = h >> 1;        // rep = 2
    int lane = threadIdx.x;
    int lr = lane & 15, lg = lane >> 4;

    __shared__ unsigned short P[16 * 72];

    bf16x8 aq[2];
    int qrow = qt * 16 + lr;
#pragma unroll
    for (int c = 0; c < 2; ++c)
        aq[c] = *(const bf16x8*)&qb[(size_t)qrow * (NH * HD) + h * HD + c * 32 + lg * 8];

    f32x4 O[4] = {};
    float m[4], l[4];
#pragma unroll
    for (int r = 0; r < 4; ++r) { m[r] = -1e30f; l[r] = 0.f; }

    int ktiles = (qt * 16 + 15) / 64 + 1;
    for (int kt = 0; kt < ktiles; ++kt) {
        f32x4 s[4];
#pragma unroll
        for (int kc = 0; kc < 4; ++kc) {
            int key = kt * 64 + kc * 16 + lr;
            const unsigned short* krow = &kb[(size_t)key * (NKV * HD) + kvh * HD];
            bf16x8 bk0 = *(const bf16x8*)&krow[lg * 8];
            bf16x8 bk1 = *(const bf16x8*)&krow[32 + lg * 8];
            f32x4 z = {};
            z = __builtin_amdgcn_mfma_f32_16x16x32_bf16(aq[0], bk0, z, 0, 0, 0);
            z = __builtin_amdgcn_mfma_f32_16x16x32_bf16(aq[1], bk1, z, 0, 0, 0);
            s[kc] = z;
        }
        float pv[4][4];
#pragma unroll
        for (int r = 0; r < 4; ++r) {
            int row = qt * 16 + lg * 4 + r;
            float tm = -1e30f;
#pragma unroll
            for (int kc = 0; kc < 4; ++kc) {
                int key = kt * 64 + kc * 16 + lr;
                float val = s[kc][r] * 0.125f;
                if (key > row) val = -1e30f;
                pv[kc][r] = val;
                tm = fmaxf(tm, val);
            }
#pragma unroll
            for (int off = 1; off < 16; off <<= 1)
                tm = fmaxf(tm, __shfl_xor(tm, off));
            float mn = fmaxf(m[r], tm);
            float sc = __expf(m[r] - mn);
            l[r] *= sc;
#pragma unroll
            for (int n = 0; n < 4; ++n) O[n][r] *= sc;
            float rs = 0.f;
#pragma unroll
            for (int kc = 0; kc < 4; ++kc) {
                float p = __expf(pv[kc][r] - mn);
                pv[kc][r] = p;
                rs += p;
            }
#pragma unroll
            for (int off = 1; off < 16; off <<= 1)
                rs += __shfl_xor(rs, off);
            l[r] += rs;
            m[r] = mn;
        }
#pragma unroll
        for (int r = 0; r < 4; ++r)
#pragma unroll
            for (int kc = 0; kc < 4; ++kc)
                P[(lg * 4 + r) * 72 + kc * 16 + lr] = f2bf(pv[kc][r]);
        __syncthreads();
        bf16x8 pa[2];
#pragma unroll
        for (int g = 0; g < 2; ++g)
            pa[g] = *(const bf16x8*)&P[lr * 72 + g * 32 + lg * 8];
#pragma unroll
        for (int n = 0; n < 4; ++n) {
#pragma unroll
            for (int g = 0; g < 2; ++g) {
                bf16x8 bv = *(const bf16x8*)&vT[(size_t)(kvh * 64 + n * 16 + lr) * 2048 + kt * 64 + g * 32 + lg * 8];
                O[n] = __builtin_amdgcn_mfma_f32_16x16x32_bf16(pa[g], bv, O[n], 0, 0, 0);
            }
        }
        __syncthreads();
    }
#pragma unroll
    for (int n = 0; n < 4; ++n)
#pragma unroll
        for (int r = 0; r < 4; ++r) {
            int row = qt * 16 + lg * 4 + r;
            yb[(size_t)row * (NH * HD) + h * HD + n * 16 + lr] = f2bf(O[n][r] / l[r]);
        }
}

// ---------------- silu(g)*u in fused gu bf16 [S][5632], in place into g half ----------------
__global__ __launch_bounds__(256) void silu_mul_kernel(unsigned short* __restrict__ gu) {
    size_t idx = (size_t)blockIdx.x * 256 + threadIdx.x;
    int s = (int)(idx / 352);
    int c8 = (int)(idx % 352);
    unsigned short* gp = gu + (size_t)s * 5632 + c8 * 8;
    ushort8v a = *(const ushort8v*)gp;
    ushort8v b = *(const ushort8v*)(gp + 2816);
#pragma unroll
    for (int j = 0; j < 8; ++j) {
        float x = bf2f(a[j]), y = bf2f(b[j]);
        a[j] = f2bf(x / (1.f + __expf(-x)) * y);
    }
    *(ushort8v*)gp = a;
}

extern "C" void kernel_launch(void* const* d_in, const int* in_sizes, int n_in,
                              void* d_out, int out_size, void* d_ws, size_t ws_size,
                              hipStream_t stream) {
    const int* tokens = (const int*)d_in[0];
    const float* freqs_cos = (const float*)d_in[2];
    const float* freqs_sin = (const float*)d_in[3];
    const float* tok_emb = (const float*)d_in[4];
    const float* wq = (const float*)d_in[5];
    const float* wk = (const float*)d_in[6];
    const float* wv = (const float*)d_in[7];
    const float* wo = (const float*)d_in[8];
    const float* attn_norm_w = (const float*)d_in[9];
    const float* ffn_norm_w = (const float*)d_in[10];
    const float* w1 = (const float*)d_in[11];
    const float* w2 = (const float*)d_in[12];
    const float* w3 = (const float*)d_in[13];
    const float* final_norm_w = (const float*)d_in[14];
    const float* out_w = (const float*)d_in[15];
    float* out = (float*)d_out;

    const size_t SD = (size_t)S_LEN * DIM;
    const size_t SKV = (size_t)S_LEN * NKV * HD;

    char* p = (char*)d_ws;
    auto take = [&](size_t bytes) { char* r = p; p += (bytes + 255) & ~(size_t)255; return r; };
    float* h            = (float*)take(SD * 4);
    unsigned short* xnb = (unsigned short*)take(SD * 2);
    char* uni = p;
    float* qkvf         = (float*)uni;                                  // 16 MB
    unsigned short* qb  = (unsigned short*)(uni + 17039360);            // 4 MB
    unsigned short* kb  = qb + SD;                                      // 2 MB
    unsigned short* vb  = kb + SKV;                                     // 2 MB
    unsigned short* vT  = vb + SKV;                                     // 2 MB
    unsigned short* ybv = vT + SKV;                                     // 4 MB
    unsigned short* gu  = ybv + SD;                                     // 23 MB
    unsigned short* wT  = gu + (size_t)S_LEN * 5632;                    // 11.5 MB
    unsigned short* owT = (unsigned short*)uni;                         // 65.5 MB (final phase)

    embed_kernel<<<S_LEN, 256, 0, stream>>>(tokens, tok_emb, h);
    for (int l = 0; l < 2; ++l) {
        rmsnorm_kernel<<<S_LEN, 256, 0, stream>>>(h, attn_norm_w + l * DIM, xnb);
        transpose_w<<<dim3(16, 16), 256, 0, stream>>>(wq + (size_t)l * DIM * 1024, wT, DIM, 1024);
        transpose_w<<<dim3(8, 16), 256, 0, stream>>>(wk + (size_t)l * DIM * 512, wT + (size_t)1024 * DIM, DIM, 512);
        transpose_w<<<dim3(8, 16), 256, 0, stream>>>(wv + (size_t)l * DIM * 512, wT + (size_t)1536 * DIM, DIM, 512);
        gemm_tn<<<dim3(16, 16), 256, 0, stream>>>(xnb, DIM, wT, qkvf, nullptr, nullptr, 2048, DIM);
        rope_kernel<<<dim3(S_LEN, 32), 64, 0, stream>>>(qkvf, freqs_cos, freqs_sin, qb, kb, vb, out, l);
        transpose_v<<<dim3(8, 32), 256, 0, stream>>>(vb, vT);
        attn_kernel<<<dim3(S_LEN / 16, NH), 64, 0, stream>>>(qb, kb, vT, ybv);
        transpose_w<<<dim3(16, 16), 256, 0, stream>>>(wo + (size_t)l * 1024 * DIM, wT, 1024, DIM);
        gemm_tn<<<dim3(16, 8), 256, 0, stream>>>(ybv, 1024, wT, h, nullptr, h, DIM, 1024);
        rmsnorm_kernel<<<S_LEN, 256, 0, stream>>>(h, ffn_norm_w + l * DIM, xnb);
        transpose_w<<<dim3(44, 16), 256, 0, stream>>>(w1 + (size_t)l * DIM * HID, wT, DIM, HID);
        transpose_w<<<dim3(44, 16), 256, 0, stream>>>(w3 + (size_t)l * DIM * HID, wT + (size_t)HID * DIM, DIM, HID);
        gemm8<<<dim3(8, 22), 512, 0, stream>>>(xnb, wT, nullptr, gu, 5632, DIM);
        silu_mul_kernel<<<(S_LEN * 352) / 256, 256, 0, stream>>>(gu);
        transpose_w<<<dim3(16, 44), 256, 0, stream>>>(w2 + (size_t)l * HID * 1024, wT, HID, 1024);
        gemm_tn<<<dim3(16, 8), 256, 0, stream>>>(gu, 5632, wT, h, nullptr, h, DIM, HID);
    }
    rmsnorm_kernel<<<S_LEN, 256, 0, stream>>>(h, final_norm_w, xnb);
    transpose_w<<<dim3(500, 16), 256, 0, stream>>>(out_w, owT, DIM, 32000);
    gemm8<<<dim3(8, 125), 512, 0, stream>>>(xnb, owT, out, nullptr, 32000, DIM);
}

// Round 6
// 921.066 us; speedup vs baseline: 1.0397x; 1.0397x over previous
//
#include <hip/hip_runtime.h>
#include <hip/hip_bf16.h>

typedef __bf16 bf16x8 __attribute__((ext_vector_type(8)));
typedef float f32x4 __attribute__((ext_vector_type(4)));
typedef unsigned short ushort4v __attribute__((ext_vector_type(4)));
typedef unsigned short ushort8v __attribute__((ext_vector_type(8)));

#define S_LEN 2048
#define DIM 1024
#define NH 16
#define NKV 8
#define HD 64
#define HID 2816

__device__ __forceinline__ unsigned short f2bf(float f) {
    union { float f; unsigned u; } v; v.f = f;
    unsigned r = v.u + 0x7fffu + ((v.u >> 16) & 1u);   // RNE
    return (unsigned short)(r >> 16);
}
__device__ __forceinline__ float bf2f(unsigned short u) {
    union { unsigned u; float f; } v; v.u = (unsigned)u << 16; return v.f;
}

__device__ __forceinline__ void gload16(const unsigned short* g, unsigned short* l) {
    __builtin_amdgcn_global_load_lds(
        (const __attribute__((address_space(1))) unsigned int*)g,
        (__attribute__((address_space(3))) unsigned int*)l,
        16, 0, 0);
}

union Frag { f32x4 f; bf16x8 h; };

__device__ __forceinline__ f32x4 lds_read_b128(unsigned addr) {
    f32x4 d;
    asm volatile("ds_read_b128 %0, %1" : "=v"(d) : "v"(addr));
    return d;
}

// ---------------- embedding gather ----------------
__global__ __launch_bounds__(256) void embed_kernel(const int* __restrict__ tokens,
                                                    const float* __restrict__ emb,
                                                    float* __restrict__ h) {
    int s = blockIdx.x;
    int t = tokens[s];
    float4 v = *(const float4*)&emb[(size_t)t * DIM + threadIdx.x * 4];
    *(float4*)&h[(size_t)s * DIM + threadIdx.x * 4] = v;
}

// ---------------- rmsnorm: f32 in -> bf16 out ----------------
__global__ __launch_bounds__(256) void rmsnorm_kernel(const float* __restrict__ x,
                                                      const float* __restrict__ w,
                                                      unsigned short* __restrict__ out) {
    __shared__ float sred[4];
    int s = blockIdx.x;
    int tid = threadIdx.x;
    float4 v = *(const float4*)&x[(size_t)s * DIM + tid * 4];
    float ss = v.x * v.x + v.y * v.y + v.z * v.z + v.w * v.w;
#pragma unroll
    for (int off = 32; off; off >>= 1) ss += __shfl_down(ss, off);
    if ((tid & 63) == 0) sred[tid >> 6] = ss;
    __syncthreads();
    float tot = sred[0] + sred[1] + sred[2] + sred[3];
    float scale = rsqrtf(tot * (1.0f / DIM) + 1e-5f);
    float4 wv = *(const float4*)&w[tid * 4];
    ushort4v o;
    o[0] = f2bf(v.x * scale * wv.x); o[1] = f2bf(v.y * scale * wv.y);
    o[2] = f2bf(v.z * scale * wv.z); o[3] = f2bf(v.w * scale * wv.w);
    *(ushort4v*)&out[(size_t)s * DIM + tid * 4] = o;
}

// ---------------- transpose + convert: f32 [K][N] -> bf16 [N][K] ----------------
__global__ __launch_bounds__(256) void transpose_w(const float* __restrict__ in,
                                                   unsigned short* __restrict__ out,
                                                   int K, int N) {
    __shared__ unsigned short t[64][68];
    int n0 = blockIdx.x * 64, k0 = blockIdx.y * 64;
    int tid = threadIdx.x;
    int tn = tid & 15, tk = tid >> 4;
#pragma unroll
    for (int p = 0; p < 4; ++p) {
        int k = tk + p * 16;
        float4 v = *(const float4*)&in[(size_t)(k0 + k) * N + n0 + tn * 4];
        t[tn * 4 + 0][k] = f2bf(v.x);
        t[tn * 4 + 1][k] = f2bf(v.y);
        t[tn * 4 + 2][k] = f2bf(v.z);
        t[tn * 4 + 3][k] = f2bf(v.w);
    }
    __syncthreads();
    int wk = tid & 15, wn = tid >> 4;
#pragma unroll
    for (int p = 0; p < 4; ++p) {
        int n = wn + p * 16;
        ushort4v v;
        v[0] = t[n][wk * 4]; v[1] = t[n][wk * 4 + 1];
        v[2] = t[n][wk * 4 + 2]; v[3] = t[n][wk * 4 + 3];
        *(ushort4v*)&out[(size_t)(n0 + n) * K + k0 + wk * 4] = v;
    }
}

// ---------------- bf16 transpose: [2048][512] -> [512][2048] (for V) ----------------
__global__ __launch_bounds__(256) void transpose_v(const unsigned short* __restrict__ in,
                                                   unsigned short* __restrict__ out) {
    __shared__ unsigned short t[64][72];
    int c0 = blockIdx.x * 64, s0 = blockIdx.y * 64;
    int tid = threadIdx.x;
    int tc = tid & 15, ts = tid >> 4;
#pragma unroll
    for (int p = 0; p < 4; ++p) {
        int s = ts + p * 16;
        ushort4v v = *(const ushort4v*)&in[(size_t)(s0 + s) * 512 + c0 + tc * 4];
        t[tc * 4 + 0][s] = v[0];
        t[tc * 4 + 1][s] = v[1];
        t[tc * 4 + 2][s] = v[2];
        t[tc * 4 + 3][s] = v[3];
    }
    __syncthreads();
    int ws_ = tid & 15, wc = tid >> 4;
#pragma unroll
    for (int p = 0; p < 4; ++p) {
        int c = wc + p * 16;
        ushort4v v;
        v[0] = t[c][ws_ * 4]; v[1] = t[c][ws_ * 4 + 1];
        v[2] = t[c][ws_ * 4 + 2]; v[3] = t[c][ws_ * 4 + 3];
        *(ushort4v*)&out[(size_t)(c0 + c) * 2048 + s0 + ws_ * 4] = v;
    }
}

// ---------------- GEMM (m97 structure, 128^2): A bf16 [M][lda], Bt bf16 [N][K] ----------------
__global__ __launch_bounds__(256) void gemm_tn(const unsigned short* __restrict__ A, int lda,
                                               const unsigned short* __restrict__ Bt,
                                               float* __restrict__ Cf,
                                               unsigned short* __restrict__ Cb,
                                               const float* __restrict__ addsrc,
                                               int N, int K) {
    __shared__ unsigned short As[128 * 64];
    __shared__ unsigned short Bs[128 * 64];
    int tid = threadIdx.x;
    int lane = tid & 63;
    int wid = tid >> 6;
    int wrow = wid >> 1, wcol = wid & 1;
    int lr = lane & 15, lg = lane >> 4;
    const int m0 = blockIdx.x * 128, n0 = blockIdx.y * 128;

    const unsigned short* aG = A + (size_t)(m0 + wid * 32 + (lane >> 3)) * lda + (lane & 7) * 8;
    const unsigned short* bG = Bt + (size_t)(n0 + wid * 32 + (lane >> 3)) * K + (lane & 7) * 8;
    unsigned short* aL = As + wid * 2048;
    unsigned short* bL = Bs + wid * 2048;

    f32x4 acc[4][4] = {};

    for (int k0 = 0; k0 < K; k0 += 64) {
#pragma unroll
        for (int i = 0; i < 4; ++i)
            gload16(aG + (size_t)(i * 8) * lda + k0, aL + i * 512);
#pragma unroll
        for (int i = 0; i < 4; ++i)
            gload16(bG + (size_t)(i * 8) * K + k0, bL + i * 512);
        __syncthreads();
#pragma unroll
        for (int kk = 0; kk < 2; ++kk) {
            bf16x8 aF[4], bF[4];
#pragma unroll
            for (int mi = 0; mi < 4; ++mi)
                aF[mi] = *(const bf16x8*)&As[(wrow * 64 + mi * 16 + lr) * 64 + kk * 32 + lg * 8];
#pragma unroll
            for (int ni = 0; ni < 4; ++ni)
                bF[ni] = *(const bf16x8*)&Bs[(wcol * 64 + ni * 16 + lr) * 64 + kk * 32 + lg * 8];
#pragma unroll
            for (int mi = 0; mi < 4; ++mi)
#pragma unroll
                for (int ni = 0; ni < 4; ++ni)
                    acc[mi][ni] = __builtin_amdgcn_mfma_f32_16x16x32_bf16(aF[mi], bF[ni], acc[mi][ni], 0, 0, 0);
        }
        __syncthreads();
    }
#pragma unroll
    for (int mi = 0; mi < 4; ++mi)
#pragma unroll
        for (int ni = 0; ni < 4; ++ni) {
            int row = m0 + wrow * 64 + mi * 16 + lg * 4;
            int col = n0 + wcol * 64 + ni * 16 + lr;
#pragma unroll
            for (int r = 0; r < 4; ++r) {
                size_t idx = (size_t)(row + r) * N + col;
                float v = acc[mi][ni][r];
                if (addsrc) v += addsrc[idx];
                if (Cb) Cb[idx] = f2bf(v);
                else    Cf[idx] = v;
            }
        }
}

// ---------------- GEMM 256^2 8-phase (T1+T2+T3+T4+T5): A bf16 [M][K], Bt bf16 [N][K] ----------------
// gridDim.x MUST be 8 (M=2048). XCD y-chunked swizzle: each XCD walks all m for a y-chunk.
#define BAR()  asm volatile("s_barrier" ::: "memory")
#define WAITV(n) asm volatile("s_waitcnt vmcnt(" #n ")" ::: "memory")
#define LGKM0() do { asm volatile("s_waitcnt lgkmcnt(0)" ::: "memory"); __builtin_amdgcn_sched_barrier(0); } while (0)

__global__ __launch_bounds__(512) void gemm8(const unsigned short* __restrict__ A,
                                             const unsigned short* __restrict__ Bt,
                                             float* __restrict__ Cf,
                                             unsigned short* __restrict__ Cb,
                                             int N, int K) {
    __shared__ unsigned short ldsbuf[65536];
    const int NT = K >> 6;
    int tid = threadIdx.x;
    int lane = tid & 63;
    int wid = tid >> 6;
    int wm = wid >> 2, wn = wid & 3;
    int lr = lane & 15, lg = lane >> 4;
    // XCD swizzle: dispatch slot = by*8+bx -> XCD = bx; give XCD bx a contiguous y-chunk.
    int wl = blockIdx.x * gridDim.y + blockIdx.y;
    const int m0 = (wl & 7) * 256, n0 = (wl >> 3) * 256;

    unsigned lds0 = (unsigned)(size_t)(__attribute__((address_space(3))) unsigned short*)ldsbuf;
    const unsigned xoff = (unsigned)((lg ^ ((lr >> 1) & 3)) * 16);
    const int gsw = (lane & 3) ^ ((lane >> 3) & 3);
    const int srow = wid * 16 + (lane >> 2);

#define STAGE(buf, ab, s, t) do {                                                   \
        const unsigned short* _src = (ab) ? Bt : A;                                 \
        int _r0 = (ab) ? n0 : m0;                                                   \
        unsigned short* _l = ldsbuf + (((buf) * 2 + (ab)) * 2 + (s)) * 8192 + wid * 512; \
        const unsigned short* _g = _src + (size_t)(_r0 + srow) * K + (size_t)(t) * 64 + (s) * 32 + gsw * 8; \
        gload16(_g, _l);                                                            \
        gload16(_g + (size_t)128 * K, _l + 4096);                                   \
    } while (0)

    f32x4 acc[8][4] = {};

    STAGE(0, 0, 0, 0); STAGE(0, 1, 0, 0);
    STAGE(0, 0, 1, 0); STAGE(0, 1, 1, 0);
    STAGE(1, 0, 0, 1); STAGE(1, 1, 0, 1);
    WAITV(8);
    BAR();

    for (int t = 0; t < NT; ++t) {
        int buf = t & 1;
        unsigned aBase = lds0 + (unsigned)(buf * 65536) + (unsigned)((wm * 128 + lr) * 64) + xoff;
        unsigned bBase = lds0 + (unsigned)(buf * 65536 + 32768) + (unsigned)((wn * 64 + lr) * 64) + xoff;
        Frag aF[4], bF[4];
#pragma unroll
        for (int s = 0; s < 2; ++s) {
#pragma unroll
            for (int ni = 0; ni < 4; ++ni)
                bF[ni].f = lds_read_b128(bBase + (unsigned)(s * 16384 + ni * 1024));
#pragma unroll
            for (int mi = 0; mi < 4; ++mi)
                aF[mi].f = lds_read_b128(aBase + (unsigned)(s * 16384 + mi * 1024));
            if (s == 0) { if (t + 1 < NT) STAGE(buf ^ 1, 0, 1, t + 1); }
            else        { if (t + 2 < NT) STAGE(buf,     0, 0, t + 2); }
            BAR();
            LGKM0();
            __builtin_amdgcn_s_setprio(1);
#pragma unroll
            for (int mi = 0; mi < 4; ++mi)
#pragma unroll
                for (int ni = 0; ni < 4; ++ni)
                    acc[mi][ni] = __builtin_amdgcn_mfma_f32_16x16x32_bf16(aF[mi].h, bF[ni].h, acc[mi][ni], 0, 0, 0);
            __builtin_amdgcn_s_setprio(0);
            BAR();
#pragma unroll
            for (int mi = 0; mi < 4; ++mi)
                aF[mi].f = lds_read_b128(aBase + (unsigned)(4096 + s * 16384 + mi * 1024));
            if (s == 0) { if (t + 1 < NT) STAGE(buf ^ 1, 1, 1, t + 1); }
            else        { if (t + 2 < NT) STAGE(buf,     1, 0, t + 2); }
            BAR();
            LGKM0();
            __builtin_amdgcn_s_setprio(1);
#pragma unroll
            for (int mi = 0; mi < 4; ++mi)
#pragma unroll
                for (int ni = 0; ni < 4; ++ni)
                    acc[4 + mi][ni] = __builtin_amdgcn_mfma_f32_16x16x32_bf16(aF[mi].h, bF[ni].h, acc[4 + mi][ni], 0, 0, 0);
            __builtin_amdgcn_s_setprio(0);
            if (s == 0) {
                if (t + 1 < NT) { WAITV(8); } else { WAITV(0); }
            } else {
                if (t + 2 < NT)      { WAITV(8); }
                else if (t + 1 < NT) { WAITV(4); }
            }
            BAR();
        }
    }
#undef STAGE

#pragma unroll
    for (int mi = 0; mi < 8; ++mi)
#pragma unroll
        for (int ni = 0; ni < 4; ++ni) {
            int row = m0 + wm * 128 + mi * 16 + lg * 4;
            int col = n0 + wn * 64 + ni * 16 + lr;
#pragma unroll
            for (int r = 0; r < 4; ++r) {
                size_t idx = (size_t)(row + r) * N + col;
                float v = acc[mi][ni][r];
                if (Cb) Cb[idx] = f2bf(v);
                else    Cf[idx] = v;
            }
        }
}

// ---------------- RoPE on fused qkv f32 [S][2048]; 4 s-positions per block ----------------
__global__ __launch_bounds__(256) void rope_kernel(const float* __restrict__ qkv,
                                                   const float* __restrict__ fc,
                                                   const float* __restrict__ fs,
                                                   unsigned short* __restrict__ qb,
                                                   unsigned short* __restrict__ kb,
                                                   unsigned short* __restrict__ vb,
                                                   float* __restrict__ out, int layer) {
    const size_t LOGITS = (size_t)S_LEN * 32000;
    int s = blockIdx.x * 4 + (threadIdx.x >> 6);
    int hh = blockIdx.y;
    int lane = threadIdx.x & 63;
    const float* base = qkv + (size_t)s * 2048;
    if (hh < NH) {
        if (lane < 32) {
            const float* row = base + hh * HD;
            float2 x2 = *(const float2*)&row[2 * lane];
            float c = fc[s * 32 + lane], sn = fs[s * 32 + lane];
            size_t o = (size_t)s * (NH * HD) + hh * HD + lane;
            qb[o] = f2bf(x2.x * c - x2.y * sn);
            qb[o + 32] = f2bf(x2.x * sn + x2.y * c);
        }
    } else if (hh < NH + NKV) {
        int kh = hh - NH;
        if (lane < 32) {
            const float* row = base + 1024 + kh * HD;
            float2 x2 = *(const float2*)&row[2 * lane];
            float c = fc[s * 32 + lane], sn = fs[s * 32 + lane];
            float o0 = x2.x * c - x2.y * sn, o1 = x2.x * sn + x2.y * c;
            size_t o = (size_t)s * (NKV * HD) + kh * HD + lane;
            kb[o] = f2bf(o0);
            kb[o + 32] = f2bf(o1);
            if (s == S_LEN - 1) {
                float* kn = out + LOGITS + (size_t)layer * (NKV * HD) + kh * HD;
                kn[lane] = o0; kn[lane + 32] = o1;
            }
        }
    } else {
        int vh = hh - NH - NKV;
        const float* row = base + 1536 + vh * HD;
        float val = row[lane];
        vb[(size_t)s * (NKV * HD) + vh * HD + lane] = f2bf(val);
        if (s == S_LEN - 1)
            out[LOGITS + (size_t)2 * (NKV * HD) + (size_t)layer * (NKV * HD) + vh * HD + lane] = val;
    }
}

// ---------------- flash attention, swapped QK^T: lane owns q=lane&15, keys in-register ----------------
__global__ __launch_bounds__(64) void attn_kernel(const unsigned short* __restrict__ qb,
                                                  const unsigned short* __restrict__ kb,
                                                  const unsigned short* __restrict__ vT,
                                                  unsigned short* __restrict__ yb) {
    int qt = blockIdx.x;     // 0..127
    int h = blockIdx.y;      // 0..15
    int kvh = h >> 1;        // rep = 2
    int lane = threadIdx.x;
    int lr = lane & 15, lg = lane >> 4;

    __shared__ unsigned short P[16 * 72];

    // Q as B-fragment (rows = q)
    bf16x8 bq[2];
    int qrow = qt * 16 + lr;
#pragma unroll
    for (int c = 0; c < 2; ++c)
        bq[c] = *(const bf16x8*)&qb[(size_t)qrow * (NH * HD) + h * HD + c * 32 + lg * 8];

    f32x4 O[4] = {};
    float mstate = -1e30f, lstate = 0.f;
    const int qglob = qt * 16 + lr;

    int ktiles = (qt * 16 + 15) / 64 + 1;
    for (int kt = 0; kt < ktiles; ++kt) {
        // S^T = K · Q^T : lane holds S[q=lr][key = kt*64 + kc*16 + lg*4 + r]
        f32x4 s[4];
#pragma unroll
        for (int kc = 0; kc < 4; ++kc) {
            int key = kt * 64 + kc * 16 + lr;  // A-frag row
            const unsigned short* krow = &kb[(size_t)key * (NKV * HD) + kvh * HD];
            bf16x8 ak0 = *(const bf16x8*)&krow[lg * 8];
            bf16x8 ak1 = *(const bf16x8*)&krow[32 + lg * 8];
            f32x4 z = {};
            z = __builtin_amdgcn_mfma_f32_16x16x32_bf16(ak0, bq[0], z, 0, 0, 0);
            z = __builtin_amdgcn_mfma_f32_16x16x32_bf16(ak1, bq[1], z, 0, 0, 0);
            s[kc] = z;
        }
        float tm = -1e30f;
#pragma unroll
        for (int kc = 0; kc < 4; ++kc)
#pragma unroll
            for (int r = 0; r < 4; ++r) {
                int key = kt * 64 + kc * 16 + lg * 4 + r;
                float val = s[kc][r] * 0.125f;
                if (key > qglob) val = -1e30f;
                s[kc][r] = val;
                tm = fmaxf(tm, val);
            }
        tm = fmaxf(tm, __shfl_xor(tm, 16));
        tm = fmaxf(tm, __shfl_xor(tm, 32));
        float mn = fmaxf(mstate, tm);
        float sc = __expf(mstate - mn);
        float rs = 0.f;
        ushort4v pk[4];
#pragma unroll
        for (int kc = 0; kc < 4; ++kc)
#pragma unroll
            for (int r = 0; r < 4; ++r) {
                float pf = __expf(s[kc][r] - mn);
                rs += pf;
                pk[kc][r] = f2bf(pf);
            }
        rs += __shfl_xor(rs, 16);
        rs += __shfl_xor(rs, 32);
        lstate = lstate * sc + rs;
        mstate = mn;
        // O rescale: O row q_local = lg*4+r; sc lives in lane with lr == q_local
        float osc[4];
#pragma unroll
        for (int r = 0; r < 4; ++r)
            osc[r] = __shfl(sc, lg * 4 + r);
#pragma unroll
        for (int n = 0; n < 4; ++n)
#pragma unroll
            for (int r = 0; r < 4; ++r)
                O[n][r] *= osc[r];
        // P[q=lr][key_local]: 4 contiguous keys per kc -> b64 writes
        __syncthreads();
#pragma unroll
        for (int kc = 0; kc < 4; ++kc)
            *(ushort4v*)&P[lr * 72 + kc * 16 + lg * 4] = pk[kc];
        __syncthreads();
        bf16x8 pa[2];
#pragma unroll
        for (int g = 0; g < 2; ++g)
            pa[g] = *(const bf16x8*)&P[lr * 72 + g * 32 + lg * 8];
#pragma unroll
        for (int n = 0; n < 4; ++n)
#pragma unroll
            for (int g = 0; g < 2; ++g) {
                bf16x8 bv = *(const bf16x8*)&vT[(size_t)(kvh * 64 + n * 16 + lr) * 2048 + kt * 64 + g * 32 + lg * 8];
                O[n] = __builtin_amdgcn_mfma_f32_16x16x32_bf16(pa[g], bv, O[n], 0, 0, 0);
            }
    }
    float linv[4];
#pragma unroll
    for (int r = 0; r < 4; ++r)
        linv[r] = 1.f / __shfl(lstate, lg * 4 + r);
#pragma unroll
    for (int n = 0; n < 4; ++n)
#pragma unroll
        for (int r = 0; r < 4; ++r) {
            int row = qt * 16 + lg * 4 + r;
            yb[(size_t)row * (NH * HD) + h * HD + n * 16 + lr] = f2bf(O[n][r] * linv[r]);
        }
}

// ---------------- silu(g)*u in fused gu bf16 [S][5632], in place into g half ----------------
__global__ __launch_bounds__(256) void silu_mul_kernel(unsigned short* __restrict__ gu) {
    size_t idx = (size_t)blockIdx.x * 256 + threadIdx.x;
    int s = (int)(idx / 352);
    int c8 = (int)(idx % 352);
    unsigned short* gp = gu + (size_t)s * 5632 + c8 * 8;
    ushort8v a = *(const ushort8v*)gp;
    ushort8v b = *(const ushort8v*)(gp + 2816);
#pragma unroll
    for (int j = 0; j < 8; ++j) {
        float x = bf2f(a[j]), y = bf2f(b[j]);
        a[j] = f2bf(x / (1.f + __expf(-x)) * y);
    }
    *(ushort8v*)gp = a;
}

extern "C" void kernel_launch(void* const* d_in, const int* in_sizes, int n_in,
                              void* d_out, int out_size, void* d_ws, size_t ws_size,
                              hipStream_t stream) {
    const int* tokens = (const int*)d_in[0];
    const float* freqs_cos = (const float*)d_in[2];
    const float* freqs_sin = (const float*)d_in[3];
    const float* tok_emb = (const float*)d_in[4];
    const float* wq = (const float*)d_in[5];
    const float* wk = (const float*)d_in[6];
    const float* wv = (const float*)d_in[7];
    const float* wo = (const float*)d_in[8];
    const float* attn_norm_w = (const float*)d_in[9];
    const float* ffn_norm_w = (const float*)d_in[10];
    const float* w1 = (const float*)d_in[11];
    const float* w2 = (const float*)d_in[12];
    const float* w3 = (const float*)d_in[13];
    const float* final_norm_w = (const float*)d_in[14];
    const float* out_w = (const float*)d_in[15];
    float* out = (float*)d_out;

    const size_t SD = (size_t)S_LEN * DIM;
    const size_t SKV = (size_t)S_LEN * NKV * HD;

    char* p = (char*)d_ws;
    auto take = [&](size_t bytes) { char* r = p; p += (bytes + 255) & ~(size_t)255; return r; };
    float* h            = (float*)take(SD * 4);
    unsigned short* xnb = (unsigned short*)take(SD * 2);
    char* uni = p;
    float* qkvf         = (float*)uni;                                  // 16 MB
    unsigned short* qb  = (unsigned short*)(uni + 17039360);            // 4 MB
    unsigned short* kb  = qb + SD;                                      // 2 MB
    unsigned short* vb  = kb + SKV;                                     // 2 MB
    unsigned short* vT  = vb + SKV;                                     // 2 MB
    unsigned short* ybv = vT + SKV;                                     // 4 MB
    unsigned short* gu  = ybv + SD;                                     // 23 MB
    unsigned short* wT  = gu + (size_t)S_LEN * 5632;                    // 11.5 MB
    unsigned short* owT = (unsigned short*)uni;                         // 65.5 MB (final phase)

    embed_kernel<<<S_LEN, 256, 0, stream>>>(tokens, tok_emb, h);
    for (int l = 0; l < 2; ++l) {
        rmsnorm_kernel<<<S_LEN, 256, 0, stream>>>(h, attn_norm_w + l * DIM, xnb);
        transpose_w<<<dim3(16, 16), 256, 0, stream>>>(wq + (size_t)l * DIM * 1024, wT, DIM, 1024);
        transpose_w<<<dim3(8, 16), 256, 0, stream>>>(wk + (size_t)l * DIM * 512, wT + (size_t)1024 * DIM, DIM, 512);
        transpose_w<<<dim3(8, 16), 256, 0, stream>>>(wv + (size_t)l * DIM * 512, wT + (size_t)1536 * DIM, DIM, 512);
        gemm_tn<<<dim3(16, 16), 256, 0, stream>>>(xnb, DIM, wT, qkvf, nullptr, nullptr, 2048, DIM);
        rope_kernel<<<dim3(S_LEN / 4, 32), 256, 0, stream>>>(qkvf, freqs_cos, freqs_sin, qb, kb, vb, out, l);
        transpose_v<<<dim3(8, 32), 256, 0, stream>>>(vb, vT);
        attn_kernel<<<dim3(S_LEN / 16, NH), 64, 0, stream>>>(qb, kb, vT, ybv);
        transpose_w<<<dim3(16, 16), 256, 0, stream>>>(wo + (size_t)l * 1024 * DIM, wT, 1024, DIM);
        gemm_tn<<<dim3(16, 8), 256, 0, stream>>>(ybv, 1024, wT, h, nullptr, h, DIM, 1024);
        rmsnorm_kernel<<<S_LEN, 256, 0, stream>>>(h, ffn_norm_w + l * DIM, xnb);
        transpose_w<<<dim3(44, 16), 256, 0, stream>>>(w1 + (size_t)l * DIM * HID, wT, DIM, HID);
        transpose_w<<<dim3(44, 16), 256, 0, stream>>>(w3 + (size_t)l * DIM * HID, wT + (size_t)HID * DIM, DIM, HID);
        gemm8<<<dim3(8, 22), 512, 0, stream>>>(xnb, wT, nullptr, gu, 5632, DIM);
        silu_mul_kernel<<<(S_LEN * 352) / 256, 256, 0, stream>>>(gu);
        transpose_w<<<dim3(16, 44), 256, 0, stream>>>(w2 + (size_t)l * HID * 1024, wT, HID, 1024);
        gemm_tn<<<dim3(16, 8), 256, 0, stream>>>(gu, 5632, wT, h, nullptr, h, DIM, HID);
    }
    rmsnorm_kernel<<<S_LEN, 256, 0, stream>>>(h, final_norm_w, xnb);
    transpose_w<<<dim3(500, 16), 256, 0, stream>>>(out_w, owT, DIM, 32000);
    gemm8<<<dim3(8, 125), 512, 0, stream>>>(xnb, owT, out, nullptr, 32000, DIM);
}

// Round 7
// 688.506 us; speedup vs baseline: 1.3909x; 1.3378x over previous
//
#include <hip/hip_runtime.h>
#include <hip/hip_bf16.h>

typedef __bf16 bf16x8 __attribute__((ext_vector_type(8)));
typedef float f32x4 __attribute__((ext_vector_type(4)));
typedef unsigned short ushort4v __attribute__((ext_vector_type(4)));
typedef unsigned short ushort8v __attribute__((ext_vector_type(8)));

#define S_LEN 2048
#define DIM 1024
#define NH 16
#define NKV 8
#define HD 64
#define HID 2816

__device__ __forceinline__ unsigned short f2bf(float f) {
    union { float f; unsigned u; } v; v.f = f;
    unsigned r = v.u + 0x7fffu + ((v.u >> 16) & 1u);   // RNE
    return (unsigned short)(r >> 16);
}
__device__ __forceinline__ float bf2f(unsigned short u) {
    union { unsigned u; float f; } v; v.u = (unsigned)u << 16; return v.f;
}

__device__ __forceinline__ void gload16(const unsigned short* g, unsigned short* l) {
    __builtin_amdgcn_global_load_lds(
        (const __attribute__((address_space(1))) unsigned int*)g,
        (__attribute__((address_space(3))) unsigned int*)l,
        16, 0, 0);
}

union Frag { f32x4 f; bf16x8 h; };

__device__ __forceinline__ f32x4 lds_read_b128(unsigned addr) {
    f32x4 d;
    asm volatile("ds_read_b128 %0, %1" : "=v"(d) : "v"(addr));
    return d;
}

#define BAR()  asm volatile("s_barrier" ::: "memory")
#define WAITV(n) asm volatile("s_waitcnt vmcnt(" #n ")" ::: "memory")
#define LGKM0() do { asm volatile("s_waitcnt lgkmcnt(0)" ::: "memory"); __builtin_amdgcn_sched_barrier(0); } while (0)

// ---------------- embedding gather ----------------
__global__ __launch_bounds__(256) void embed_kernel(const int* __restrict__ tokens,
                                                    const float* __restrict__ emb,
                                                    float* __restrict__ h) {
    int s = blockIdx.x;
    int t = tokens[s];
    float4 v = *(const float4*)&emb[(size_t)t * DIM + threadIdx.x * 4];
    *(float4*)&h[(size_t)s * DIM + threadIdx.x * 4] = v;
}

// ---------------- rmsnorm: f32 in -> bf16 out ----------------
__global__ __launch_bounds__(256) void rmsnorm_kernel(const float* __restrict__ x,
                                                      const float* __restrict__ w,
                                                      unsigned short* __restrict__ out) {
    __shared__ float sred[4];
    int s = blockIdx.x;
    int tid = threadIdx.x;
    float4 v = *(const float4*)&x[(size_t)s * DIM + tid * 4];
    float ss = v.x * v.x + v.y * v.y + v.z * v.z + v.w * v.w;
#pragma unroll
    for (int off = 32; off; off >>= 1) ss += __shfl_down(ss, off);
    if ((tid & 63) == 0) sred[tid >> 6] = ss;
    __syncthreads();
    float tot = sred[0] + sred[1] + sred[2] + sred[3];
    float scale = rsqrtf(tot * (1.0f / DIM) + 1e-5f);
    float4 wv = *(const float4*)&w[tid * 4];
    ushort4v o;
    o[0] = f2bf(v.x * scale * wv.x); o[1] = f2bf(v.y * scale * wv.y);
    o[2] = f2bf(v.z * scale * wv.z); o[3] = f2bf(v.w * scale * wv.w);
    *(ushort4v*)&out[(size_t)s * DIM + tid * 4] = o;
}

// ---------------- transpose + convert: f32 [K][N] -> bf16 [N][K] ----------------
__global__ __launch_bounds__(256) void transpose_w(const float* __restrict__ in,
                                                   unsigned short* __restrict__ out,
                                                   int K, int N) {
    __shared__ unsigned short t[64][68];
    int n0 = blockIdx.x * 64, k0 = blockIdx.y * 64;
    int tid = threadIdx.x;
    int tn = tid & 15, tk = tid >> 4;
#pragma unroll
    for (int p = 0; p < 4; ++p) {
        int k = tk + p * 16;
        float4 v = *(const float4*)&in[(size_t)(k0 + k) * N + n0 + tn * 4];
        t[tn * 4 + 0][k] = f2bf(v.x);
        t[tn * 4 + 1][k] = f2bf(v.y);
        t[tn * 4 + 2][k] = f2bf(v.z);
        t[tn * 4 + 3][k] = f2bf(v.w);
    }
    __syncthreads();
    int wk = tid & 15, wn = tid >> 4;
#pragma unroll
    for (int p = 0; p < 4; ++p) {
        int n = wn + p * 16;
        ushort4v v;
        v[0] = t[n][wk * 4]; v[1] = t[n][wk * 4 + 1];
        v[2] = t[n][wk * 4 + 2]; v[3] = t[n][wk * 4 + 3];
        *(ushort4v*)&out[(size_t)(n0 + n) * K + k0 + wk * 4] = v;
    }
}

// ---------------- bf16 transpose: [2048][512] -> [512][2048] (for V) ----------------
__global__ __launch_bounds__(256) void transpose_v(const unsigned short* __restrict__ in,
                                                   unsigned short* __restrict__ out) {
    __shared__ unsigned short t[64][72];
    int c0 = blockIdx.x * 64, s0 = blockIdx.y * 64;
    int tid = threadIdx.x;
    int tc = tid & 15, ts = tid >> 4;
#pragma unroll
    for (int p = 0; p < 4; ++p) {
        int s = ts + p * 16;
        ushort4v v = *(const ushort4v*)&in[(size_t)(s0 + s) * 512 + c0 + tc * 4];
        t[tc * 4 + 0][s] = v[0];
        t[tc * 4 + 1][s] = v[1];
        t[tc * 4 + 2][s] = v[2];
        t[tc * 4 + 3][s] = v[3];
    }
    __syncthreads();
    int ws_ = tid & 15, wc = tid >> 4;
#pragma unroll
    for (int p = 0; p < 4; ++p) {
        int c = wc + p * 16;
        ushort4v v;
        v[0] = t[c][ws_ * 4]; v[1] = t[c][ws_ * 4 + 1];
        v[2] = t[c][ws_ * 4 + 2]; v[3] = t[c][ws_ * 4 + 3];
        *(ushort4v*)&out[(size_t)(c0 + c) * 2048 + s0 + ws_ * 4] = v;
    }
}

// ---------------- GEMM 128^2, swizzled LDS: A bf16 [M][lda], Bt bf16 [N][K] ----------------
__global__ __launch_bounds__(256) void gemm_tn(const unsigned short* __restrict__ A, int lda,
                                               const unsigned short* __restrict__ Bt,
                                               float* __restrict__ Cf,
                                               unsigned short* __restrict__ Cb,
                                               const float* __restrict__ addsrc,
                                               int N, int K) {
    __shared__ unsigned short As[128 * 64];
    __shared__ unsigned short Bs[128 * 64];
    int tid = threadIdx.x;
    int lane = tid & 63;
    int wid = tid >> 6;
    int wrow = wid >> 1, wcol = wid & 1;
    int lr = lane & 15, lg = lane >> 4;
    const int m0 = blockIdx.x * 128, n0 = blockIdx.y * 128;

    // staged rows are (wid*32 + (lane>>3) + 8i): row&7 == (lane>>3)&7, thread-invariant
    const int col8 = (((lane & 7) ^ ((lane >> 3) & 7)) * 8);
    const unsigned short* aG = A + (size_t)(m0 + wid * 32 + (lane >> 3)) * lda + col8;
    const unsigned short* bG = Bt + (size_t)(n0 + wid * 32 + (lane >> 3)) * K + col8;
    unsigned short* aL = As + wid * 2048;
    unsigned short* bL = Bs + wid * 2048;

    f32x4 acc[4][4] = {};

    for (int k0 = 0; k0 < K; k0 += 64) {
#pragma unroll
        for (int i = 0; i < 4; ++i)
            gload16(aG + (size_t)(i * 8) * lda + k0, aL + i * 512);
#pragma unroll
        for (int i = 0; i < 4; ++i)
            gload16(bG + (size_t)(i * 8) * K + k0, bL + i * 512);
        __syncthreads();
#pragma unroll
        for (int kk = 0; kk < 2; ++kk) {
            const int slot = ((kk * 4 + lg) ^ (lr & 7)) * 8;
            bf16x8 aF[4], bF[4];
#pragma unroll
            for (int mi = 0; mi < 4; ++mi)
                aF[mi] = *(const bf16x8*)&As[(wrow * 64 + mi * 16 + lr) * 64 + slot];
#pragma unroll
            for (int ni = 0; ni < 4; ++ni)
                bF[ni] = *(const bf16x8*)&Bs[(wcol * 64 + ni * 16 + lr) * 64 + slot];
#pragma unroll
            for (int mi = 0; mi < 4; ++mi)
#pragma unroll
                for (int ni = 0; ni < 4; ++ni)
                    acc[mi][ni] = __builtin_amdgcn_mfma_f32_16x16x32_bf16(aF[mi], bF[ni], acc[mi][ni], 0, 0, 0);
        }
        __syncthreads();
    }
#pragma unroll
    for (int mi = 0; mi < 4; ++mi)
#pragma unroll
        for (int ni = 0; ni < 4; ++ni) {
            int row = m0 + wrow * 64 + mi * 16 + lg * 4;
            int col = n0 + wcol * 64 + ni * 16 + lr;
#pragma unroll
            for (int r = 0; r < 4; ++r) {
                size_t idx = (size_t)(row + r) * N + col;
                float v = acc[mi][ni][r];
                if (addsrc) v += addsrc[idx];
                if (Cb) Cb[idx] = f2bf(v);
                else    Cf[idx] = v;
            }
        }
}

// ---------------- GEMM BM=64, BN=128 (for N=1024 outputs: full-chip grid 32x8) ----------------
__global__ __launch_bounds__(256) void gemm_tn64(const unsigned short* __restrict__ A, int lda,
                                                 const unsigned short* __restrict__ Bt,
                                                 float* __restrict__ Cf,
                                                 unsigned short* __restrict__ Cb,
                                                 const float* __restrict__ addsrc,
                                                 int N, int K) {
    __shared__ unsigned short As[64 * 64];
    __shared__ unsigned short Bs[128 * 64];
    int tid = threadIdx.x;
    int lane = tid & 63;
    int wid = tid >> 6;
    int lr = lane & 15, lg = lane >> 4;
    const int m0 = blockIdx.x * 64, n0 = blockIdx.y * 128;

    const int srow = tid >> 3;                        // 0..31? no: 0..31 for 256 threads -> t>>3 in 0..31
    // NOTE: 256 threads cover 64 rows x 8 granules with 2 passes for A? No:
    // t>>3 spans 0..31 -> stage A rows 0..31 and 32..63 separately.
    const int col8 = (((tid & 7) ^ ((tid >> 3) & 7)) * 8);
    const unsigned short* aG = A + (size_t)(m0 + srow) * lda + col8;
    const unsigned short* bG = Bt + (size_t)(n0 + srow) * K + col8;
    unsigned short* aL = As + wid * 512;
    unsigned short* bL = Bs + wid * 512;

    f32x4 acc[4][2] = {};

    for (int k0 = 0; k0 < K; k0 += 64) {
        // A: 64 rows (rows srow, srow+32; row&7 invariant under +32)
        gload16(aG + k0, aL);
        gload16(aG + (size_t)32 * lda + k0, aL + 2048);
        // B: 128 rows (srow, +32, +64, +96)
#pragma unroll
        for (int i = 0; i < 4; ++i)
            gload16(bG + (size_t)(i * 32) * K + k0, bL + i * 2048);
        __syncthreads();
#pragma unroll
        for (int kk = 0; kk < 2; ++kk) {
            const int slot = ((kk * 4 + lg) ^ (lr & 7)) * 8;
            bf16x8 aF[4], bF[2];
#pragma unroll
            for (int mi = 0; mi < 4; ++mi)
                aF[mi] = *(const bf16x8*)&As[(mi * 16 + lr) * 64 + slot];
#pragma unroll
            for (int ni = 0; ni < 2; ++ni)
                bF[ni] = *(const bf16x8*)&Bs[(wid * 32 + ni * 16 + lr) * 64 + slot];
#pragma unroll
            for (int mi = 0; mi < 4; ++mi)
#pragma unroll
                for (int ni = 0; ni < 2; ++ni)
                    acc[mi][ni] = __builtin_amdgcn_mfma_f32_16x16x32_bf16(aF[mi], bF[ni], acc[mi][ni], 0, 0, 0);
        }
        __syncthreads();
    }
#pragma unroll
    for (int mi = 0; mi < 4; ++mi)
#pragma unroll
        for (int ni = 0; ni < 2; ++ni) {
            int row = m0 + mi * 16 + lg * 4;
            int col = n0 + wid * 32 + ni * 16 + lr;
#pragma unroll
            for (int r = 0; r < 4; ++r) {
                size_t idx = (size_t)(row + r) * N + col;
                float v = acc[mi][ni][r];
                if (addsrc) v += addsrc[idx];
                if (Cb) Cb[idx] = f2bf(v);
                else    Cf[idx] = v;
            }
        }
}

// ---------------- GEMM 256^2 8-phase (T1+T2+T3+T4+T5) ----------------
__global__ __launch_bounds__(512) void gemm8(const unsigned short* __restrict__ A,
                                             const unsigned short* __restrict__ Bt,
                                             float* __restrict__ Cf,
                                             unsigned short* __restrict__ Cb,
                                             int N, int K) {
    __shared__ unsigned short ldsbuf[65536];
    const int NT = K >> 6;
    int tid = threadIdx.x;
    int lane = tid & 63;
    int wid = tid >> 6;
    int wm = wid >> 2, wn = wid & 3;
    int lr = lane & 15, lg = lane >> 4;
    int wl = blockIdx.x * gridDim.y + blockIdx.y;
    const int m0 = (wl & 7) * 256, n0 = (wl >> 3) * 256;

    unsigned lds0 = (unsigned)(size_t)(__attribute__((address_space(3))) unsigned short*)ldsbuf;
    const unsigned xoff = (unsigned)((lg ^ ((lr >> 1) & 3)) * 16);
    const int gsw = (lane & 3) ^ ((lane >> 3) & 3);
    const int srow = wid * 16 + (lane >> 2);

#define STAGE(buf, ab, s, t) do {                                                   \
        const unsigned short* _src = (ab) ? Bt : A;                                 \
        int _r0 = (ab) ? n0 : m0;                                                   \
        unsigned short* _l = ldsbuf + (((buf) * 2 + (ab)) * 2 + (s)) * 8192 + wid * 512; \
        const unsigned short* _g = _src + (size_t)(_r0 + srow) * K + (size_t)(t) * 64 + (s) * 32 + gsw * 8; \
        gload16(_g, _l);                                                            \
        gload16(_g + (size_t)128 * K, _l + 4096);                                   \
    } while (0)

    f32x4 acc[8][4] = {};

    STAGE(0, 0, 0, 0); STAGE(0, 1, 0, 0);
    STAGE(0, 0, 1, 0); STAGE(0, 1, 1, 0);
    STAGE(1, 0, 0, 1); STAGE(1, 1, 0, 1);
    WAITV(8);
    BAR();

    for (int t = 0; t < NT; ++t) {
        int buf = t & 1;
        unsigned aBase = lds0 + (unsigned)(buf * 65536) + (unsigned)((wm * 128 + lr) * 64) + xoff;
        unsigned bBase = lds0 + (unsigned)(buf * 65536 + 32768) + (unsigned)((wn * 64 + lr) * 64) + xoff;
        Frag aF[4], bF[4];
#pragma unroll
        for (int s = 0; s < 2; ++s) {
#pragma unroll
            for (int ni = 0; ni < 4; ++ni)
                bF[ni].f = lds_read_b128(bBase + (unsigned)(s * 16384 + ni * 1024));
#pragma unroll
            for (int mi = 0; mi < 4; ++mi)
                aF[mi].f = lds_read_b128(aBase + (unsigned)(s * 16384 + mi * 1024));
            if (s == 0) { if (t + 1 < NT) STAGE(buf ^ 1, 0, 1, t + 1); }
            else        { if (t + 2 < NT) STAGE(buf,     0, 0, t + 2); }
            BAR();
            LGKM0();
            __builtin_amdgcn_s_setprio(1);
#pragma unroll
            for (int mi = 0; mi < 4; ++mi)
#pragma unroll
                for (int ni = 0; ni < 4; ++ni)
                    acc[mi][ni] = __builtin_amdgcn_mfma_f32_16x16x32_bf16(aF[mi].h, bF[ni].h, acc[mi][ni], 0, 0, 0);
            __builtin_amdgcn_s_setprio(0);
            BAR();
#pragma unroll
            for (int mi = 0; mi < 4; ++mi)
                aF[mi].f = lds_read_b128(aBase + (unsigned)(4096 + s * 16384 + mi * 1024));
            if (s == 0) { if (t + 1 < NT) STAGE(buf ^ 1, 1, 1, t + 1); }
            else        { if (t + 2 < NT) STAGE(buf,     1, 0, t + 2); }
            BAR();
            LGKM0();
            __builtin_amdgcn_s_setprio(1);
#pragma unroll
            for (int mi = 0; mi < 4; ++mi)
#pragma unroll
                for (int ni = 0; ni < 4; ++ni)
                    acc[4 + mi][ni] = __builtin_amdgcn_mfma_f32_16x16x32_bf16(aF[mi].h, bF[ni].h, acc[4 + mi][ni], 0, 0, 0);
            __builtin_amdgcn_s_setprio(0);
            if (s == 0) {
                if (t + 1 < NT) { WAITV(8); } else { WAITV(0); }
            } else {
                if (t + 2 < NT)      { WAITV(8); }
                else if (t + 1 < NT) { WAITV(4); }
            }
            BAR();
        }
    }
#undef STAGE

#pragma unroll
    for (int mi = 0; mi < 8; ++mi)
#pragma unroll
        for (int ni = 0; ni < 4; ++ni) {
            int row = m0 + wm * 128 + mi * 16 + lg * 4;
            int col = n0 + wn * 64 + ni * 16 + lr;
#pragma unroll
            for (int r = 0; r < 4; ++r) {
                size_t idx = (size_t)(row + r) * N + col;
                float v = acc[mi][ni][r];
                if (Cb) Cb[idx] = f2bf(v);
                else    Cf[idx] = v;
            }
        }
}

// ---------------- RoPE on fused qkv f32 [S][2048]; 4 s-positions per block ----------------
__global__ __launch_bounds__(256) void rope_kernel(const float* __restrict__ qkv,
                                                   const float* __restrict__ fc,
                                                   const float* __restrict__ fs,
                                                   unsigned short* __restrict__ qb,
                                                   unsigned short* __restrict__ kb,
                                                   unsigned short* __restrict__ vb,
                                                   float* __restrict__ out, int layer) {
    const size_t LOGITS = (size_t)S_LEN * 32000;
    int s = blockIdx.x * 4 + (threadIdx.x >> 6);
    int hh = blockIdx.y;
    int lane = threadIdx.x & 63;
    const float* base = qkv + (size_t)s * 2048;
    if (hh < NH) {
        if (lane < 32) {
            const float* row = base + hh * HD;
            float2 x2 = *(const float2*)&row[2 * lane];
            float c = fc[s * 32 + lane], sn = fs[s * 32 + lane];
            size_t o = (size_t)s * (NH * HD) + hh * HD + lane;
            qb[o] = f2bf(x2.x * c - x2.y * sn);
            qb[o + 32] = f2bf(x2.x * sn + x2.y * c);
        }
    } else if (hh < NH + NKV) {
        int kh = hh - NH;
        if (lane < 32) {
            const float* row = base + 1024 + kh * HD;
            float2 x2 = *(const float2*)&row[2 * lane];
            float c = fc[s * 32 + lane], sn = fs[s * 32 + lane];
            float o0 = x2.x * c - x2.y * sn, o1 = x2.x * sn + x2.y * c;
            size_t o = (size_t)s * (NKV * HD) + kh * HD + lane;
            kb[o] = f2bf(o0);
            kb[o + 32] = f2bf(o1);
            if (s == S_LEN - 1) {
                float* kn = out + LOGITS + (size_t)layer * (NKV * HD) + kh * HD;
                kn[lane] = o0; kn[lane + 32] = o1;
            }
        }
    } else {
        int vh = hh - NH - NKV;
        const float* row = base + 1536 + vh * HD;
        float val = row[lane];
        vb[(size_t)s * (NKV * HD) + vh * HD + lane] = f2bf(val);
        if (s == S_LEN - 1)
            out[LOGITS + (size_t)2 * (NKV * HD) + (size_t)layer * (NKV * HD) + vh * HD + lane] = val;
    }
}

// ---------------- flash attention: 8-wave GQA blocks, LDS-staged K/V, double-buffered ----------------
// grid (NKV, S/64). Block: kvh = bx, 64 q-rows = by*64; wave w: qsub=w>>1, head = kvh*2+(w&1).
__global__ __launch_bounds__(512) void attn_kernel(const unsigned short* __restrict__ qb,
                                                   const unsigned short* __restrict__ kb,
                                                   const unsigned short* __restrict__ vT,
                                                   unsigned short* __restrict__ yb) {
    __shared__ unsigned short Klds[2][4096];   // [buf][key_local*64 + swizzled d]
    __shared__ unsigned short Vlds[2][4096];   // [buf][d*64 + swizzled key_local]
    __shared__ unsigned short P[8][16 * 72];
    int kvh = blockIdx.x;
    int qt64 = blockIdx.y;
    int tid = threadIdx.x;
    int lane = tid & 63;
    int w = tid >> 6;
    int hq = w & 1, qsub = w >> 1;
    int h = kvh * 2 + hq;
    int lr = lane & 15, lg = lane >> 4;
    int qbase = qt64 * 64 + qsub * 16;
    int qrow = qbase + lr;

    // staging: thread t covers row sr = t>>3 (8 rows/wave), granule sg = t&7; pre-swizzled src col
    const int sr = tid >> 3;
    const int scol8 = (((tid & 7) ^ ((tid >> 3) & 7)) * 8);
    const int NT = qt64 + 1;

#define STAGEKV(buf, kt) do { \
        gload16(&kb[(size_t)((kt) * 64 + sr) * (NKV * HD) + kvh * 64 + scol8], &Klds[buf][w * 512]); \
        gload16(&vT[(size_t)(kvh * 64 + sr) * 2048 + (kt) * 64 + scol8], &Vlds[buf][w * 512]); \
    } while (0)

    bf16x8 bq[2];
#pragma unroll
    for (int c = 0; c < 2; ++c)
        bq[c] = *(const bf16x8*)&qb[(size_t)qrow * (NH * HD) + h * HD + c * 32 + lg * 8];

    f32x4 O[4] = {};
    float mstate = -1e30f, lstate = 0.f;

    STAGEKV(0, 0);
    WAITV(0);
    BAR();

    for (int kt = 0; kt < NT; ++kt) {
        int buf = kt & 1;
        if (kt + 1 < NT) STAGEKV(buf ^ 1, kt + 1);
        // swapped QK^T: lane holds S[q=lr][key = kt*64 + kc*16 + lg*4 + r]
        f32x4 s[4];
#pragma unroll
        for (int kc = 0; kc < 4; ++kc) {
            int krl = kc * 16 + lr;
            const unsigned short* kp = &Klds[buf][krl * 64];
            bf16x8 ak0 = *(const bf16x8*)&kp[((lg ^ (lr & 7)) * 8)];
            bf16x8 ak1 = *(const bf16x8*)&kp[(((4 + lg) ^ (lr & 7)) * 8)];
            f32x4 z = {};
            z = __builtin_amdgcn_mfma_f32_16x16x32_bf16(ak0, bq[0], z, 0, 0, 0);
            z = __builtin_amdgcn_mfma_f32_16x16x32_bf16(ak1, bq[1], z, 0, 0, 0);
            s[kc] = z;
        }
        float tm = -1e30f;
#pragma unroll
        for (int kc = 0; kc < 4; ++kc)
#pragma unroll
            for (int r = 0; r < 4; ++r) {
                int key = kt * 64 + kc * 16 + lg * 4 + r;
                float val = s[kc][r] * 0.125f;
                if (key > qrow) val = -1e30f;
                s[kc][r] = val;
                tm = fmaxf(tm, val);
            }
        tm = fmaxf(tm, __shfl_xor(tm, 16));
        tm = fmaxf(tm, __shfl_xor(tm, 32));
        float mn = fmaxf(mstate, tm);
        float sc = __expf(mstate - mn);
        float rs = 0.f;
        ushort4v pk[4];
#pragma unroll
        for (int kc = 0; kc < 4; ++kc)
#pragma unroll
            for (int r = 0; r < 4; ++r) {
                float pf = __expf(s[kc][r] - mn);
                rs += pf;
                pk[kc][r] = f2bf(pf);
            }
        rs += __shfl_xor(rs, 16);
        rs += __shfl_xor(rs, 32);
        lstate = lstate * sc + rs;
        mstate = mn;
        float osc[4];
#pragma unroll
        for (int r = 0; r < 4; ++r)
            osc[r] = __shfl(sc, lg * 4 + r);
#pragma unroll
        for (int n = 0; n < 4; ++n)
#pragma unroll
            for (int r = 0; r < 4; ++r)
                O[n][r] *= osc[r];
        // per-wave P buffer (no cross-wave sharing -> no barrier needed)
#pragma unroll
        for (int kc = 0; kc < 4; ++kc)
            *(ushort4v*)&P[w][lr * 72 + kc * 16 + lg * 4] = pk[kc];
        bf16x8 pa[2];
#pragma unroll
        for (int g = 0; g < 2; ++g)
            pa[g] = *(const bf16x8*)&P[w][lr * 72 + g * 32 + lg * 8];
#pragma unroll
        for (int n = 0; n < 4; ++n) {
            const unsigned short* vp = &Vlds[buf][(n * 16 + lr) * 64];
#pragma unroll
            for (int g = 0; g < 2; ++g) {
                bf16x8 bv = *(const bf16x8*)&vp[(((g * 4 + lg) ^ (lr & 7)) * 8)];
                O[n] = __builtin_amdgcn_mfma_f32_16x16x32_bf16(pa[g], bv, O[n], 0, 0, 0);
            }
        }
        if (kt + 1 < NT) WAITV(0);
        LGKM0();
        BAR();
    }
#undef STAGEKV

    float linv[4];
#pragma unroll
    for (int r = 0; r < 4; ++r)
        linv[r] = 1.f / __shfl(lstate, lg * 4 + r);
#pragma unroll
    for (int n = 0; n < 4; ++n)
#pragma unroll
        for (int r = 0; r < 4; ++r) {
            int row = qbase + lg * 4 + r;
            yb[(size_t)row * (NH * HD) + h * HD + n * 16 + lr] = f2bf(O[n][r] * linv[r]);
        }
}

// ---------------- silu(g)*u in fused gu bf16 [S][5632], in place into g half ----------------
__global__ __launch_bounds__(256) void silu_mul_kernel(unsigned short* __restrict__ gu) {
    size_t idx = (size_t)blockIdx.x * 256 + threadIdx.x;
    int s = (int)(idx / 352);
    int c8 = (int)(idx % 352);
    unsigned short* gp = gu + (size_t)s * 5632 + c8 * 8;
    ushort8v a = *(const ushort8v*)gp;
    ushort8v b = *(const ushort8v*)(gp + 2816);
#pragma unroll
    for (int j = 0; j < 8; ++j) {
        float x = bf2f(a[j]), y = bf2f(b[j]);
        a[j] = f2bf(x / (1.f + __expf(-x)) * y);
    }
    *(ushort8v*)gp = a;
}

extern "C" void kernel_launch(void* const* d_in, const int* in_sizes, int n_in,
                              void* d_out, int out_size, void* d_ws, size_t ws_size,
                              hipStream_t stream) {
    const int* tokens = (const int*)d_in[0];
    const float* freqs_cos = (const float*)d_in[2];
    const float* freqs_sin = (const float*)d_in[3];
    const float* tok_emb = (const float*)d_in[4];
    const float* wq = (const float*)d_in[5];
    const float* wk = (const float*)d_in[6];
    const float* wv = (const float*)d_in[7];
    const float* wo = (const float*)d_in[8];
    const float* attn_norm_w = (const float*)d_in[9];
    const float* ffn_norm_w = (const float*)d_in[10];
    const float* w1 = (const float*)d_in[11];
    const float* w2 = (const float*)d_in[12];
    const float* w3 = (const float*)d_in[13];
    const float* final_norm_w = (const float*)d_in[14];
    const float* out_w = (const float*)d_in[15];
    float* out = (float*)d_out;

    const size_t SD = (size_t)S_LEN * DIM;
    const size_t SKV = (size_t)S_LEN * NKV * HD;

    char* p = (char*)d_ws;
    auto take = [&](size_t bytes) { char* r = p; p += (bytes + 255) & ~(size_t)255; return r; };
    float* h            = (float*)take(SD * 4);
    unsigned short* xnb = (unsigned short*)take(SD * 2);
    char* uni = p;
    float* qkvf         = (float*)uni;                                  // 16 MB
    unsigned short* qb  = (unsigned short*)(uni + 17039360);            // 4 MB
    unsigned short* kb  = qb + SD;                                      // 2 MB
    unsigned short* vb  = kb + SKV;                                     // 2 MB
    unsigned short* vT  = vb + SKV;                                     // 2 MB
    unsigned short* ybv = vT + SKV;                                     // 4 MB
    unsigned short* gu  = ybv + SD;                                     // 23 MB
    unsigned short* wT  = gu + (size_t)S_LEN * 5632;                    // 11.5 MB
    unsigned short* owT = (unsigned short*)uni;                         // 65.5 MB (final phase)

    embed_kernel<<<S_LEN, 256, 0, stream>>>(tokens, tok_emb, h);
    for (int l = 0; l < 2; ++l) {
        rmsnorm_kernel<<<S_LEN, 256, 0, stream>>>(h, attn_norm_w + l * DIM, xnb);
        transpose_w<<<dim3(16, 16), 256, 0, stream>>>(wq + (size_t)l * DIM * 1024, wT, DIM, 1024);
        transpose_w<<<dim3(8, 16), 256, 0, stream>>>(wk + (size_t)l * DIM * 512, wT + (size_t)1024 * DIM, DIM, 512);
        transpose_w<<<dim3(8, 16), 256, 0, stream>>>(wv + (size_t)l * DIM * 512, wT + (size_t)1536 * DIM, DIM, 512);
        gemm_tn<<<dim3(16, 16), 256, 0, stream>>>(xnb, DIM, wT, qkvf, nullptr, nullptr, 2048, DIM);
        rope_kernel<<<dim3(S_LEN / 4, 32), 256, 0, stream>>>(qkvf, freqs_cos, freqs_sin, qb, kb, vb, out, l);
        transpose_v<<<dim3(8, 32), 256, 0, stream>>>(vb, vT);
        attn_kernel<<<dim3(NKV, S_LEN / 64), 512, 0, stream>>>(qb, kb, vT, ybv);
        transpose_w<<<dim3(16, 16), 256, 0, stream>>>(wo + (size_t)l * 1024 * DIM, wT, 1024, DIM);
        gemm_tn64<<<dim3(32, 8), 256, 0, stream>>>(ybv, 1024, wT, h, nullptr, h, DIM, 1024);
        rmsnorm_kernel<<<S_LEN, 256, 0, stream>>>(h, ffn_norm_w + l * DIM, xnb);
        transpose_w<<<dim3(44, 16), 256, 0, stream>>>(w1 + (size_t)l * DIM * HID, wT, DIM, HID);
        transpose_w<<<dim3(44, 16), 256, 0, stream>>>(w3 + (size_t)l * DIM * HID, wT + (size_t)HID * DIM, DIM, HID);
        gemm8<<<dim3(8, 22), 512, 0, stream>>>(xnb, wT, nullptr, gu, 5632, DIM);
        silu_mul_kernel<<<(S_LEN * 352) / 256, 256, 0, stream>>>(gu);
        transpose_w<<<dim3(16, 44), 256, 0, stream>>>(w2 + (size_t)l * HID * 1024, wT, HID, 1024);
        gemm_tn64<<<dim3(32, 8), 256, 0, stream>>>(gu, 5632, wT, h, nullptr, h, DIM, HID);
    }
    rmsnorm_kernel<<<S_LEN, 256, 0, stream>>>(h, final_norm_w, xnb);
    transpose_w<<<dim3(500, 16), 256, 0, stream>>>(out_w, owT, DIM, 32000);
    gemm8<<<dim3(8, 125), 512, 0, stream>>>(xnb, owT, out, nullptr, 32000, DIM);
}

// Round 8
// 669.548 us; speedup vs baseline: 1.4303x; 1.0283x over previous
//
#include <hip/hip_runtime.h>
#include <hip/hip_bf16.h>

typedef __bf16 bf16x8 __attribute__((ext_vector_type(8)));
typedef float f32x4 __attribute__((ext_vector_type(4)));
typedef unsigned short ushort4v __attribute__((ext_vector_type(4)));
typedef unsigned short ushort8v __attribute__((ext_vector_type(8)));

#define S_LEN 2048
#define DIM 1024
#define NH 16
#define NKV 8
#define HD 64
#define HID 2816
#define LOGITS ((size_t)S_LEN * 32000)

__device__ __forceinline__ unsigned short f2bf(float f) {
    union { float f; unsigned u; } v; v.f = f;
    unsigned r = v.u + 0x7fffu + ((v.u >> 16) & 1u);   // RNE
    return (unsigned short)(r >> 16);
}
__device__ __forceinline__ float bf2f(unsigned short u) {
    union { unsigned u; float f; } v; v.u = (unsigned)u << 16; return v.f;
}

__device__ __forceinline__ void gload16(const unsigned short* g, unsigned short* l) {
    __builtin_amdgcn_global_load_lds(
        (const __attribute__((address_space(1))) unsigned int*)g,
        (__attribute__((address_space(3))) unsigned int*)l,
        16, 0, 0);
}

union Frag { f32x4 f; bf16x8 h; };

__device__ __forceinline__ f32x4 lds_read_b128(unsigned addr) {
    f32x4 d;
    asm volatile("ds_read_b128 %0, %1" : "=v"(d) : "v"(addr));
    return d;
}

#define BAR()  asm volatile("s_barrier" ::: "memory")
#define WAITV(n) asm volatile("s_waitcnt vmcnt(" #n ")" ::: "memory")
#define LGKM0() do { asm volatile("s_waitcnt lgkmcnt(0)" ::: "memory"); __builtin_amdgcn_sched_barrier(0); } while (0)

// ---------------- embedding gather ----------------
__global__ __launch_bounds__(256) void embed_kernel(const int* __restrict__ tokens,
                                                    const float* __restrict__ emb,
                                                    float* __restrict__ h) {
    int s = blockIdx.x;
    int t = tokens[s];
    float4 v = *(const float4*)&emb[(size_t)t * DIM + threadIdx.x * 4];
    *(float4*)&h[(size_t)s * DIM + threadIdx.x * 4] = v;
}

// ---------------- rmsnorm: f32 in -> bf16 out ----------------
__global__ __launch_bounds__(256) void rmsnorm_kernel(const float* __restrict__ x,
                                                      const float* __restrict__ w,
                                                      unsigned short* __restrict__ out) {
    __shared__ float sred[4];
    int s = blockIdx.x;
    int tid = threadIdx.x;
    float4 v = *(const float4*)&x[(size_t)s * DIM + tid * 4];
    float ss = v.x * v.x + v.y * v.y + v.z * v.z + v.w * v.w;
#pragma unroll
    for (int off = 32; off; off >>= 1) ss += __shfl_down(ss, off);
    if ((tid & 63) == 0) sred[tid >> 6] = ss;
    __syncthreads();
    float tot = sred[0] + sred[1] + sred[2] + sred[3];
    float scale = rsqrtf(tot * (1.0f / DIM) + 1e-5f);
    float4 wv = *(const float4*)&w[tid * 4];
    ushort4v o;
    o[0] = f2bf(v.x * scale * wv.x); o[1] = f2bf(v.y * scale * wv.y);
    o[2] = f2bf(v.z * scale * wv.z); o[3] = f2bf(v.w * scale * wv.w);
    *(ushort4v*)&out[(size_t)s * DIM + tid * 4] = o;
}

// ---------------- transpose body: f32 [K][N] tile -> bf16 [rowMul*n+rowOff][K] ----------------
__device__ __forceinline__ void tpose_body(const float* __restrict__ in,
                                           unsigned short* __restrict__ out,
                                           int K, int N, int n0, int k0,
                                           int rowMul, int rowOff) {
    __shared__ unsigned short t[64][68];
    int tid = threadIdx.x;
    int tn = tid & 15, tk = tid >> 4;
#pragma unroll
    for (int p = 0; p < 4; ++p) {
        int k = tk + p * 16;
        float4 v = *(const float4*)&in[(size_t)(k0 + k) * N + n0 + tn * 4];
        t[tn * 4 + 0][k] = f2bf(v.x);
        t[tn * 4 + 1][k] = f2bf(v.y);
        t[tn * 4 + 2][k] = f2bf(v.z);
        t[tn * 4 + 3][k] = f2bf(v.w);
    }
    __syncthreads();
    int wk = tid & 15, wn = tid >> 4;
#pragma unroll
    for (int p = 0; p < 4; ++p) {
        int n = wn + p * 16;
        ushort4v v;
        v[0] = t[n][wk * 4]; v[1] = t[n][wk * 4 + 1];
        v[2] = t[n][wk * 4 + 2]; v[3] = t[n][wk * 4 + 3];
        *(ushort4v*)&out[(size_t)(rowMul * (n0 + n) + rowOff) * K + k0 + wk * 4] = v;
    }
}

__global__ __launch_bounds__(256) void transpose_w(const float* __restrict__ in,
                                                   unsigned short* __restrict__ out,
                                                   int K, int N) {
    tpose_body(in, out, K, N, blockIdx.x * 64, blockIdx.y * 64, 1, 0);
}

// qkv fused: z=0 wq (N=1024, rows 0..1023), z=1 wk (N=512, rows 1024..), z=2 wv (rows 1536..)
__global__ __launch_bounds__(256) void transpose_qkv(const float* __restrict__ wq,
                                                     const float* __restrict__ wk,
                                                     const float* __restrict__ wv,
                                                     unsigned short* __restrict__ out) {
    int z = blockIdx.z;
    if (z > 0 && blockIdx.x >= 8) return;
    const float* in = z == 0 ? wq : (z == 1 ? wk : wv);
    int N = z == 0 ? 1024 : 512;
    int rowOff = z == 0 ? 0 : (z == 1 ? 1024 : 1536);
    tpose_body(in, out, DIM, N, blockIdx.x * 64, blockIdx.y * 64, 1, rowOff);
}

// w1|w3 interleaved: out row 2j = w1 col j, row 2j+1 = w3 col j
__global__ __launch_bounds__(256) void transpose_w13(const float* __restrict__ w1,
                                                     const float* __restrict__ w3,
                                                     unsigned short* __restrict__ out) {
    int z = blockIdx.z;
    tpose_body(z ? w3 : w1, out, DIM, HID, blockIdx.x * 64, blockIdx.y * 64, 2, z);
}

// ---------------- V transpose from qkvf f32 (cols 1536..2047) -> vT bf16 [512][2048]; emits v_news ----------------
__global__ __launch_bounds__(256) void transpose_vf(const float* __restrict__ qkvf,
                                                    unsigned short* __restrict__ vT,
                                                    float* __restrict__ out, int layer) {
    __shared__ unsigned short t[64][72];
    int c0 = blockIdx.x * 64, s0 = blockIdx.y * 64;
    int tid = threadIdx.x;
    int tc = tid & 15, ts = tid >> 4;
#pragma unroll
    for (int p = 0; p < 4; ++p) {
        int s = ts + p * 16;
        float4 v = *(const float4*)&qkvf[(size_t)(s0 + s) * 2048 + 1536 + c0 + tc * 4];
        t[tc * 4 + 0][s] = f2bf(v.x);
        t[tc * 4 + 1][s] = f2bf(v.y);
        t[tc * 4 + 2][s] = f2bf(v.z);
        t[tc * 4 + 3][s] = f2bf(v.w);
        if (s0 + s == S_LEN - 1) {
            float* vn = out + LOGITS + 2 * (NKV * HD) + (size_t)layer * (NKV * HD) + c0 + tc * 4;
            vn[0] = v.x; vn[1] = v.y; vn[2] = v.z; vn[3] = v.w;
        }
    }
    __syncthreads();
    int ws_ = tid & 15, wc = tid >> 4;
#pragma unroll
    for (int p = 0; p < 4; ++p) {
        int c = wc + p * 16;
        ushort4v v;
        v[0] = t[c][ws_ * 4]; v[1] = t[c][ws_ * 4 + 1];
        v[2] = t[c][ws_ * 4 + 2]; v[3] = t[c][ws_ * 4 + 3];
        *(ushort4v*)&vT[(size_t)(c0 + c) * 2048 + s0 + ws_ * 4] = v;
    }
}

// ---------------- GEMM 128^2, swizzled LDS: A bf16 [M][lda], Bt bf16 [N][K] ----------------
__global__ __launch_bounds__(256) void gemm_tn(const unsigned short* __restrict__ A, int lda,
                                               const unsigned short* __restrict__ Bt,
                                               float* __restrict__ Cf,
                                               unsigned short* __restrict__ Cb,
                                               const float* __restrict__ addsrc,
                                               int N, int K) {
    __shared__ unsigned short As[128 * 64];
    __shared__ unsigned short Bs[128 * 64];
    int tid = threadIdx.x;
    int lane = tid & 63;
    int wid = tid >> 6;
    int wrow = wid >> 1, wcol = wid & 1;
    int lr = lane & 15, lg = lane >> 4;
    const int m0 = blockIdx.x * 128, n0 = blockIdx.y * 128;

    const int col8 = (((lane & 7) ^ ((lane >> 3) & 7)) * 8);
    const unsigned short* aG = A + (size_t)(m0 + wid * 32 + (lane >> 3)) * lda + col8;
    const unsigned short* bG = Bt + (size_t)(n0 + wid * 32 + (lane >> 3)) * K + col8;
    unsigned short* aL = As + wid * 2048;
    unsigned short* bL = Bs + wid * 2048;

    f32x4 acc[4][4] = {};

    for (int k0 = 0; k0 < K; k0 += 64) {
#pragma unroll
        for (int i = 0; i < 4; ++i)
            gload16(aG + (size_t)(i * 8) * lda + k0, aL + i * 512);
#pragma unroll
        for (int i = 0; i < 4; ++i)
            gload16(bG + (size_t)(i * 8) * K + k0, bL + i * 512);
        __syncthreads();
#pragma unroll
        for (int kk = 0; kk < 2; ++kk) {
            const int slot = ((kk * 4 + lg) ^ (lr & 7)) * 8;
            bf16x8 aF[4], bF[4];
#pragma unroll
            for (int mi = 0; mi < 4; ++mi)
                aF[mi] = *(const bf16x8*)&As[(wrow * 64 + mi * 16 + lr) * 64 + slot];
#pragma unroll
            for (int ni = 0; ni < 4; ++ni)
                bF[ni] = *(const bf16x8*)&Bs[(wcol * 64 + ni * 16 + lr) * 64 + slot];
#pragma unroll
            for (int mi = 0; mi < 4; ++mi)
#pragma unroll
                for (int ni = 0; ni < 4; ++ni)
                    acc[mi][ni] = __builtin_amdgcn_mfma_f32_16x16x32_bf16(aF[mi], bF[ni], acc[mi][ni], 0, 0, 0);
        }
        __syncthreads();
    }
#pragma unroll
    for (int mi = 0; mi < 4; ++mi)
#pragma unroll
        for (int ni = 0; ni < 4; ++ni) {
            int row = m0 + wrow * 64 + mi * 16 + lg * 4;
            int col = n0 + wcol * 64 + ni * 16 + lr;
#pragma unroll
            for (int r = 0; r < 4; ++r) {
                size_t idx = (size_t)(row + r) * N + col;
                float v = acc[mi][ni][r];
                if (addsrc) v += addsrc[idx];
                if (Cb) Cb[idx] = f2bf(v);
                else    Cf[idx] = v;
            }
        }
}

// ---------------- GEMM BM=64, BN=128 (for N=1024 outputs: full-chip grid 32x8) ----------------
__global__ __launch_bounds__(256) void gemm_tn64(const unsigned short* __restrict__ A, int lda,
                                                 const unsigned short* __restrict__ Bt,
                                                 float* __restrict__ Cf,
                                                 unsigned short* __restrict__ Cb,
                                                 const float* __restrict__ addsrc,
                                                 int N, int K) {
    __shared__ unsigned short As[64 * 64];
    __shared__ unsigned short Bs[128 * 64];
    int tid = threadIdx.x;
    int lane = tid & 63;
    int wid = tid >> 6;
    int lr = lane & 15, lg = lane >> 4;
    const int m0 = blockIdx.x * 64, n0 = blockIdx.y * 128;

    const int srow = tid >> 3;
    const int col8 = (((tid & 7) ^ ((tid >> 3) & 7)) * 8);
    const unsigned short* aG = A + (size_t)(m0 + srow) * lda + col8;
    const unsigned short* bG = Bt + (size_t)(n0 + srow) * K + col8;
    unsigned short* aL = As + wid * 512;
    unsigned short* bL = Bs + wid * 512;

    f32x4 acc[4][2] = {};

    for (int k0 = 0; k0 < K; k0 += 64) {
        gload16(aG + k0, aL);
        gload16(aG + (size_t)32 * lda + k0, aL + 2048);
#pragma unroll
        for (int i = 0; i < 4; ++i)
            gload16(bG + (size_t)(i * 32) * K + k0, bL + i * 2048);
        __syncthreads();
#pragma unroll
        for (int kk = 0; kk < 2; ++kk) {
            const int slot = ((kk * 4 + lg) ^ (lr & 7)) * 8;
            bf16x8 aF[4], bF[2];
#pragma unroll
            for (int mi = 0; mi < 4; ++mi)
                aF[mi] = *(const bf16x8*)&As[(mi * 16 + lr) * 64 + slot];
#pragma unroll
            for (int ni = 0; ni < 2; ++ni)
                bF[ni] = *(const bf16x8*)&Bs[(wid * 32 + ni * 16 + lr) * 64 + slot];
#pragma unroll
            for (int mi = 0; mi < 4; ++mi)
#pragma unroll
                for (int ni = 0; ni < 2; ++ni)
                    acc[mi][ni] = __builtin_amdgcn_mfma_f32_16x16x32_bf16(aF[mi], bF[ni], acc[mi][ni], 0, 0, 0);
        }
        __syncthreads();
    }
#pragma unroll
    for (int mi = 0; mi < 4; ++mi)
#pragma unroll
        for (int ni = 0; ni < 2; ++ni) {
            int row = m0 + mi * 16 + lg * 4;
            int col = n0 + wid * 32 + ni * 16 + lr;
#pragma unroll
            for (int r = 0; r < 4; ++r) {
                size_t idx = (size_t)(row + r) * N + col;
                float v = acc[mi][ni][r];
                if (addsrc) v += addsrc[idx];
                if (Cb) Cb[idx] = f2bf(v);
                else    Cf[idx] = v;
            }
        }
}

// ---------------- GEMM 256^2 8-phase (T1+T2+T3+T4+T5); FUSE=1: silu(even)*odd -> bf16 [.][2816] ----------------
template<int FUSE>
__global__ __launch_bounds__(512) void gemm8(const unsigned short* __restrict__ A,
                                             const unsigned short* __restrict__ Bt,
                                             float* __restrict__ Cf,
                                             unsigned short* __restrict__ Cb,
                                             int N, int K) {
    __shared__ unsigned short ldsbuf[65536];
    const int NT = K >> 6;
    int tid = threadIdx.x;
    int lane = tid & 63;
    int wid = tid >> 6;
    int wm = wid >> 2, wn = wid & 3;
    int lr = lane & 15, lg = lane >> 4;
    int wl = blockIdx.x * gridDim.y + blockIdx.y;
    const int m0 = (wl & 7) * 256, n0 = (wl >> 3) * 256;

    unsigned lds0 = (unsigned)(size_t)(__attribute__((address_space(3))) unsigned short*)ldsbuf;
    const unsigned xoff = (unsigned)((lg ^ ((lr >> 1) & 3)) * 16);
    const int gsw = (lane & 3) ^ ((lane >> 3) & 3);
    const int srow = wid * 16 + (lane >> 2);

#define STAGE(buf, ab, s, t) do {                                                   \
        const unsigned short* _src = (ab) ? Bt : A;                                 \
        int _r0 = (ab) ? n0 : m0;                                                   \
        unsigned short* _l = ldsbuf + (((buf) * 2 + (ab)) * 2 + (s)) * 8192 + wid * 512; \
        const unsigned short* _g = _src + (size_t)(_r0 + srow) * K + (size_t)(t) * 64 + (s) * 32 + gsw * 8; \
        gload16(_g, _l);                                                            \
        gload16(_g + (size_t)128 * K, _l + 4096);                                   \
    } while (0)

    f32x4 acc[8][4] = {};

    STAGE(0, 0, 0, 0); STAGE(0, 1, 0, 0);
    STAGE(0, 0, 1, 0); STAGE(0, 1, 1, 0);
    STAGE(1, 0, 0, 1); STAGE(1, 1, 0, 1);
    WAITV(8);
    BAR();

    for (int t = 0; t < NT; ++t) {
        int buf = t & 1;
        unsigned aBase = lds0 + (unsigned)(buf * 65536) + (unsigned)((wm * 128 + lr) * 64) + xoff;
        unsigned bBase = lds0 + (unsigned)(buf * 65536 + 32768) + (unsigned)((wn * 64 + lr) * 64) + xoff;
        Frag aF[4], bF[4];
#pragma unroll
        for (int s = 0; s < 2; ++s) {
#pragma unroll
            for (int ni = 0; ni < 4; ++ni)
                bF[ni].f = lds_read_b128(bBase + (unsigned)(s * 16384 + ni * 1024));
#pragma unroll
            for (int mi = 0; mi < 4; ++mi)
                aF[mi].f = lds_read_b128(aBase + (unsigned)(s * 16384 + mi * 1024));
            if (s == 0) { if (t + 1 < NT) STAGE(buf ^ 1, 0, 1, t + 1); }
            else        { if (t + 2 < NT) STAGE(buf,     0, 0, t + 2); }
            BAR();
            LGKM0();
            __builtin_amdgcn_s_setprio(1);
#pragma unroll
            for (int mi = 0; mi < 4; ++mi)
#pragma unroll
                for (int ni = 0; ni < 4; ++ni)
                    acc[mi][ni] = __builtin_amdgcn_mfma_f32_16x16x32_bf16(aF[mi].h, bF[ni].h, acc[mi][ni], 0, 0, 0);
            __builtin_amdgcn_s_setprio(0);
            BAR();
#pragma unroll
            for (int mi = 0; mi < 4; ++mi)
                aF[mi].f = lds_read_b128(aBase + (unsigned)(4096 + s * 16384 + mi * 1024));
            if (s == 0) { if (t + 1 < NT) STAGE(buf ^ 1, 1, 1, t + 1); }
            else        { if (t + 2 < NT) STAGE(buf,     1, 0, t + 2); }
            BAR();
            LGKM0();
            __builtin_amdgcn_s_setprio(1);
#pragma unroll
            for (int mi = 0; mi < 4; ++mi)
#pragma unroll
                for (int ni = 0; ni < 4; ++ni)
                    acc[4 + mi][ni] = __builtin_amdgcn_mfma_f32_16x16x32_bf16(aF[mi].h, bF[ni].h, acc[4 + mi][ni], 0, 0, 0);
            __builtin_amdgcn_s_setprio(0);
            if (s == 0) {
                if (t + 1 < NT) { WAITV(8); } else { WAITV(0); }
            } else {
                if (t + 2 < NT)      { WAITV(8); }
                else if (t + 1 < NT) { WAITV(4); }
            }
            BAR();
        }
    }
#undef STAGE

#pragma unroll
    for (int mi = 0; mi < 8; ++mi)
#pragma unroll
        for (int ni = 0; ni < 4; ++ni) {
            int row = m0 + wm * 128 + mi * 16 + lg * 4;
            int col = n0 + wn * 64 + ni * 16 + lr;
#pragma unroll
            for (int r = 0; r < 4; ++r) {
                float v = acc[mi][ni][r];
                if (FUSE) {
                    float o = __shfl_xor(v, 1);
                    if (!(lr & 1)) {
                        float res = v / (1.f + __expf(-v)) * o;
                        Cb[(size_t)(row + r) * (HID) + (col >> 1)] = f2bf(res);
                    }
                } else {
                    Cf[(size_t)(row + r) * N + col] = v;
                }
            }
        }
}

// ---------------- RoPE on fused qkv f32 [S][2048]; q + k only (v handled by transpose_vf) ----------------
__global__ __launch_bounds__(256) void rope_kernel(const float* __restrict__ qkv,
                                                   const float* __restrict__ fc,
                                                   const float* __restrict__ fs,
                                                   unsigned short* __restrict__ qb,
                                                   unsigned short* __restrict__ kb,
                                                   float* __restrict__ out, int layer) {
    int s = blockIdx.x * 4 + (threadIdx.x >> 6);
    int hh = blockIdx.y;
    int lane = threadIdx.x & 63;
    if (lane >= 32) return;
    const float* base = qkv + (size_t)s * 2048;
    if (hh < NH) {
        const float* row = base + hh * HD;
        float2 x2 = *(const float2*)&row[2 * lane];
        float c = fc[s * 32 + lane], sn = fs[s * 32 + lane];
        size_t o = (size_t)s * (NH * HD) + hh * HD + lane;
        qb[o] = f2bf(x2.x * c - x2.y * sn);
        qb[o + 32] = f2bf(x2.x * sn + x2.y * c);
    } else {
        int kh = hh - NH;
        const float* row = base + 1024 + kh * HD;
        float2 x2 = *(const float2*)&row[2 * lane];
        float c = fc[s * 32 + lane], sn = fs[s * 32 + lane];
        float o0 = x2.x * c - x2.y * sn, o1 = x2.x * sn + x2.y * c;
        size_t o = (size_t)s * (NKV * HD) + kh * HD + lane;
        kb[o] = f2bf(o0);
        kb[o + 32] = f2bf(o1);
        if (s == S_LEN - 1) {
            float* kn = out + LOGITS + (size_t)layer * (NKV * HD) + kh * HD;
            kn[lane] = o0; kn[lane + 32] = o1;
        }
    }
}

// ---------------- flash attention: 4-wave blocks, 32 q-rows, balanced big-first grid ----------------
// grid (NKV, 64). strip = 63 - by (32 q-rows each); wave w: head kvh*2+(w&1), qsub w>>1.
__global__ __launch_bounds__(256) void attn_kernel(const unsigned short* __restrict__ qb,
                                                   const unsigned short* __restrict__ kb,
                                                   const unsigned short* __restrict__ vT,
                                                   unsigned short* __restrict__ yb) {
    __shared__ unsigned short Klds[2][4096];
    __shared__ unsigned short Vlds[2][4096];
    __shared__ unsigned short P[4][16 * 72];
    int kvh = blockIdx.x;
    int strip = 63 - blockIdx.y;         // heaviest blocks dispatch first
    int tid = threadIdx.x;
    int lane = tid & 63;
    int w = tid >> 6;
    int hq = w & 1, qsub = w >> 1;
    int h = kvh * 2 + hq;
    int lr = lane & 15, lg = lane >> 4;
    int qbase = strip * 32 + qsub * 16;
    int qrow = qbase + lr;

    const int sr = tid >> 3;             // 0..31
    const int scol8 = (((tid & 7) ^ (sr & 7)) * 8);
    const int NT = (strip >> 1) + 1;

#define STAGEKV(buf, kt) do { \
        gload16(&kb[(size_t)((kt) * 64 + sr) * 512 + kvh * 64 + scol8], &Klds[buf][w * 512]); \
        gload16(&kb[(size_t)((kt) * 64 + sr + 32) * 512 + kvh * 64 + scol8], &Klds[buf][2048 + w * 512]); \
        gload16(&vT[(size_t)(kvh * 64 + sr) * 2048 + (kt) * 64 + scol8], &Vlds[buf][w * 512]); \
        gload16(&vT[(size_t)(kvh * 64 + sr + 32) * 2048 + (kt) * 64 + scol8], &Vlds[buf][2048 + w * 512]); \
    } while (0)

    bf16x8 bq[2];
#pragma unroll
    for (int c = 0; c < 2; ++c)
        bq[c] = *(const bf16x8*)&qb[(size_t)qrow * (NH * HD) + h * HD + c * 32 + lg * 8];

    f32x4 O[4] = {};
    float mstate = -1e30f, lstate = 0.f;

    STAGEKV(0, 0);
    WAITV(0);
    BAR();

    for (int kt = 0; kt < NT; ++kt) {
        int buf = kt & 1;
        if (kt + 1 < NT) STAGEKV(buf ^ 1, kt + 1);
        f32x4 s[4];
#pragma unroll
        for (int kc = 0; kc < 4; ++kc) {
            int krl = kc * 16 + lr;
            const unsigned short* kp = &Klds[buf][krl * 64];
            bf16x8 ak0 = *(const bf16x8*)&kp[((lg ^ (lr & 7)) * 8)];
            bf16x8 ak1 = *(const bf16x8*)&kp[(((4 + lg) ^ (lr & 7)) * 8)];
            f32x4 z = {};
            z = __builtin_amdgcn_mfma_f32_16x16x32_bf16(ak0, bq[0], z, 0, 0, 0);
            z = __builtin_amdgcn_mfma_f32_16x16x32_bf16(ak1, bq[1], z, 0, 0, 0);
            s[kc] = z;
        }
        float tm = -1e30f;
#pragma unroll
        for (int kc = 0; kc < 4; ++kc)
#pragma unroll
            for (int r = 0; r < 4; ++r) {
                int key = kt * 64 + kc * 16 + lg * 4 + r;
                float val = s[kc][r] * 0.125f;
                if (key > qrow) val = -1e30f;
                s[kc][r] = val;
                tm = fmaxf(tm, val);
            }
        tm = fmaxf(tm, __shfl_xor(tm, 16));
        tm = fmaxf(tm, __shfl_xor(tm, 32));
        float mn = fmaxf(mstate, tm);
        float sc = __expf(mstate - mn);
        float rs = 0.f;
        ushort4v pk[4];
#pragma unroll
        for (int kc = 0; kc < 4; ++kc)
#pragma unroll
            for (int r = 0; r < 4; ++r) {
                float pf = __expf(s[kc][r] - mn);
                rs += pf;
                pk[kc][r] = f2bf(pf);
            }
        rs += __shfl_xor(rs, 16);
        rs += __shfl_xor(rs, 32);
        lstate = lstate * sc + rs;
        mstate = mn;
        float osc[4];
#pragma unroll
        for (int r = 0; r < 4; ++r)
            osc[r] = __shfl(sc, lg * 4 + r);
#pragma unroll
        for (int n = 0; n < 4; ++n)
#pragma unroll
            for (int r = 0; r < 4; ++r)
                O[n][r] *= osc[r];
#pragma unroll
        for (int kc = 0; kc < 4; ++kc)
            *(ushort4v*)&P[w][lr * 72 + kc * 16 + lg * 4] = pk[kc];
        bf16x8 pa[2];
#pragma unroll
        for (int g = 0; g < 2; ++g)
            pa[g] = *(const bf16x8*)&P[w][lr * 72 + g * 32 + lg * 8];
#pragma unroll
        for (int n = 0; n < 4; ++n) {
            const unsigned short* vp = &Vlds[buf][(n * 16 + lr) * 64];
#pragma unroll
            for (int g = 0; g < 2; ++g) {
                bf16x8 bv = *(const bf16x8*)&vp[(((g * 4 + lg) ^ (lr & 7)) * 8)];
                O[n] = __builtin_amdgcn_mfma_f32_16x16x32_bf16(pa[g], bv, O[n], 0, 0, 0);
            }
        }
        if (kt + 1 < NT) WAITV(0);
        LGKM0();
        BAR();
    }
#undef STAGEKV

    float linv[4];
#pragma unroll
    for (int r = 0; r < 4; ++r)
        linv[r] = 1.f / __shfl(lstate, lg * 4 + r);
#pragma unroll
    for (int n = 0; n < 4; ++n)
#pragma unroll
        for (int r = 0; r < 4; ++r) {
            int row = qbase + lg * 4 + r;
            yb[(size_t)row * (NH * HD) + h * HD + n * 16 + lr] = f2bf(O[n][r] * linv[r]);
        }
}

extern "C" void kernel_launch(void* const* d_in, const int* in_sizes, int n_in,
                              void* d_out, int out_size, void* d_ws, size_t ws_size,
                              hipStream_t stream) {
    const int* tokens = (const int*)d_in[0];
    const float* freqs_cos = (const float*)d_in[2];
    const float* freqs_sin = (const float*)d_in[3];
    const float* tok_emb = (const float*)d_in[4];
    const float* wq = (const float*)d_in[5];
    const float* wk = (const float*)d_in[6];
    const float* wv = (const float*)d_in[7];
    const float* wo = (const float*)d_in[8];
    const float* attn_norm_w = (const float*)d_in[9];
    const float* ffn_norm_w = (const float*)d_in[10];
    const float* w1 = (const float*)d_in[11];
    const float* w2 = (const float*)d_in[12];
    const float* w3 = (const float*)d_in[13];
    const float* final_norm_w = (const float*)d_in[14];
    const float* out_w = (const float*)d_in[15];
    float* out = (float*)d_out;

    const size_t SD = (size_t)S_LEN * DIM;
    const size_t SKV = (size_t)S_LEN * NKV * HD;

    char* p = (char*)d_ws;
    auto take = [&](size_t bytes) { char* r = p; p += (bytes + 255) & ~(size_t)255; return r; };
    float* h            = (float*)take(SD * 4);
    unsigned short* xnb = (unsigned short*)take(SD * 2);
    char* uni = p;
    float* qkvf         = (float*)uni;                                  // 16 MB
    unsigned short* qb  = (unsigned short*)(uni + 17039360);            // 4 MB
    unsigned short* kb  = qb + SD;                                      // 2 MB
    unsigned short* vT  = kb + SKV;                                     // 2 MB
    unsigned short* ybv = vT + SKV;                                     // 4 MB
    unsigned short* gu  = ybv + SD;                                     // 11.5 MB ([S][2816])
    unsigned short* wT  = gu + (size_t)S_LEN * HID;                     // 11.5 MB
    unsigned short* owT = (unsigned short*)uni;                         // 65.5 MB (final phase)

    embed_kernel<<<S_LEN, 256, 0, stream>>>(tokens, tok_emb, h);
    for (int l = 0; l < 2; ++l) {
        rmsnorm_kernel<<<S_LEN, 256, 0, stream>>>(h, attn_norm_w + l * DIM, xnb);
        transpose_qkv<<<dim3(16, 16, 3), 256, 0, stream>>>(
            wq + (size_t)l * DIM * 1024, wk + (size_t)l * DIM * 512, wv + (size_t)l * DIM * 512, wT);
        gemm_tn<<<dim3(16, 16), 256, 0, stream>>>(xnb, DIM, wT, qkvf, nullptr, nullptr, 2048, DIM);
        rope_kernel<<<dim3(S_LEN / 4, 24), 256, 0, stream>>>(qkvf, freqs_cos, freqs_sin, qb, kb, out, l);
        transpose_vf<<<dim3(8, 32), 256, 0, stream>>>(qkvf, vT, out, l);
        attn_kernel<<<dim3(NKV, 64), 256, 0, stream>>>(qb, kb, vT, ybv);
        transpose_w<<<dim3(16, 16), 256, 0, stream>>>(wo + (size_t)l * 1024 * DIM, wT, 1024, DIM);
        gemm_tn64<<<dim3(32, 8), 256, 0, stream>>>(ybv, 1024, wT, h, nullptr, h, DIM, 1024);
        rmsnorm_kernel<<<S_LEN, 256, 0, stream>>>(h, ffn_norm_w + l * DIM, xnb);
        transpose_w13<<<dim3(44, 16, 2), 256, 0, stream>>>(
            w1 + (size_t)l * DIM * HID, w3 + (size_t)l * DIM * HID, wT);
        gemm8<1><<<dim3(8, 22), 512, 0, stream>>>(xnb, wT, nullptr, gu, 5632, DIM);
        transpose_w<<<dim3(16, 44), 256, 0, stream>>>(w2 + (size_t)l * HID * 1024, wT, HID, 1024);
        gemm_tn64<<<dim3(32, 8), 256, 0, stream>>>(gu, HID, wT, h, nullptr, h, DIM, HID);
    }
    rmsnorm_kernel<<<S_LEN, 256, 0, stream>>>(h, final_norm_w, xnb);
    transpose_w<<<dim3(500, 16), 256, 0, stream>>>(out_w, owT, DIM, 32000);
    gemm8<0><<<dim3(8, 125), 512, 0, stream>>>(xnb, owT, out, nullptr, 32000, DIM);
}

// Round 9
// 649.328 us; speedup vs baseline: 1.4748x; 1.0311x over previous
//
#include <hip/hip_runtime.h>
#include <hip/hip_bf16.h>

typedef __bf16 bf16x8 __attribute__((ext_vector_type(8)));
typedef float f32x4 __attribute__((ext_vector_type(4)));
typedef unsigned short ushort4v __attribute__((ext_vector_type(4)));
typedef unsigned short ushort8v __attribute__((ext_vector_type(8)));

#define S_LEN 2048
#define DIM 1024
#define NH 16
#define NKV 8
#define HD 64
#define HID 2816
#define LOGITS ((size_t)S_LEN * 32000)

__device__ __forceinline__ unsigned short f2bf(float f) {
    union { float f; unsigned u; } v; v.f = f;
    unsigned r = v.u + 0x7fffu + ((v.u >> 16) & 1u);   // RNE
    return (unsigned short)(r >> 16);
}
__device__ __forceinline__ float bf2f(unsigned short u) {
    union { unsigned u; float f; } v; v.u = (unsigned)u << 16; return v.f;
}

__device__ __forceinline__ void gload16(const unsigned short* g, unsigned short* l) {
    __builtin_amdgcn_global_load_lds(
        (const __attribute__((address_space(1))) unsigned int*)g,
        (__attribute__((address_space(3))) unsigned int*)l,
        16, 0, 0);
}

union Frag { f32x4 f; bf16x8 h; };

__device__ __forceinline__ f32x4 lds_read_b128(unsigned addr) {
    f32x4 d;
    asm volatile("ds_read_b128 %0, %1" : "=v"(d) : "v"(addr));
    return d;
}

#define BAR()  asm volatile("s_barrier" ::: "memory")
#define WAITV(n) asm volatile("s_waitcnt vmcnt(" #n ")" ::: "memory")
#define LGKM0() do { asm volatile("s_waitcnt lgkmcnt(0)" ::: "memory"); __builtin_amdgcn_sched_barrier(0); } while (0)

// ---------------- embedding gather ----------------
__global__ __launch_bounds__(256) void embed_kernel(const int* __restrict__ tokens,
                                                    const float* __restrict__ emb,
                                                    float* __restrict__ h) {
    int s = blockIdx.x;
    int t = tokens[s];
    float4 v = *(const float4*)&emb[(size_t)t * DIM + threadIdx.x * 4];
    *(float4*)&h[(size_t)s * DIM + threadIdx.x * 4] = v;
}

// ---------------- rmsnorm: f32 in -> bf16 out ----------------
__global__ __launch_bounds__(256) void rmsnorm_kernel(const float* __restrict__ x,
                                                      const float* __restrict__ w,
                                                      unsigned short* __restrict__ out) {
    __shared__ float sred[4];
    int s = blockIdx.x;
    int tid = threadIdx.x;
    float4 v = *(const float4*)&x[(size_t)s * DIM + tid * 4];
    float ss = v.x * v.x + v.y * v.y + v.z * v.z + v.w * v.w;
#pragma unroll
    for (int off = 32; off; off >>= 1) ss += __shfl_down(ss, off);
    if ((tid & 63) == 0) sred[tid >> 6] = ss;
    __syncthreads();
    float tot = sred[0] + sred[1] + sred[2] + sred[3];
    float scale = rsqrtf(tot * (1.0f / DIM) + 1e-5f);
    float4 wv = *(const float4*)&w[tid * 4];
    ushort4v o;
    o[0] = f2bf(v.x * scale * wv.x); o[1] = f2bf(v.y * scale * wv.y);
    o[2] = f2bf(v.z * scale * wv.z); o[3] = f2bf(v.w * scale * wv.w);
    *(ushort4v*)&out[(size_t)s * DIM + tid * 4] = o;
}

// ---------------- transpose body: f32 [K][N] tile -> bf16 [rowMul*n+rowOff][K] ----------------
__device__ __forceinline__ void tpose_body(const float* __restrict__ in,
                                           unsigned short* __restrict__ out,
                                           int K, int N, int n0, int k0,
                                           int rowMul, int rowOff) {
    __shared__ unsigned short t[64][68];
    int tid = threadIdx.x;
    int tn = tid & 15, tk = tid >> 4;
#pragma unroll
    for (int p = 0; p < 4; ++p) {
        int k = tk + p * 16;
        float4 v = *(const float4*)&in[(size_t)(k0 + k) * N + n0 + tn * 4];
        t[tn * 4 + 0][k] = f2bf(v.x);
        t[tn * 4 + 1][k] = f2bf(v.y);
        t[tn * 4 + 2][k] = f2bf(v.z);
        t[tn * 4 + 3][k] = f2bf(v.w);
    }
    __syncthreads();
    int wk = tid & 15, wn = tid >> 4;
#pragma unroll
    for (int p = 0; p < 4; ++p) {
        int n = wn + p * 16;
        ushort4v v;
        v[0] = t[n][wk * 4]; v[1] = t[n][wk * 4 + 1];
        v[2] = t[n][wk * 4 + 2]; v[3] = t[n][wk * 4 + 3];
        *(ushort4v*)&out[(size_t)(rowMul * (n0 + n) + rowOff) * K + k0 + wk * 4] = v;
    }
}

__global__ __launch_bounds__(256) void transpose_w(const float* __restrict__ in,
                                                   unsigned short* __restrict__ out,
                                                   int K, int N) {
    tpose_body(in, out, K, N, blockIdx.x * 64, blockIdx.y * 64, 1, 0);
}

// qkv fused: z=0 wq (N=1024, rows 0..1023), z=1 wk (rows 1024..), z=2 wv (rows 1536..)
__global__ __launch_bounds__(256) void transpose_qkv(const float* __restrict__ wq,
                                                     const float* __restrict__ wk,
                                                     const float* __restrict__ wv,
                                                     unsigned short* __restrict__ out) {
    int z = blockIdx.z;
    if (z > 0 && blockIdx.x >= 8) return;
    const float* in = z == 0 ? wq : (z == 1 ? wk : wv);
    int N = z == 0 ? 1024 : 512;
    int rowOff = z == 0 ? 0 : (z == 1 ? 1024 : 1536);
    tpose_body(in, out, DIM, N, blockIdx.x * 64, blockIdx.y * 64, 1, rowOff);
}

// w1|w3 interleaved: out row 2j = w1 col j, row 2j+1 = w3 col j
__global__ __launch_bounds__(256) void transpose_w13(const float* __restrict__ w1,
                                                     const float* __restrict__ w3,
                                                     unsigned short* __restrict__ out) {
    int z = blockIdx.z;
    tpose_body(z ? w3 : w1, out, DIM, HID, blockIdx.x * 64, blockIdx.y * 64, 2, z);
}

// ---------------- qkv GEMM 128^2 + fused RoPE/V-transpose/news epilogue ----------------
// A = xnb [2048][1024], Bt = wT [2048][1024]. Writes qb [S][1024], kb [S][512], vT [512][2048].
__global__ __launch_bounds__(256) void gemm_qkv(const unsigned short* __restrict__ A,
                                                const unsigned short* __restrict__ Bt,
                                                const float* __restrict__ fc,
                                                const float* __restrict__ fs,
                                                unsigned short* __restrict__ qb,
                                                unsigned short* __restrict__ kb,
                                                unsigned short* __restrict__ vT,
                                                float* __restrict__ out, int layer) {
    __shared__ unsigned short As[128 * 64];
    __shared__ unsigned short Bs[128 * 64];
    const int K = DIM, lda = DIM;
    int tid = threadIdx.x;
    int lane = tid & 63;
    int wid = tid >> 6;
    int wrow = wid >> 1, wcol = wid & 1;
    int lr = lane & 15, lg = lane >> 4;
    const int m0 = blockIdx.x * 128, n0 = blockIdx.y * 128;

    const int col8 = (((lane & 7) ^ ((lane >> 3) & 7)) * 8);
    const unsigned short* aG = A + (size_t)(m0 + wid * 32 + (lane >> 3)) * lda + col8;
    const unsigned short* bG = Bt + (size_t)(n0 + wid * 32 + (lane >> 3)) * K + col8;
    unsigned short* aL = As + wid * 2048;
    unsigned short* bL = Bs + wid * 2048;

    f32x4 acc[4][4] = {};

    for (int k0 = 0; k0 < K; k0 += 64) {
#pragma unroll
        for (int i = 0; i < 4; ++i)
            gload16(aG + (size_t)(i * 8) * lda + k0, aL + i * 512);
#pragma unroll
        for (int i = 0; i < 4; ++i)
            gload16(bG + (size_t)(i * 8) * K + k0, bL + i * 512);
        __syncthreads();
#pragma unroll
        for (int kk = 0; kk < 2; ++kk) {
            const int slot = ((kk * 4 + lg) ^ (lr & 7)) * 8;
            bf16x8 aF[4], bF[4];
#pragma unroll
            for (int mi = 0; mi < 4; ++mi)
                aF[mi] = *(const bf16x8*)&As[(wrow * 64 + mi * 16 + lr) * 64 + slot];
#pragma unroll
            for (int ni = 0; ni < 4; ++ni)
                bF[ni] = *(const bf16x8*)&Bs[(wcol * 64 + ni * 16 + lr) * 64 + slot];
#pragma unroll
            for (int mi = 0; mi < 4; ++mi)
#pragma unroll
                for (int ni = 0; ni < 4; ++ni)
                    acc[mi][ni] = __builtin_amdgcn_mfma_f32_16x16x32_bf16(aF[mi], bF[ni], acc[mi][ni], 0, 0, 0);
        }
        __syncthreads();
    }
    // fused epilogue: col<1024 q-rope, col<1536 k-rope(+k_news), else v-transpose(+v_news)
#pragma unroll
    for (int mi = 0; mi < 4; ++mi)
#pragma unroll
        for (int ni = 0; ni < 4; ++ni) {
            int col = n0 + wcol * 64 + ni * 16 + lr;
            int s0r = m0 + wrow * 64 + mi * 16 + lg * 4;
            if (col < 1536) {
                int p = (col & 63) >> 1;
                int odd = col & 1;
#pragma unroll
                for (int r = 0; r < 4; ++r) {
                    float v = acc[mi][ni][r];
                    float o = __shfl_xor(v, 1);
                    int s = s0r + r;
                    float c = fc[s * 32 + p], sn = fs[s * 32 + p];
                    float res = odd ? (o * sn + v * c) : (v * c - o * sn);
                    int dpos = (odd ? 32 : 0) + p;
                    if (col < 1024) {
                        qb[(size_t)s * 1024 + (col >> 6) * 64 + dpos] = f2bf(res);
                    } else {
                        int kcol = ((col >> 6) - 16) * 64 + dpos;
                        kb[(size_t)s * 512 + kcol] = f2bf(res);
                        if (s == S_LEN - 1)
                            out[LOGITS + (size_t)layer * 512 + kcol] = res;
                    }
                }
            } else {
                int d = col - 1536;
                ushort4v vv;
#pragma unroll
                for (int r = 0; r < 4; ++r) vv[r] = f2bf(acc[mi][ni][r]);
                *(ushort4v*)&vT[(size_t)d * 2048 + s0r] = vv;
                if (s0r + 3 == S_LEN - 1)
                    out[LOGITS + 2 * 512 + (size_t)layer * 512 + d] = acc[mi][ni][3];
            }
        }
}

// ---------------- GEMM BM=64, BN=128 (for N=1024 outputs: full-chip grid 32x8) ----------------
__global__ __launch_bounds__(256) void gemm_tn64(const unsigned short* __restrict__ A, int lda,
                                                 const unsigned short* __restrict__ Bt,
                                                 float* __restrict__ Cf,
                                                 const float* __restrict__ addsrc,
                                                 int N, int K) {
    __shared__ unsigned short As[64 * 64];
    __shared__ unsigned short Bs[128 * 64];
    int tid = threadIdx.x;
    int lane = tid & 63;
    int wid = tid >> 6;
    int lr = lane & 15, lg = lane >> 4;
    const int m0 = blockIdx.x * 64, n0 = blockIdx.y * 128;

    const int srow = tid >> 3;
    const int col8 = (((tid & 7) ^ ((tid >> 3) & 7)) * 8);
    const unsigned short* aG = A + (size_t)(m0 + srow) * lda + col8;
    const unsigned short* bG = Bt + (size_t)(n0 + srow) * K + col8;
    unsigned short* aL = As + wid * 512;
    unsigned short* bL = Bs + wid * 512;

    f32x4 acc[4][2] = {};

    for (int k0 = 0; k0 < K; k0 += 64) {
        gload16(aG + k0, aL);
        gload16(aG + (size_t)32 * lda + k0, aL + 2048);
#pragma unroll
        for (int i = 0; i < 4; ++i)
            gload16(bG + (size_t)(i * 32) * K + k0, bL + i * 2048);
        __syncthreads();
#pragma unroll
        for (int kk = 0; kk < 2; ++kk) {
            const int slot = ((kk * 4 + lg) ^ (lr & 7)) * 8;
            bf16x8 aF[4], bF[2];
#pragma unroll
            for (int mi = 0; mi < 4; ++mi)
                aF[mi] = *(const bf16x8*)&As[(mi * 16 + lr) * 64 + slot];
#pragma unroll
            for (int ni = 0; ni < 2; ++ni)
                bF[ni] = *(const bf16x8*)&Bs[(wid * 32 + ni * 16 + lr) * 64 + slot];
#pragma unroll
            for (int mi = 0; mi < 4; ++mi)
#pragma unroll
                for (int ni = 0; ni < 2; ++ni)
                    acc[mi][ni] = __builtin_amdgcn_mfma_f32_16x16x32_bf16(aF[mi], bF[ni], acc[mi][ni], 0, 0, 0);
        }
        __syncthreads();
    }
#pragma unroll
    for (int mi = 0; mi < 4; ++mi)
#pragma unroll
        for (int ni = 0; ni < 2; ++ni) {
            int row = m0 + mi * 16 + lg * 4;
            int col = n0 + wid * 32 + ni * 16 + lr;
#pragma unroll
            for (int r = 0; r < 4; ++r) {
                size_t idx = (size_t)(row + r) * N + col;
                float v = acc[mi][ni][r];
                if (addsrc) v += addsrc[idx];
                Cf[idx] = v;
            }
        }
}

// ---------------- GEMM 256^2 8-phase BK=64 (T1..T5); FUSE=1: silu(even)*odd -> bf16 [.][2816] ----------------
template<int FUSE>
__global__ __launch_bounds__(512) void gemm8(const unsigned short* __restrict__ A,
                                             const unsigned short* __restrict__ Bt,
                                             float* __restrict__ Cf,
                                             unsigned short* __restrict__ Cb,
                                             int N, int K) {
    __shared__ unsigned short ldsbuf[65536];
    const int NT = K >> 6;
    int tid = threadIdx.x;
    int lane = tid & 63;
    int wid = tid >> 6;
    int wm = wid >> 2, wn = wid & 3;
    int lr = lane & 15, lg = lane >> 4;
    int wl = blockIdx.x * gridDim.y + blockIdx.y;
    const int m0 = (wl & 7) * 256, n0 = (wl >> 3) * 256;

    unsigned lds0 = (unsigned)(size_t)(__attribute__((address_space(3))) unsigned short*)ldsbuf;
    const unsigned xoff = (unsigned)((lg ^ ((lr >> 1) & 3)) * 16);
    const int gsw = (lane & 3) ^ ((lane >> 3) & 3);
    const int srow = wid * 16 + (lane >> 2);

#define STAGE(buf, ab, s, t) do {                                                   \
        const unsigned short* _src = (ab) ? Bt : A;                                 \
        int _r0 = (ab) ? n0 : m0;                                                   \
        unsigned short* _l = ldsbuf + (((buf) * 2 + (ab)) * 2 + (s)) * 8192 + wid * 512; \
        const unsigned short* _g = _src + (size_t)(_r0 + srow) * K + (size_t)(t) * 64 + (s) * 32 + gsw * 8; \
        gload16(_g, _l);                                                            \
        gload16(_g + (size_t)128 * K, _l + 4096);                                   \
    } while (0)

    f32x4 acc[8][4] = {};

    STAGE(0, 0, 0, 0); STAGE(0, 1, 0, 0);
    STAGE(0, 0, 1, 0); STAGE(0, 1, 1, 0);
    STAGE(1, 0, 0, 1); STAGE(1, 1, 0, 1);
    WAITV(8);
    BAR();

    for (int t = 0; t < NT; ++t) {
        int buf = t & 1;
        unsigned aBase = lds0 + (unsigned)(buf * 65536) + (unsigned)((wm * 128 + lr) * 64) + xoff;
        unsigned bBase = lds0 + (unsigned)(buf * 65536 + 32768) + (unsigned)((wn * 64 + lr) * 64) + xoff;
        Frag aF[4], bF[4];
#pragma unroll
        for (int s = 0; s < 2; ++s) {
#pragma unroll
            for (int ni = 0; ni < 4; ++ni)
                bF[ni].f = lds_read_b128(bBase + (unsigned)(s * 16384 + ni * 1024));
#pragma unroll
            for (int mi = 0; mi < 4; ++mi)
                aF[mi].f = lds_read_b128(aBase + (unsigned)(s * 16384 + mi * 1024));
            if (s == 0) { if (t + 1 < NT) STAGE(buf ^ 1, 0, 1, t + 1); }
            else        { if (t + 2 < NT) STAGE(buf,     0, 0, t + 2); }
            BAR();
            LGKM0();
            __builtin_amdgcn_s_setprio(1);
#pragma unroll
            for (int mi = 0; mi < 4; ++mi)
#pragma unroll
                for (int ni = 0; ni < 4; ++ni)
                    acc[mi][ni] = __builtin_amdgcn_mfma_f32_16x16x32_bf16(aF[mi].h, bF[ni].h, acc[mi][ni], 0, 0, 0);
            __builtin_amdgcn_s_setprio(0);
            BAR();
#pragma unroll
            for (int mi = 0; mi < 4; ++mi)
                aF[mi].f = lds_read_b128(aBase + (unsigned)(4096 + s * 16384 + mi * 1024));
            if (s == 0) { if (t + 1 < NT) STAGE(buf ^ 1, 1, 1, t + 1); }
            else        { if (t + 2 < NT) STAGE(buf,     1, 0, t + 2); }
            BAR();
            LGKM0();
            __builtin_amdgcn_s_setprio(1);
#pragma unroll
            for (int mi = 0; mi < 4; ++mi)
#pragma unroll
                for (int ni = 0; ni < 4; ++ni)
                    acc[4 + mi][ni] = __builtin_amdgcn_mfma_f32_16x16x32_bf16(aF[mi].h, bF[ni].h, acc[4 + mi][ni], 0, 0, 0);
            __builtin_amdgcn_s_setprio(0);
            if (s == 0) {
                if (t + 1 < NT) { WAITV(8); } else { WAITV(0); }
            } else {
                if (t + 2 < NT)      { WAITV(8); }
                else if (t + 1 < NT) { WAITV(4); }
            }
            BAR();
        }
    }
#undef STAGE

#pragma unroll
    for (int mi = 0; mi < 8; ++mi)
#pragma unroll
        for (int ni = 0; ni < 4; ++ni) {
            int row = m0 + wm * 128 + mi * 16 + lg * 4;
            int col = n0 + wn * 64 + ni * 16 + lr;
#pragma unroll
            for (int r = 0; r < 4; ++r) {
                float v = acc[mi][ni][r];
                if (FUSE) {
                    float o = __shfl_xor(v, 1);
                    if (!(lr & 1)) {
                        float res = v / (1.f + __expf(-v)) * o;
                        Cb[(size_t)(row + r) * (HID) + (col >> 1)] = f2bf(res);
                    }
                } else {
                    Cf[(size_t)(row + r) * N + col] = v;
                }
            }
        }
}

// ---------------- GEMM 256^2 BK=32, 64 KB LDS -> 2 blocks/CU (logits) ----------------
// Race-free staging: SA(t+1) issued ph0 (targets idle buf^1); SB(t+2) issued ph1
// (buf's B last read drained at the post-MFMA barrier of ph0); end-of-tile vmcnt(2).
__global__ __launch_bounds__(512) void gemm8k32(const unsigned short* __restrict__ A,
                                                const unsigned short* __restrict__ Bt,
                                                float* __restrict__ Cf,
                                                int N, int K) {
    __shared__ unsigned short ldsbuf[32768];   // 64 KB: [buf][ab] x 256 rows x 32 k
    const int NT = K >> 5;
    int tid = threadIdx.x;
    int lane = tid & 63;
    int wid = tid >> 6;
    int wm = wid >> 2, wn = wid & 3;
    int lr = lane & 15, lg = lane >> 4;
    int wl = blockIdx.x * gridDim.y + blockIdx.y;
    const int m0 = (wl & 7) * 256, n0 = (wl >> 3) * 256;

    unsigned lds0 = (unsigned)(size_t)(__attribute__((address_space(3))) unsigned short*)ldsbuf;
    const unsigned xoff = (unsigned)((lg ^ ((lr >> 1) & 3)) * 16);
    const int gsw = (lane & 3) ^ ((lane >> 3) & 3);
    const int srow = wid * 16 + (lane >> 2);

#define STGA(t) do { \
        unsigned short* _l = ldsbuf + (((t) & 1) * 2 + 0) * 8192 + wid * 512; \
        const unsigned short* _g = A + (size_t)(m0 + srow) * K + (size_t)(t) * 32 + gsw * 8; \
        gload16(_g, _l); \
        gload16(_g + (size_t)128 * K, _l + 4096); \
    } while (0)
#define STGB(t) do { \
        unsigned short* _l = ldsbuf + (((t) & 1) * 2 + 1) * 8192 + wid * 512; \
        const unsigned short* _g = Bt + (size_t)(n0 + srow) * K + (size_t)(t) * 32 + gsw * 8; \
        gload16(_g, _l); \
        gload16(_g + (size_t)128 * K, _l + 4096); \
    } while (0)

    f32x4 acc[8][4] = {};

    STGA(0); STGB(0); STGB(1);
    WAITV(2);
    BAR();

    for (int t = 0; t < NT; ++t) {
        int buf = t & 1;
        unsigned aBase = lds0 + (unsigned)(buf * 32768) + (unsigned)((wm * 128 + lr) * 64) + xoff;
        unsigned bBase = lds0 + (unsigned)(buf * 32768 + 16384) + (unsigned)((wn * 64 + lr) * 64) + xoff;
        Frag aF[4], bF[4];
        // ---- ph0: read B + A(mh0); issue SA(t+1) into buf^1 ----
#pragma unroll
        for (int ni = 0; ni < 4; ++ni)
            bF[ni].f = lds_read_b128(bBase + (unsigned)(ni * 1024));
#pragma unroll
        for (int mi = 0; mi < 4; ++mi)
            aF[mi].f = lds_read_b128(aBase + (unsigned)(mi * 1024));
        if (t + 1 < NT) STGA(t + 1);
        BAR();
        LGKM0();
        __builtin_amdgcn_s_setprio(1);
#pragma unroll
        for (int mi = 0; mi < 4; ++mi)
#pragma unroll
            for (int ni = 0; ni < 4; ++ni)
                acc[mi][ni] = __builtin_amdgcn_mfma_f32_16x16x32_bf16(aF[mi].h, bF[ni].h, acc[mi][ni], 0, 0, 0);
        __builtin_amdgcn_s_setprio(0);
        BAR();
        // ---- ph1: read A(mh1); issue SB(t+2) into buf (B fully read in ph0) ----
#pragma unroll
        for (int mi = 0; mi < 4; ++mi)
            aF[mi].f = lds_read_b128(aBase + (unsigned)(4096 + mi * 1024));
        if (t + 2 < NT) STGB(t + 2);
        BAR();
        LGKM0();
        __builtin_amdgcn_s_setprio(1);
#pragma unroll
        for (int mi = 0; mi < 4; ++mi)
#pragma unroll
            for (int ni = 0; ni < 4; ++ni)
                acc[4 + mi][ni] = __builtin_amdgcn_mfma_f32_16x16x32_bf16(aF[mi].h, bF[ni].h, acc[4 + mi][ni], 0, 0, 0);
        __builtin_amdgcn_s_setprio(0);
        if (t + 2 < NT)      { WAITV(2); }
        else if (t + 1 < NT) { WAITV(0); }
        BAR();
    }
#undef STGA
#undef STGB

#pragma unroll
    for (int mi = 0; mi < 8; ++mi)
#pragma unroll
        for (int ni = 0; ni < 4; ++ni) {
            int row = m0 + wm * 128 + mi * 16 + lg * 4;
            int col = n0 + wn * 64 + ni * 16 + lr;
#pragma unroll
            for (int r = 0; r < 4; ++r)
                Cf[(size_t)(row + r) * N + col] = acc[mi][ni][r];
        }
}

// ---------------- flash attention: 4-wave blocks, 32 q-rows, balanced big-first grid ----------------
__global__ __launch_bounds__(256) void attn_kernel(const unsigned short* __restrict__ qb,
                                                   const unsigned short* __restrict__ kb,
                                                   const unsigned short* __restrict__ vT,
                                                   unsigned short* __restrict__ yb) {
    __shared__ unsigned short Klds[2][4096];
    __shared__ unsigned short Vlds[2][4096];
    __shared__ unsigned short P[4][16 * 72];
    int kvh = blockIdx.x;
    int strip = 63 - blockIdx.y;
    int tid = threadIdx.x;
    int lane = tid & 63;
    int w = tid >> 6;
    int hq = w & 1, qsub = w >> 1;
    int h = kvh * 2 + hq;
    int lr = lane & 15, lg = lane >> 4;
    int qbase = strip * 32 + qsub * 16;
    int qrow = qbase + lr;

    const int sr = tid >> 3;
    const int scol8 = (((tid & 7) ^ (sr & 7)) * 8);
    const int NT = (strip >> 1) + 1;

#define STAGEKV(buf, kt) do { \
        gload16(&kb[(size_t)((kt) * 64 + sr) * 512 + kvh * 64 + scol8], &Klds[buf][w * 512]); \
        gload16(&kb[(size_t)((kt) * 64 + sr + 32) * 512 + kvh * 64 + scol8], &Klds[buf][2048 + w * 512]); \
        gload16(&vT[(size_t)(kvh * 64 + sr) * 2048 + (kt) * 64 + scol8], &Vlds[buf][w * 512]); \
        gload16(&vT[(size_t)(kvh * 64 + sr + 32) * 2048 + (kt) * 64 + scol8], &Vlds[buf][2048 + w * 512]); \
    } while (0)

    bf16x8 bq[2];
#pragma unroll
    for (int c = 0; c < 2; ++c)
        bq[c] = *(const bf16x8*)&qb[(size_t)qrow * (NH * HD) + h * HD + c * 32 + lg * 8];

    f32x4 O[4] = {};
    float mstate = -1e30f, lstate = 0.f;

    STAGEKV(0, 0);
    WAITV(0);
    BAR();

    for (int kt = 0; kt < NT; ++kt) {
        int buf = kt & 1;
        if (kt + 1 < NT) STAGEKV(buf ^ 1, kt + 1);
        f32x4 s[4];
#pragma unroll
        for (int kc = 0; kc < 4; ++kc) {
            int krl = kc * 16 + lr;
            const unsigned short* kp = &Klds[buf][krl * 64];
            bf16x8 ak0 = *(const bf16x8*)&kp[((lg ^ (lr & 7)) * 8)];
            bf16x8 ak1 = *(const bf16x8*)&kp[(((4 + lg) ^ (lr & 7)) * 8)];
            f32x4 z = {};
            z = __builtin_amdgcn_mfma_f32_16x16x32_bf16(ak0, bq[0], z, 0, 0, 0);
            z = __builtin_amdgcn_mfma_f32_16x16x32_bf16(ak1, bq[1], z, 0, 0, 0);
            s[kc] = z;
        }
        float tm = -1e30f;
#pragma unroll
        for (int kc = 0; kc < 4; ++kc)
#pragma unroll
            for (int r = 0; r < 4; ++r) {
                int key = kt * 64 + kc * 16 + lg * 4 + r;
                float val = s[kc][r] * 0.125f;
                if (key > qrow) val = -1e30f;
                s[kc][r] = val;
                tm = fmaxf(tm, val);
            }
        tm = fmaxf(tm, __shfl_xor(tm, 16));
        tm = fmaxf(tm, __shfl_xor(tm, 32));
        float mn = fmaxf(mstate, tm);
        float sc = __expf(mstate - mn);
        float rs = 0.f;
        ushort4v pk[4];
#pragma unroll
        for (int kc = 0; kc < 4; ++kc)
#pragma unroll
            for (int r = 0; r < 4; ++r) {
                float pf = __expf(s[kc][r] - mn);
                rs += pf;
                pk[kc][r] = f2bf(pf);
            }
        rs += __shfl_xor(rs, 16);
        rs += __shfl_xor(rs, 32);
        lstate = lstate * sc + rs;
        mstate = mn;
        float osc[4];
#pragma unroll
        for (int r = 0; r < 4; ++r)
            osc[r] = __shfl(sc, lg * 4 + r);
#pragma unroll
        for (int n = 0; n < 4; ++n)
#pragma unroll
            for (int r = 0; r < 4; ++r)
                O[n][r] *= osc[r];
#pragma unroll
        for (int kc = 0; kc < 4; ++kc)
            *(ushort4v*)&P[w][lr * 72 + kc * 16 + lg * 4] = pk[kc];
        bf16x8 pa[2];
#pragma unroll
        for (int g = 0; g < 2; ++g)
            pa[g] = *(const bf16x8*)&P[w][lr * 72 + g * 32 + lg * 8];
#pragma unroll
        for (int n = 0; n < 4; ++n) {
            const unsigned short* vp = &Vlds[buf][(n * 16 + lr) * 64];
#pragma unroll
            for (int g = 0; g < 2; ++g) {
                bf16x8 bv = *(const bf16x8*)&vp[(((g * 4 + lg) ^ (lr & 7)) * 8)];
                O[n] = __builtin_amdgcn_mfma_f32_16x16x32_bf16(pa[g], bv, O[n], 0, 0, 0);
            }
        }
        if (kt + 1 < NT) WAITV(0);
        LGKM0();
        BAR();
    }
#undef STAGEKV

    float linv[4];
#pragma unroll
    for (int r = 0; r < 4; ++r)
        linv[r] = 1.f / __shfl(lstate, lg * 4 + r);
#pragma unroll
    for (int n = 0; n < 4; ++n)
#pragma unroll
        for (int r = 0; r < 4; ++r) {
            int row = qbase + lg * 4 + r;
            yb[(size_t)row * (NH * HD) + h * HD + n * 16 + lr] = f2bf(O[n][r] * linv[r]);
        }
}

extern "C" void kernel_launch(void* const* d_in, const int* in_sizes, int n_in,
                              void* d_out, int out_size, void* d_ws, size_t ws_size,
                              hipStream_t stream) {
    const int* tokens = (const int*)d_in[0];
    const float* freqs_cos = (const float*)d_in[2];
    const float* freqs_sin = (const float*)d_in[3];
    const float* tok_emb = (const float*)d_in[4];
    const float* wq = (const float*)d_in[5];
    const float* wk = (const float*)d_in[6];
    const float* wv = (const float*)d_in[7];
    const float* wo = (const float*)d_in[8];
    const float* attn_norm_w = (const float*)d_in[9];
    const float* ffn_norm_w = (const float*)d_in[10];
    const float* w1 = (const float*)d_in[11];
    const float* w2 = (const float*)d_in[12];
    const float* w3 = (const float*)d_in[13];
    const float* final_norm_w = (const float*)d_in[14];
    const float* out_w = (const float*)d_in[15];
    float* out = (float*)d_out;

    const size_t SD = (size_t)S_LEN * DIM;
    const size_t SKV = (size_t)S_LEN * NKV * HD;

    char* p = (char*)d_ws;
    auto take = [&](size_t bytes) { char* r = p; p += (bytes + 255) & ~(size_t)255; return r; };
    float* h            = (float*)take(SD * 4);
    unsigned short* xnb = (unsigned short*)take(SD * 2);
    char* uni = p;
    unsigned short* qb  = (unsigned short*)uni;                         // 4 MB
    unsigned short* kb  = qb + SD;                                      // 2 MB
    unsigned short* vT  = kb + SKV;                                     // 2 MB
    unsigned short* ybv = vT + SKV;                                     // 4 MB
    unsigned short* gu  = ybv + SD;                                     // 11.5 MB ([S][2816])
    unsigned short* wT  = gu + (size_t)S_LEN * HID;                     // 11.5 MB
    unsigned short* owT = (unsigned short*)uni;                         // 65.5 MB (final phase)

    embed_kernel<<<S_LEN, 256, 0, stream>>>(tokens, tok_emb, h);
    for (int l = 0; l < 2; ++l) {
        rmsnorm_kernel<<<S_LEN, 256, 0, stream>>>(h, attn_norm_w + l * DIM, xnb);
        transpose_qkv<<<dim3(16, 16, 3), 256, 0, stream>>>(
            wq + (size_t)l * DIM * 1024, wk + (size_t)l * DIM * 512, wv + (size_t)l * DIM * 512, wT);
        gemm_qkv<<<dim3(16, 16), 256, 0, stream>>>(xnb, wT, freqs_cos, freqs_sin,
                                                   qb, kb, vT, out, l);
        attn_kernel<<<dim3(NKV, 64), 256, 0, stream>>>(qb, kb, vT, ybv);
        transpose_w<<<dim3(16, 16), 256, 0, stream>>>(wo + (size_t)l * 1024 * DIM, wT, 1024, DIM);
        gemm_tn64<<<dim3(32, 8), 256, 0, stream>>>(ybv, 1024, wT, h, h, DIM, 1024);
        rmsnorm_kernel<<<S_LEN, 256, 0, stream>>>(h, ffn_norm_w + l * DIM, xnb);
        transpose_w13<<<dim3(44, 16, 2), 256, 0, stream>>>(
            w1 + (size_t)l * DIM * HID, w3 + (size_t)l * DIM * HID, wT);
        gemm8<1><<<dim3(8, 22), 512, 0, stream>>>(xnb, wT, nullptr, gu, 5632, DIM);
        transpose_w<<<dim3(16, 44), 256, 0, stream>>>(w2 + (size_t)l * HID * 1024, wT, HID, 1024);
        gemm_tn64<<<dim3(32, 8), 256, 0, stream>>>(gu, HID, wT, h, h, DIM, HID);
    }
    rmsnorm_kernel<<<S_LEN, 256, 0, stream>>>(h, final_norm_w, xnb);
    transpose_w<<<dim3(500, 16), 256, 0, stream>>>(out_w, owT, DIM, 32000);
    gemm8k32<<<dim3(8, 125), 512, 0, stream>>>(xnb, owT, out, 32000, DIM);
}

// Round 10
// 647.123 us; speedup vs baseline: 1.4799x; 1.0034x over previous
//
#include <hip/hip_runtime.h>
#include <hip/hip_bf16.h>

typedef __bf16 bf16x8 __attribute__((ext_vector_type(8)));
typedef float f32x4 __attribute__((ext_vector_type(4)));
typedef unsigned short ushort4v __attribute__((ext_vector_type(4)));
typedef unsigned short ushort8v __attribute__((ext_vector_type(8)));

#define S_LEN 2048
#define DIM 1024
#define NH 16
#define NKV 8
#define HD 64
#define HID 2816
#define LOGITS ((size_t)S_LEN * 32000)

__device__ __forceinline__ unsigned short f2bf(float f) {
    union { float f; unsigned u; } v; v.f = f;
    unsigned r = v.u + 0x7fffu + ((v.u >> 16) & 1u);   // RNE
    return (unsigned short)(r >> 16);
}
__device__ __forceinline__ float bf2f(unsigned short u) {
    union { unsigned u; float f; } v; v.u = (unsigned)u << 16; return v.f;
}

__device__ __forceinline__ void gload16(const unsigned short* g, unsigned short* l) {
    __builtin_amdgcn_global_load_lds(
        (const __attribute__((address_space(1))) unsigned int*)g,
        (__attribute__((address_space(3))) unsigned int*)l,
        16, 0, 0);
}

union Frag { f32x4 f; bf16x8 h; };

__device__ __forceinline__ f32x4 lds_read_b128(unsigned addr) {
    f32x4 d;
    asm volatile("ds_read_b128 %0, %1" : "=v"(d) : "v"(addr));
    return d;
}

#define BAR()  asm volatile("s_barrier" ::: "memory")
#define WAITV(n) asm volatile("s_waitcnt vmcnt(" #n ")" ::: "memory")
#define LGKM0() do { asm volatile("s_waitcnt lgkmcnt(0)" ::: "memory"); __builtin_amdgcn_sched_barrier(0); } while (0)

// ---------------- embedding gather ----------------
__global__ __launch_bounds__(256) void embed_kernel(const int* __restrict__ tokens,
                                                    const float* __restrict__ emb,
                                                    float* __restrict__ h) {
    int s = blockIdx.x;
    int t = tokens[s];
    float4 v = *(const float4*)&emb[(size_t)t * DIM + threadIdx.x * 4];
    *(float4*)&h[(size_t)s * DIM + threadIdx.x * 4] = v;
}

// ---------------- rmsnorm: f32 in -> bf16 out ----------------
__global__ __launch_bounds__(256) void rmsnorm_kernel(const float* __restrict__ x,
                                                      const float* __restrict__ w,
                                                      unsigned short* __restrict__ out) {
    __shared__ float sred[4];
    int s = blockIdx.x;
    int tid = threadIdx.x;
    float4 v = *(const float4*)&x[(size_t)s * DIM + tid * 4];
    float ss = v.x * v.x + v.y * v.y + v.z * v.z + v.w * v.w;
#pragma unroll
    for (int off = 32; off; off >>= 1) ss += __shfl_down(ss, off);
    if ((tid & 63) == 0) sred[tid >> 6] = ss;
    __syncthreads();
    float tot = sred[0] + sred[1] + sred[2] + sred[3];
    float scale = rsqrtf(tot * (1.0f / DIM) + 1e-5f);
    float4 wv = *(const float4*)&w[tid * 4];
    ushort4v o;
    o[0] = f2bf(v.x * scale * wv.x); o[1] = f2bf(v.y * scale * wv.y);
    o[2] = f2bf(v.z * scale * wv.z); o[3] = f2bf(v.w * scale * wv.w);
    *(ushort4v*)&out[(size_t)s * DIM + tid * 4] = o;
}

// ---------------- transpose body: f32 [K][N] tile -> bf16 [rowMul*n+rowOff][K] ----------------
__device__ __forceinline__ void tpose_body(const float* __restrict__ in,
                                           unsigned short* __restrict__ out,
                                           int K, int N, int n0, int k0,
                                           int rowMul, int rowOff) {
    __shared__ unsigned short t[64][68];
    int tid = threadIdx.x;
    int tn = tid & 15, tk = tid >> 4;
#pragma unroll
    for (int p = 0; p < 4; ++p) {
        int k = tk + p * 16;
        float4 v = *(const float4*)&in[(size_t)(k0 + k) * N + n0 + tn * 4];
        t[tn * 4 + 0][k] = f2bf(v.x);
        t[tn * 4 + 1][k] = f2bf(v.y);
        t[tn * 4 + 2][k] = f2bf(v.z);
        t[tn * 4 + 3][k] = f2bf(v.w);
    }
    __syncthreads();
    int wk = tid & 15, wn = tid >> 4;
#pragma unroll
    for (int p = 0; p < 4; ++p) {
        int n = wn + p * 16;
        ushort4v v;
        v[0] = t[n][wk * 4]; v[1] = t[n][wk * 4 + 1];
        v[2] = t[n][wk * 4 + 2]; v[3] = t[n][wk * 4 + 3];
        *(ushort4v*)&out[(size_t)(rowMul * (n0 + n) + rowOff) * K + k0 + wk * 4] = v;
    }
}

__global__ __launch_bounds__(256) void transpose_w(const float* __restrict__ in,
                                                   unsigned short* __restrict__ out,
                                                   int K, int N) {
    tpose_body(in, out, K, N, blockIdx.x * 64, blockIdx.y * 64, 1, 0);
}

// qkv fused: z=0 wq (N=1024, rows 0..1023), z=1 wk (rows 1024..), z=2 wv (rows 1536..)
__global__ __launch_bounds__(256) void transpose_qkv(const float* __restrict__ wq,
                                                     const float* __restrict__ wk,
                                                     const float* __restrict__ wv,
                                                     unsigned short* __restrict__ out) {
    int z = blockIdx.z;
    if (z > 0 && blockIdx.x >= 8) return;
    const float* in = z == 0 ? wq : (z == 1 ? wk : wv);
    int N = z == 0 ? 1024 : 512;
    int rowOff = z == 0 ? 0 : (z == 1 ? 1024 : 1536);
    tpose_body(in, out, DIM, N, blockIdx.x * 64, blockIdx.y * 64, 1, rowOff);
}

// w1|w3 interleaved: out row 2j = w1 col j, row 2j+1 = w3 col j
__global__ __launch_bounds__(256) void transpose_w13(const float* __restrict__ w1,
                                                     const float* __restrict__ w3,
                                                     unsigned short* __restrict__ out) {
    int z = blockIdx.z;
    tpose_body(z ? w3 : w1, out, DIM, HID, blockIdx.x * 64, blockIdx.y * 64, 2, z);
}

// ---------------- qkv GEMM 128^2 + fused RoPE/V-transpose/news epilogue ----------------
// A = xnb [2048][1024], Bt = wT [2048][1024]. Writes qb [S][1024], kb [S][512], vT [512][2048].
__global__ __launch_bounds__(256) void gemm_qkv(const unsigned short* __restrict__ A,
                                                const unsigned short* __restrict__ Bt,
                                                const float* __restrict__ fc,
                                                const float* __restrict__ fs,
                                                unsigned short* __restrict__ qb,
                                                unsigned short* __restrict__ kb,
                                                unsigned short* __restrict__ vT,
                                                float* __restrict__ out, int layer) {
    __shared__ unsigned short As[128 * 64];
    __shared__ unsigned short Bs[128 * 64];
    const int K = DIM, lda = DIM;
    int tid = threadIdx.x;
    int lane = tid & 63;
    int wid = tid >> 6;
    int wrow = wid >> 1, wcol = wid & 1;
    int lr = lane & 15, lg = lane >> 4;
    const int m0 = blockIdx.x * 128, n0 = blockIdx.y * 128;

    const int col8 = (((lane & 7) ^ ((lane >> 3) & 7)) * 8);
    const unsigned short* aG = A + (size_t)(m0 + wid * 32 + (lane >> 3)) * lda + col8;
    const unsigned short* bG = Bt + (size_t)(n0 + wid * 32 + (lane >> 3)) * K + col8;
    unsigned short* aL = As + wid * 2048;
    unsigned short* bL = Bs + wid * 2048;

    f32x4 acc[4][4] = {};

    for (int k0 = 0; k0 < K; k0 += 64) {
#pragma unroll
        for (int i = 0; i < 4; ++i)
            gload16(aG + (size_t)(i * 8) * lda + k0, aL + i * 512);
#pragma unroll
        for (int i = 0; i < 4; ++i)
            gload16(bG + (size_t)(i * 8) * K + k0, bL + i * 512);
        __syncthreads();
#pragma unroll
        for (int kk = 0; kk < 2; ++kk) {
            const int slot = ((kk * 4 + lg) ^ (lr & 7)) * 8;
            bf16x8 aF[4], bF[4];
#pragma unroll
            for (int mi = 0; mi < 4; ++mi)
                aF[mi] = *(const bf16x8*)&As[(wrow * 64 + mi * 16 + lr) * 64 + slot];
#pragma unroll
            for (int ni = 0; ni < 4; ++ni)
                bF[ni] = *(const bf16x8*)&Bs[(wcol * 64 + ni * 16 + lr) * 64 + slot];
#pragma unroll
            for (int mi = 0; mi < 4; ++mi)
#pragma unroll
                for (int ni = 0; ni < 4; ++ni)
                    acc[mi][ni] = __builtin_amdgcn_mfma_f32_16x16x32_bf16(aF[mi], bF[ni], acc[mi][ni], 0, 0, 0);
        }
        __syncthreads();
    }
    // fused epilogue: col<1024 q-rope, col<1536 k-rope(+k_news), else v-transpose(+v_news)
#pragma unroll
    for (int mi = 0; mi < 4; ++mi)
#pragma unroll
        for (int ni = 0; ni < 4; ++ni) {
            int col = n0 + wcol * 64 + ni * 16 + lr;
            int s0r = m0 + wrow * 64 + mi * 16 + lg * 4;
            if (col < 1536) {
                int p = (col & 63) >> 1;
                int odd = col & 1;
#pragma unroll
                for (int r = 0; r < 4; ++r) {
                    float v = acc[mi][ni][r];
                    float o = __shfl_xor(v, 1);
                    int s = s0r + r;
                    float c = fc[s * 32 + p], sn = fs[s * 32 + p];
                    float res = odd ? (o * sn + v * c) : (v * c - o * sn);
                    int dpos = (odd ? 32 : 0) + p;
                    if (col < 1024) {
                        qb[(size_t)s * 1024 + (col >> 6) * 64 + dpos] = f2bf(res);
                    } else {
                        int kcol = ((col >> 6) - 16) * 64 + dpos;
                        kb[(size_t)s * 512 + kcol] = f2bf(res);
                        if (s == S_LEN - 1)
                            out[LOGITS + (size_t)layer * 512 + kcol] = res;
                    }
                }
            } else {
                int d = col - 1536;
                ushort4v vv;
#pragma unroll
                for (int r = 0; r < 4; ++r) vv[r] = f2bf(acc[mi][ni][r]);
                *(ushort4v*)&vT[(size_t)d * 2048 + s0r] = vv;
                if (s0r + 3 == S_LEN - 1)
                    out[LOGITS + 2 * 512 + (size_t)layer * 512 + d] = acc[mi][ni][3];
            }
        }
}

// ---------------- GEMM BM=64, BN=128 (for N=1024 outputs: full-chip grid 32x8) ----------------
__global__ __launch_bounds__(256) void gemm_tn64(const unsigned short* __restrict__ A, int lda,
                                                 const unsigned short* __restrict__ Bt,
                                                 float* __restrict__ Cf,
                                                 const float* __restrict__ addsrc,
                                                 int N, int K) {
    __shared__ unsigned short As[64 * 64];
    __shared__ unsigned short Bs[128 * 64];
    int tid = threadIdx.x;
    int lane = tid & 63;
    int wid = tid >> 6;
    int lr = lane & 15, lg = lane >> 4;
    const int m0 = blockIdx.x * 64, n0 = blockIdx.y * 128;

    const int srow = tid >> 3;
    const int col8 = (((tid & 7) ^ ((tid >> 3) & 7)) * 8);
    const unsigned short* aG = A + (size_t)(m0 + srow) * lda + col8;
    const unsigned short* bG = Bt + (size_t)(n0 + srow) * K + col8;
    unsigned short* aL = As + wid * 512;
    unsigned short* bL = Bs + wid * 512;

    f32x4 acc[4][2] = {};

    for (int k0 = 0; k0 < K; k0 += 64) {
        gload16(aG + k0, aL);
        gload16(aG + (size_t)32 * lda + k0, aL + 2048);
#pragma unroll
        for (int i = 0; i < 4; ++i)
            gload16(bG + (size_t)(i * 32) * K + k0, bL + i * 2048);
        __syncthreads();
#pragma unroll
        for (int kk = 0; kk < 2; ++kk) {
            const int slot = ((kk * 4 + lg) ^ (lr & 7)) * 8;
            bf16x8 aF[4], bF[2];
#pragma unroll
            for (int mi = 0; mi < 4; ++mi)
                aF[mi] = *(const bf16x8*)&As[(mi * 16 + lr) * 64 + slot];
#pragma unroll
            for (int ni = 0; ni < 2; ++ni)
                bF[ni] = *(const bf16x8*)&Bs[(wid * 32 + ni * 16 + lr) * 64 + slot];
#pragma unroll
            for (int mi = 0; mi < 4; ++mi)
#pragma unroll
                for (int ni = 0; ni < 2; ++ni)
                    acc[mi][ni] = __builtin_amdgcn_mfma_f32_16x16x32_bf16(aF[mi], bF[ni], acc[mi][ni], 0, 0, 0);
        }
        __syncthreads();
    }
#pragma unroll
    for (int mi = 0; mi < 4; ++mi)
#pragma unroll
        for (int ni = 0; ni < 2; ++ni) {
            int row = m0 + mi * 16 + lg * 4;
            int col = n0 + wid * 32 + ni * 16 + lr;
#pragma unroll
            for (int r = 0; r < 4; ++r) {
                size_t idx = (size_t)(row + r) * N + col;
                float v = acc[mi][ni][r];
                if (addsrc) v += addsrc[idx];
                Cf[idx] = v;
            }
        }
}

// ---------------- GEMM 256^2 8-phase BK=64 (T1..T5); FUSE=1: silu(even)*odd -> bf16 [.][2816] ----------------
template<int FUSE>
__global__ __launch_bounds__(512) void gemm8(const unsigned short* __restrict__ A,
                                             const unsigned short* __restrict__ Bt,
                                             float* __restrict__ Cf,
                                             unsigned short* __restrict__ Cb,
                                             int N, int K) {
    __shared__ unsigned short ldsbuf[65536];
    const int NT = K >> 6;
    int tid = threadIdx.x;
    int lane = tid & 63;
    int wid = tid >> 6;
    int wm = wid >> 2, wn = wid & 3;
    int lr = lane & 15, lg = lane >> 4;
    int wl = blockIdx.x * gridDim.y + blockIdx.y;
    const int m0 = (wl & 7) * 256, n0 = (wl >> 3) * 256;

    unsigned lds0 = (unsigned)(size_t)(__attribute__((address_space(3))) unsigned short*)ldsbuf;
    const unsigned xoff = (unsigned)((lg ^ ((lr >> 1) & 3)) * 16);
    const int gsw = (lane & 3) ^ ((lane >> 3) & 3);
    const int srow = wid * 16 + (lane >> 2);

#define STAGE(buf, ab, s, t) do {                                                   \
        const unsigned short* _src = (ab) ? Bt : A;                                 \
        int _r0 = (ab) ? n0 : m0;                                                   \
        unsigned short* _l = ldsbuf + (((buf) * 2 + (ab)) * 2 + (s)) * 8192 + wid * 512; \
        const unsigned short* _g = _src + (size_t)(_r0 + srow) * K + (size_t)(t) * 64 + (s) * 32 + gsw * 8; \
        gload16(_g, _l);                                                            \
        gload16(_g + (size_t)128 * K, _l + 4096);                                   \
    } while (0)

    f32x4 acc[8][4] = {};

    STAGE(0, 0, 0, 0); STAGE(0, 1, 0, 0);
    STAGE(0, 0, 1, 0); STAGE(0, 1, 1, 0);
    STAGE(1, 0, 0, 1); STAGE(1, 1, 0, 1);
    WAITV(8);
    BAR();

    for (int t = 0; t < NT; ++t) {
        int buf = t & 1;
        unsigned aBase = lds0 + (unsigned)(buf * 65536) + (unsigned)((wm * 128 + lr) * 64) + xoff;
        unsigned bBase = lds0 + (unsigned)(buf * 65536 + 32768) + (unsigned)((wn * 64 + lr) * 64) + xoff;
        Frag aF[4], bF[4];
#pragma unroll
        for (int s = 0; s < 2; ++s) {
#pragma unroll
            for (int ni = 0; ni < 4; ++ni)
                bF[ni].f = lds_read_b128(bBase + (unsigned)(s * 16384 + ni * 1024));
#pragma unroll
            for (int mi = 0; mi < 4; ++mi)
                aF[mi].f = lds_read_b128(aBase + (unsigned)(s * 16384 + mi * 1024));
            if (s == 0) { if (t + 1 < NT) STAGE(buf ^ 1, 0, 1, t + 1); }
            else        { if (t + 2 < NT) STAGE(buf,     0, 0, t + 2); }
            BAR();
            LGKM0();
            __builtin_amdgcn_s_setprio(1);
#pragma unroll
            for (int mi = 0; mi < 4; ++mi)
#pragma unroll
                for (int ni = 0; ni < 4; ++ni)
                    acc[mi][ni] = __builtin_amdgcn_mfma_f32_16x16x32_bf16(aF[mi].h, bF[ni].h, acc[mi][ni], 0, 0, 0);
            __builtin_amdgcn_s_setprio(0);
            BAR();
#pragma unroll
            for (int mi = 0; mi < 4; ++mi)
                aF[mi].f = lds_read_b128(aBase + (unsigned)(4096 + s * 16384 + mi * 1024));
            if (s == 0) { if (t + 1 < NT) STAGE(buf ^ 1, 1, 1, t + 1); }
            else        { if (t + 2 < NT) STAGE(buf,     1, 0, t + 2); }
            BAR();
            LGKM0();
            __builtin_amdgcn_s_setprio(1);
#pragma unroll
            for (int mi = 0; mi < 4; ++mi)
#pragma unroll
                for (int ni = 0; ni < 4; ++ni)
                    acc[4 + mi][ni] = __builtin_amdgcn_mfma_f32_16x16x32_bf16(aF[mi].h, bF[ni].h, acc[4 + mi][ni], 0, 0, 0);
            __builtin_amdgcn_s_setprio(0);
            if (s == 0) {
                if (t + 1 < NT) { WAITV(8); } else { WAITV(0); }
            } else {
                if (t + 2 < NT)      { WAITV(8); }
                else if (t + 1 < NT) { WAITV(4); }
            }
            BAR();
        }
    }
#undef STAGE

#pragma unroll
    for (int mi = 0; mi < 8; ++mi)
#pragma unroll
        for (int ni = 0; ni < 4; ++ni) {
            int row = m0 + wm * 128 + mi * 16 + lg * 4;
            int col = n0 + wn * 64 + ni * 16 + lr;
#pragma unroll
            for (int r = 0; r < 4; ++r) {
                float v = acc[mi][ni][r];
                if (FUSE) {
                    float o = __shfl_xor(v, 1);
                    if (!(lr & 1)) {
                        float res = v / (1.f + __expf(-v)) * o;
                        Cb[(size_t)(row + r) * (HID) + (col >> 1)] = f2bf(res);
                    }
                } else {
                    Cf[(size_t)(row + r) * N + col] = v;
                }
            }
        }
}

// ---------------- GEMM 256^2 BK=32, 64 KB LDS -> 2 blocks/CU (logits) ----------------
// Race-free staging: SA(t+1) issued ph0 (targets idle buf^1); SB(t+2) issued ph1
// (buf's B last read drained at the post-MFMA barrier of ph0); end-of-tile vmcnt(2).
__global__ __launch_bounds__(512) void gemm8k32(const unsigned short* __restrict__ A,
                                                const unsigned short* __restrict__ Bt,
                                                float* __restrict__ Cf,
                                                int N, int K) {
    __shared__ unsigned short ldsbuf[32768];   // 64 KB: [buf][ab] x 256 rows x 32 k
    const int NT = K >> 5;
    int tid = threadIdx.x;
    int lane = tid & 63;
    int wid = tid >> 6;
    int wm = wid >> 2, wn = wid & 3;
    int lr = lane & 15, lg = lane >> 4;
    int wl = blockIdx.x * gridDim.y + blockIdx.y;
    const int m0 = (wl & 7) * 256, n0 = (wl >> 3) * 256;

    unsigned lds0 = (unsigned)(size_t)(__attribute__((address_space(3))) unsigned short*)ldsbuf;
    const unsigned xoff = (unsigned)((lg ^ ((lr >> 1) & 3)) * 16);
    const int gsw = (lane & 3) ^ ((lane >> 3) & 3);
    const int srow = wid * 16 + (lane >> 2);

#define STGA(t) do { \
        unsigned short* _l = ldsbuf + (((t) & 1) * 2 + 0) * 8192 + wid * 512; \
        const unsigned short* _g = A + (size_t)(m0 + srow) * K + (size_t)(t) * 32 + gsw * 8; \
        gload16(_g, _l); \
        gload16(_g + (size_t)128 * K, _l + 4096); \
    } while (0)
#define STGB(t) do { \
        unsigned short* _l = ldsbuf + (((t) & 1) * 2 + 1) * 8192 + wid * 512; \
        const unsigned short* _g = Bt + (size_t)(n0 + srow) * K + (size_t)(t) * 32 + gsw * 8; \
        gload16(_g, _l); \
        gload16(_g + (size_t)128 * K, _l + 4096); \
    } while (0)

    f32x4 acc[8][4] = {};

    STGA(0); STGB(0); STGB(1);
    WAITV(2);
    BAR();

    for (int t = 0; t < NT; ++t) {
        int buf = t & 1;
        unsigned aBase = lds0 + (unsigned)(buf * 32768) + (unsigned)((wm * 128 + lr) * 64) + xoff;
        unsigned bBase = lds0 + (unsigned)(buf * 32768 + 16384) + (unsigned)((wn * 64 + lr) * 64) + xoff;
        Frag aF[4], bF[4];
        // ---- ph0: read B + A(mh0); issue SA(t+1) into buf^1 ----
#pragma unroll
        for (int ni = 0; ni < 4; ++ni)
            bF[ni].f = lds_read_b128(bBase + (unsigned)(ni * 1024));
#pragma unroll
        for (int mi = 0; mi < 4; ++mi)
            aF[mi].f = lds_read_b128(aBase + (unsigned)(mi * 1024));
        if (t + 1 < NT) STGA(t + 1);
        BAR();
        LGKM0();
        __builtin_amdgcn_s_setprio(1);
#pragma unroll
        for (int mi = 0; mi < 4; ++mi)
#pragma unroll
            for (int ni = 0; ni < 4; ++ni)
                acc[mi][ni] = __builtin_amdgcn_mfma_f32_16x16x32_bf16(aF[mi].h, bF[ni].h, acc[mi][ni], 0, 0, 0);
        __builtin_amdgcn_s_setprio(0);
        BAR();
        // ---- ph1: read A(mh1); issue SB(t+2) into buf (B fully read in ph0) ----
#pragma unroll
        for (int mi = 0; mi < 4; ++mi)
            aF[mi].f = lds_read_b128(aBase + (unsigned)(4096 + mi * 1024));
        if (t + 2 < NT) STGB(t + 2);
        BAR();
        LGKM0();
        __builtin_amdgcn_s_setprio(1);
#pragma unroll
        for (int mi = 0; mi < 4; ++mi)
#pragma unroll
            for (int ni = 0; ni < 4; ++ni)
                acc[4 + mi][ni] = __builtin_amdgcn_mfma_f32_16x16x32_bf16(aF[mi].h, bF[ni].h, acc[4 + mi][ni], 0, 0, 0);
        __builtin_amdgcn_s_setprio(0);
        if (t + 2 < NT)      { WAITV(2); }
        else if (t + 1 < NT) { WAITV(0); }
        BAR();
    }
#undef STGA
#undef STGB

#pragma unroll
    for (int mi = 0; mi < 8; ++mi)
#pragma unroll
        for (int ni = 0; ni < 4; ++ni) {
            int row = m0 + wm * 128 + mi * 16 + lg * 4;
            int col = n0 + wn * 64 + ni * 16 + lr;
#pragma unroll
            for (int r = 0; r < 4; ++r)
                Cf[(size_t)(row + r) * N + col] = acc[mi][ni][r];
        }
}

// ---------------- flash attention: 4-wave blocks, 32 q-rows, balanced big-first grid ----------------
__global__ __launch_bounds__(256) void attn_kernel(const unsigned short* __restrict__ qb,
                                                   const unsigned short* __restrict__ kb,
                                                   const unsigned short* __restrict__ vT,
                                                   unsigned short* __restrict__ yb) {
    __shared__ unsigned short Klds[2][4096];
    __shared__ unsigned short Vlds[2][4096];
    __shared__ unsigned short P[4][16 * 72];
    int kvh = blockIdx.x;
    int strip = 63 - blockIdx.y;
    int tid = threadIdx.x;
    int lane = tid & 63;
    int w = tid >> 6;
    int hq = w & 1, qsub = w >> 1;
    int h = kvh * 2 + hq;
    int lr = lane & 15, lg = lane >> 4;
    int qbase = strip * 32 + qsub * 16;
    int qrow = qbase + lr;

    const int sr = tid >> 3;
    const int scol8 = (((tid & 7) ^ (sr & 7)) * 8);
    const int NT = (strip >> 1) + 1;

#define STAGEKV(buf, kt) do { \
        gload16(&kb[(size_t)((kt) * 64 + sr) * 512 + kvh * 64 + scol8], &Klds[buf][w * 512]); \
        gload16(&kb[(size_t)((kt) * 64 + sr + 32) * 512 + kvh * 64 + scol8], &Klds[buf][2048 + w * 512]); \
        gload16(&vT[(size_t)(kvh * 64 + sr) * 2048 + (kt) * 64 + scol8], &Vlds[buf][w * 512]); \
        gload16(&vT[(size_t)(kvh * 64 + sr + 32) * 2048 + (kt) * 64 + scol8], &Vlds[buf][2048 + w * 512]); \
    } while (0)

    bf16x8 bq[2];
#pragma unroll
    for (int c = 0; c < 2; ++c)
        bq[c] = *(const bf16x8*)&qb[(size_t)qrow * (NH * HD) + h * HD + c * 32 + lg * 8];

    f32x4 O[4] = {};
    float mstate = -1e30f, lstate = 0.f;

    STAGEKV(0, 0);
    WAITV(0);
    BAR();

    for (int kt = 0; kt < NT; ++kt) {
        int buf = kt & 1;
        if (kt + 1 < NT) STAGEKV(buf ^ 1, kt + 1);
        f32x4 s[4];
#pragma unroll
        for (int kc = 0; kc < 4; ++kc) {
            int krl = kc * 16 + lr;
            const unsigned short* kp = &Klds[buf][krl * 64];
            bf16x8 ak0 = *(const bf16x8*)&kp[((lg ^ (lr & 7)) * 8)];
            bf16x8 ak1 = *(const bf16x8*)&kp[(((4 + lg) ^ (lr & 7)) * 8)];
            f32x4 z = {};
            z = __builtin_amdgcn_mfma_f32_16x16x32_bf16(ak0, bq[0], z, 0, 0, 0);
            z = __builtin_amdgcn_mfma_f32_16x16x32_bf16(ak1, bq[1], z, 0, 0, 0);
            s[kc] = z;
        }
        float tm = -1e30f;
#pragma unroll
        for (int kc = 0; kc < 4; ++kc)
#pragma unroll
            for (int r = 0; r < 4; ++r) {
                int key = kt * 64 + kc * 16 + lg * 4 + r;
                float val = s[kc][r] * 0.125f;
                if (key > qrow) val = -1e30f;
                s[kc][r] = val;
                tm = fmaxf(tm, val);
            }
        tm = fmaxf(tm, __shfl_xor(tm, 16));
        tm = fmaxf(tm, __shfl_xor(tm, 32));
        float mn = fmaxf(mstate, tm);
        float sc = __expf(mstate - mn);
        float rs = 0.f;
        ushort4v pk[4];
#pragma unroll
        for (int kc = 0; kc < 4; ++kc)
#pragma unroll
            for (int r = 0; r < 4; ++r) {
                float pf = __expf(s[kc][r] - mn);
                rs += pf;
                pk[kc][r] = f2bf(pf);
            }
        rs += __shfl_xor(rs, 16);
        rs += __shfl_xor(rs, 32);
        lstate = lstate * sc + rs;
        mstate = mn;
        float osc[4];
#pragma unroll
        for (int r = 0; r < 4; ++r)
            osc[r] = __shfl(sc, lg * 4 + r);
#pragma unroll
        for (int n = 0; n < 4; ++n)
#pragma unroll
            for (int r = 0; r < 4; ++r)
                O[n][r] *= osc[r];
#pragma unroll
        for (int kc = 0; kc < 4; ++kc)
            *(ushort4v*)&P[w][lr * 72 + kc * 16 + lg * 4] = pk[kc];
        bf16x8 pa[2];
#pragma unroll
        for (int g = 0; g < 2; ++g)
            pa[g] = *(const bf16x8*)&P[w][lr * 72 + g * 32 + lg * 8];
#pragma unroll
        for (int n = 0; n < 4; ++n) {
            const unsigned short* vp = &Vlds[buf][(n * 16 + lr) * 64];
#pragma unroll
            for (int g = 0; g < 2; ++g) {
                bf16x8 bv = *(const bf16x8*)&vp[(((g * 4 + lg) ^ (lr & 7)) * 8)];
                O[n] = __builtin_amdgcn_mfma_f32_16x16x32_bf16(pa[g], bv, O[n], 0, 0, 0);
            }
        }
        if (kt + 1 < NT) WAITV(0);
        LGKM0();
        BAR();
    }
#undef STAGEKV

    float linv[4];
#pragma unroll
    for (int r = 0; r < 4; ++r)
        linv[r] = 1.f / __shfl(lstate, lg * 4 + r);
#pragma unroll
    for (int n = 0; n < 4; ++n)
#pragma unroll
        for (int r = 0; r < 4; ++r) {
            int row = qbase + lg * 4 + r;
            yb[(size_t)row * (NH * HD) + h * HD + n * 16 + lr] = f2bf(O[n][r] * linv[r]);
        }
}

extern "C" void kernel_launch(void* const* d_in, const int* in_sizes, int n_in,
                              void* d_out, int out_size, void* d_ws, size_t ws_size,
                              hipStream_t stream) {
    const int* tokens = (const int*)d_in[0];
    const float* freqs_cos = (const float*)d_in[2];
    const float* freqs_sin = (const float*)d_in[3];
    const float* tok_emb = (const float*)d_in[4];
    const float* wq = (const float*)d_in[5];
    const float* wk = (const float*)d_in[6];
    const float* wv = (const float*)d_in[7];
    const float* wo = (const float*)d_in[8];
    const float* attn_norm_w = (const float*)d_in[9];
    const float* ffn_norm_w = (const float*)d_in[10];
    const float* w1 = (const float*)d_in[11];
    const float* w2 = (const float*)d_in[12];
    const float* w3 = (const float*)d_in[13];
    const float* final_norm_w = (const float*)d_in[14];
    const float* out_w = (const float*)d_in[15];
    float* out = (float*)d_out;

    const size_t SD = (size_t)S_LEN * DIM;
    const size_t SKV = (size_t)S_LEN * NKV * HD;

    char* p = (char*)d_ws;
    auto take = [&](size_t bytes) { char* r = p; p += (bytes + 255) & ~(size_t)255; return r; };
    float* h            = (float*)take(SD * 4);
    unsigned short* xnb = (unsigned short*)take(SD * 2);
    char* uni = p;
    unsigned short* qb  = (unsigned short*)uni;                         // 4 MB
    unsigned short* kb  = qb + SD;                                      // 2 MB
    unsigned short* vT  = kb + SKV;                                     // 2 MB
    unsigned short* ybv = vT + SKV;                                     // 4 MB
    unsigned short* gu  = ybv + SD;                                     // 11.5 MB ([S][2816])
    unsigned short* wT  = gu + (size_t)S_LEN * HID;                     // 11.5 MB
    unsigned short* owT = (unsigned short*)uni;                         // 65.5 MB (final phase)

    embed_kernel<<<S_LEN, 256, 0, stream>>>(tokens, tok_emb, h);
    for (int l = 0; l < 2; ++l) {
        rmsnorm_kernel<<<S_LEN, 256, 0, stream>>>(h, attn_norm_w + l * DIM, xnb);
        transpose_qkv<<<dim3(16, 16, 3), 256, 0, stream>>>(
            wq + (size_t)l * DIM * 1024, wk + (size_t)l * DIM * 512, wv + (size_t)l * DIM * 512, wT);
        gemm_qkv<<<dim3(16, 16), 256, 0, stream>>>(xnb, wT, freqs_cos, freqs_sin,
                                                   qb, kb, vT, out, l);
        attn_kernel<<<dim3(NKV, 64), 256, 0, stream>>>(qb, kb, vT, ybv);
        transpose_w<<<dim3(16, 16), 256, 0, stream>>>(wo + (size_t)l * 1024 * DIM, wT, 1024, DIM);
        gemm_tn64<<<dim3(32, 8), 256, 0, stream>>>(ybv, 1024, wT, h, h, DIM, 1024);
        rmsnorm_kernel<<<S_LEN, 256, 0, stream>>>(h, ffn_norm_w + l * DIM, xnb);
        transpose_w13<<<dim3(44, 16, 2), 256, 0, stream>>>(
            w1 + (size_t)l * DIM * HID, w3 + (size_t)l * DIM * HID, wT);
        gemm8<1><<<dim3(8, 22), 512, 0, stream>>>(xnb, wT, nullptr, gu, 5632, DIM);
        transpose_w<<<dim3(16, 44), 256, 0, stream>>>(w2 + (size_t)l * HID * 1024, wT, HID, 1024);
        gemm_tn64<<<dim3(32, 8), 256, 0, stream>>>(gu, HID, wT, h, h, DIM, HID);
    }
    rmsnorm_kernel<<<S_LEN, 256, 0, stream>>>(h, final_norm_w, xnb);
    transpose_w<<<dim3(500, 16), 256, 0, stream>>>(out_w, owT, DIM, 32000);
    gemm8k32<<<dim3(8, 125), 512, 0, stream>>>(xnb, owT, out, 32000, DIM);
}

// Round 11
// 631.829 us; speedup vs baseline: 1.5157x; 1.0242x over previous
//
#include <hip/hip_runtime.h>
#include <hip/hip_bf16.h>

typedef __bf16 bf16x8 __attribute__((ext_vector_type(8)));
typedef float f32x4 __attribute__((ext_vector_type(4)));
typedef unsigned short ushort4v __attribute__((ext_vector_type(4)));
typedef unsigned short ushort8v __attribute__((ext_vector_type(8)));

#define S_LEN 2048
#define DIM 1024
#define NH 16
#define NKV 8
#define HD 64
#define HID 2816
#define LOGITS ((size_t)S_LEN * 32000)

__device__ __forceinline__ unsigned short f2bf(float f) {
    union { float f; unsigned u; } v; v.f = f;
    unsigned r = v.u + 0x7fffu + ((v.u >> 16) & 1u);   // RNE
    return (unsigned short)(r >> 16);
}
__device__ __forceinline__ float bf2f(unsigned short u) {
    union { unsigned u; float f; } v; v.u = (unsigned)u << 16; return v.f;
}

__device__ __forceinline__ void gload16(const unsigned short* g, unsigned short* l) {
    __builtin_amdgcn_global_load_lds(
        (const __attribute__((address_space(1))) unsigned int*)g,
        (__attribute__((address_space(3))) unsigned int*)l,
        16, 0, 0);
}

union Frag { f32x4 f; bf16x8 h; };

__device__ __forceinline__ f32x4 lds_read_b128(unsigned addr) {
    f32x4 d;
    asm volatile("ds_read_b128 %0, %1" : "=v"(d) : "v"(addr));
    return d;
}

#define BAR()  asm volatile("s_barrier" ::: "memory")
#define WAITV(n) asm volatile("s_waitcnt vmcnt(" #n ")" ::: "memory")
#define LGKM0() do { asm volatile("s_waitcnt lgkmcnt(0)" ::: "memory"); __builtin_amdgcn_sched_barrier(0); } while (0)

// ---------------- embedding gather ----------------
__global__ __launch_bounds__(256) void embed_kernel(const int* __restrict__ tokens,
                                                    const float* __restrict__ emb,
                                                    float* __restrict__ h) {
    int s = blockIdx.x;
    int t = tokens[s];
    float4 v = *(const float4*)&emb[(size_t)t * DIM + threadIdx.x * 4];
    *(float4*)&h[(size_t)s * DIM + threadIdx.x * 4] = v;
}

// ---------------- rmsnorm: f32 in -> bf16 out ----------------
__global__ __launch_bounds__(256) void rmsnorm_kernel(const float* __restrict__ x,
                                                      const float* __restrict__ w,
                                                      unsigned short* __restrict__ out) {
    __shared__ float sred[4];
    int s = blockIdx.x;
    int tid = threadIdx.x;
    float4 v = *(const float4*)&x[(size_t)s * DIM + tid * 4];
    float ss = v.x * v.x + v.y * v.y + v.z * v.z + v.w * v.w;
#pragma unroll
    for (int off = 32; off; off >>= 1) ss += __shfl_down(ss, off);
    if ((tid & 63) == 0) sred[tid >> 6] = ss;
    __syncthreads();
    float tot = sred[0] + sred[1] + sred[2] + sred[3];
    float scale = rsqrtf(tot * (1.0f / DIM) + 1e-5f);
    float4 wv = *(const float4*)&w[tid * 4];
    ushort4v o;
    o[0] = f2bf(v.x * scale * wv.x); o[1] = f2bf(v.y * scale * wv.y);
    o[2] = f2bf(v.z * scale * wv.z); o[3] = f2bf(v.w * scale * wv.w);
    *(ushort4v*)&out[(size_t)s * DIM + tid * 4] = o;
}

// ---------------- transpose body: f32 [K][N] tile -> bf16 [rowMul*n+rowOff][K] ----------------
__device__ __forceinline__ void tpose_body(const float* __restrict__ in,
                                           unsigned short* __restrict__ out,
                                           int K, int N, int n0, int k0,
                                           int rowMul, int rowOff) {
    __shared__ unsigned short t[64][68];
    int tid = threadIdx.x;
    int tn = tid & 15, tk = tid >> 4;
#pragma unroll
    for (int p = 0; p < 4; ++p) {
        int k = tk + p * 16;
        float4 v = *(const float4*)&in[(size_t)(k0 + k) * N + n0 + tn * 4];
        t[tn * 4 + 0][k] = f2bf(v.x);
        t[tn * 4 + 1][k] = f2bf(v.y);
        t[tn * 4 + 2][k] = f2bf(v.z);
        t[tn * 4 + 3][k] = f2bf(v.w);
    }
    __syncthreads();
    int wk = tid & 15, wn = tid >> 4;
#pragma unroll
    for (int p = 0; p < 4; ++p) {
        int n = wn + p * 16;
        ushort4v v;
        v[0] = t[n][wk * 4]; v[1] = t[n][wk * 4 + 1];
        v[2] = t[n][wk * 4 + 2]; v[3] = t[n][wk * 4 + 3];
        *(ushort4v*)&out[(size_t)(rowMul * (n0 + n) + rowOff) * K + k0 + wk * 4] = v;
    }
}

__global__ __launch_bounds__(256) void transpose_w(const float* __restrict__ in,
                                                   unsigned short* __restrict__ out,
                                                   int K, int N) {
    tpose_body(in, out, K, N, blockIdx.x * 64, blockIdx.y * 64, 1, 0);
}

// ---------------- mega transpose: ALL weights of one layer in one dispatch (2880 blocks) ----------------
// sections: [0,256) wq | [256,384) wk | [384,512) wv | [512,768) wo
//           [768,1472) w1(interleave even) | [1472,2176) w3(odd) | [2176,2880) w2
__global__ __launch_bounds__(256) void transpose_layer(const float* __restrict__ wq,
                                                       const float* __restrict__ wk,
                                                       const float* __restrict__ wv,
                                                       const float* __restrict__ wo,
                                                       const float* __restrict__ w1,
                                                       const float* __restrict__ w3,
                                                       const float* __restrict__ w2,
                                                       unsigned short* __restrict__ wTqkv,
                                                       unsigned short* __restrict__ wTo,
                                                       unsigned short* __restrict__ wT13,
                                                       unsigned short* __restrict__ wT2) {
    int id = blockIdx.x;
    if (id < 256) {
        tpose_body(wq, wTqkv, 1024, 1024, (id & 15) * 64, (id >> 4) * 64, 1, 0);
    } else if (id < 384) {
        int i = id - 256;
        tpose_body(wk, wTqkv, 1024, 512, (i & 7) * 64, (i >> 3) * 64, 1, 1024);
    } else if (id < 512) {
        int i = id - 384;
        tpose_body(wv, wTqkv, 1024, 512, (i & 7) * 64, (i >> 3) * 64, 1, 1536);
    } else if (id < 768) {
        int i = id - 512;
        tpose_body(wo, wTo, 1024, 1024, (i & 15) * 64, (i >> 4) * 64, 1, 0);
    } else if (id < 1472) {
        int i = id - 768;
        tpose_body(w1, wT13, 1024, HID, (i % 44) * 64, (i / 44) * 64, 2, 0);
    } else if (id < 2176) {
        int i = id - 1472;
        tpose_body(w3, wT13, 1024, HID, (i % 44) * 64, (i / 44) * 64, 2, 1);
    } else {
        int i = id - 2176;
        tpose_body(w2, wT2, 2816, 1024, (i & 15) * 64, (i >> 4) * 64, 1, 0);
    }
}

// ---------------- qkv GEMM 128^2 double-buffered + fused RoPE/V-transpose/news epilogue ----------------
__global__ __launch_bounds__(256) void gemm_qkv(const unsigned short* __restrict__ A,
                                                const unsigned short* __restrict__ Bt,
                                                const float* __restrict__ fc,
                                                const float* __restrict__ fs,
                                                unsigned short* __restrict__ qb,
                                                unsigned short* __restrict__ kb,
                                                unsigned short* __restrict__ vT,
                                                float* __restrict__ out, int layer) {
    __shared__ unsigned short As[2][128 * 64];
    __shared__ unsigned short Bs[2][128 * 64];
    const int K = DIM, lda = DIM;
    int tid = threadIdx.x;
    int lane = tid & 63;
    int wid = tid >> 6;
    int wrow = wid >> 1, wcol = wid & 1;
    int lr = lane & 15, lg = lane >> 4;
    const int m0 = blockIdx.x * 128, n0 = blockIdx.y * 128;

    const int col8 = (((lane & 7) ^ ((lane >> 3) & 7)) * 8);
    const unsigned short* aG = A + (size_t)(m0 + wid * 32 + (lane >> 3)) * lda + col8;
    const unsigned short* bG = Bt + (size_t)(n0 + wid * 32 + (lane >> 3)) * K + col8;
    const int NT = K >> 6;

#define STG128(buf, k0) do {                                                  \
        unsigned short* _aL = &As[buf][wid * 2048];                           \
        unsigned short* _bL = &Bs[buf][wid * 2048];                           \
        _Pragma("unroll")                                                     \
        for (int _i = 0; _i < 4; ++_i) {                                      \
            gload16(aG + (size_t)(_i * 8) * lda + (k0), _aL + _i * 512);      \
            gload16(bG + (size_t)(_i * 8) * K + (k0), _bL + _i * 512);        \
        }                                                                     \
    } while (0)

    f32x4 acc[4][4] = {};
    STG128(0, 0);
    WAITV(0);
    BAR();

    for (int t = 0; t < NT; ++t) {
        int buf = t & 1;
        if (t + 1 < NT) STG128(buf ^ 1, (t + 1) * 64);
#pragma unroll
        for (int kk = 0; kk < 2; ++kk) {
            const int slot = ((kk * 4 + lg) ^ (lr & 7)) * 8;
            bf16x8 aF[4], bF[4];
#pragma unroll
            for (int mi = 0; mi < 4; ++mi)
                aF[mi] = *(const bf16x8*)&As[buf][(wrow * 64 + mi * 16 + lr) * 64 + slot];
#pragma unroll
            for (int ni = 0; ni < 4; ++ni)
                bF[ni] = *(const bf16x8*)&Bs[buf][(wcol * 64 + ni * 16 + lr) * 64 + slot];
#pragma unroll
            for (int mi = 0; mi < 4; ++mi)
#pragma unroll
                for (int ni = 0; ni < 4; ++ni)
                    acc[mi][ni] = __builtin_amdgcn_mfma_f32_16x16x32_bf16(aF[mi], bF[ni], acc[mi][ni], 0, 0, 0);
        }
        if (t + 1 < NT) WAITV(0);
        BAR();
    }
#undef STG128

    // fused epilogue: col<1024 q-rope, col<1536 k-rope(+k_news), else v-transpose(+v_news)
#pragma unroll
    for (int mi = 0; mi < 4; ++mi)
#pragma unroll
        for (int ni = 0; ni < 4; ++ni) {
            int col = n0 + wcol * 64 + ni * 16 + lr;
            int s0r = m0 + wrow * 64 + mi * 16 + lg * 4;
            if (col < 1536) {
                int p = (col & 63) >> 1;
                int odd = col & 1;
#pragma unroll
                for (int r = 0; r < 4; ++r) {
                    float v = acc[mi][ni][r];
                    float o = __shfl_xor(v, 1);
                    int s = s0r + r;
                    float c = fc[s * 32 + p], sn = fs[s * 32 + p];
                    float res = odd ? (o * sn + v * c) : (v * c - o * sn);
                    int dpos = (odd ? 32 : 0) + p;
                    if (col < 1024) {
                        qb[(size_t)s * 1024 + (col >> 6) * 64 + dpos] = f2bf(res);
                    } else {
                        int kcol = ((col >> 6) - 16) * 64 + dpos;
                        kb[(size_t)s * 512 + kcol] = f2bf(res);
                        if (s == S_LEN - 1)
                            out[LOGITS + (size_t)layer * 512 + kcol] = res;
                    }
                }
            } else {
                int d = col - 1536;
                ushort4v vv;
#pragma unroll
                for (int r = 0; r < 4; ++r) vv[r] = f2bf(acc[mi][ni][r]);
                *(ushort4v*)&vT[(size_t)d * 2048 + s0r] = vv;
                if (s0r + 3 == S_LEN - 1)
                    out[LOGITS + 2 * 512 + (size_t)layer * 512 + d] = acc[mi][ni][3];
            }
        }
}

// ---------------- GEMM 128^2 double-buffered; FUSE=1: silu(even)*odd -> bf16 [.][HID] ----------------
template<int FUSE>
__global__ __launch_bounds__(256) void gemm_tn128(const unsigned short* __restrict__ A, int lda,
                                                  const unsigned short* __restrict__ Bt,
                                                  float* __restrict__ Cf,
                                                  unsigned short* __restrict__ Cb,
                                                  const float* __restrict__ addsrc,
                                                  int N, int K) {
    __shared__ unsigned short As[2][128 * 64];
    __shared__ unsigned short Bs[2][128 * 64];
    int tid = threadIdx.x;
    int lane = tid & 63;
    int wid = tid >> 6;
    int wrow = wid >> 1, wcol = wid & 1;
    int lr = lane & 15, lg = lane >> 4;
    const int m0 = blockIdx.x * 128, n0 = blockIdx.y * 128;

    const int col8 = (((lane & 7) ^ ((lane >> 3) & 7)) * 8);
    const unsigned short* aG = A + (size_t)(m0 + wid * 32 + (lane >> 3)) * lda + col8;
    const unsigned short* bG = Bt + (size_t)(n0 + wid * 32 + (lane >> 3)) * K + col8;
    const int NT = K >> 6;

#define STG128(buf, k0) do {                                                  \
        unsigned short* _aL = &As[buf][wid * 2048];                           \
        unsigned short* _bL = &Bs[buf][wid * 2048];                           \
        _Pragma("unroll")                                                     \
        for (int _i = 0; _i < 4; ++_i) {                                      \
            gload16(aG + (size_t)(_i * 8) * lda + (k0), _aL + _i * 512);      \
            gload16(bG + (size_t)(_i * 8) * K + (k0), _bL + _i * 512);        \
        }                                                                     \
    } while (0)

    f32x4 acc[4][4] = {};
    STG128(0, 0);
    WAITV(0);
    BAR();

    for (int t = 0; t < NT; ++t) {
        int buf = t & 1;
        if (t + 1 < NT) STG128(buf ^ 1, (t + 1) * 64);
#pragma unroll
        for (int kk = 0; kk < 2; ++kk) {
            const int slot = ((kk * 4 + lg) ^ (lr & 7)) * 8;
            bf16x8 aF[4], bF[4];
#pragma unroll
            for (int mi = 0; mi < 4; ++mi)
                aF[mi] = *(const bf16x8*)&As[buf][(wrow * 64 + mi * 16 + lr) * 64 + slot];
#pragma unroll
            for (int ni = 0; ni < 4; ++ni)
                bF[ni] = *(const bf16x8*)&Bs[buf][(wcol * 64 + ni * 16 + lr) * 64 + slot];
#pragma unroll
            for (int mi = 0; mi < 4; ++mi)
#pragma unroll
                for (int ni = 0; ni < 4; ++ni)
                    acc[mi][ni] = __builtin_amdgcn_mfma_f32_16x16x32_bf16(aF[mi], bF[ni], acc[mi][ni], 0, 0, 0);
        }
        if (t + 1 < NT) WAITV(0);
        BAR();
    }
#undef STG128

#pragma unroll
    for (int mi = 0; mi < 4; ++mi)
#pragma unroll
        for (int ni = 0; ni < 4; ++ni) {
            int row = m0 + wrow * 64 + mi * 16 + lg * 4;
            int col = n0 + wcol * 64 + ni * 16 + lr;
#pragma unroll
            for (int r = 0; r < 4; ++r) {
                float v = acc[mi][ni][r];
                if (FUSE) {
                    float o = __shfl_xor(v, 1);
                    if (!(lr & 1))
                        Cb[(size_t)(row + r) * HID + (col >> 1)] = f2bf(v / (1.f + __expf(-v)) * o);
                } else {
                    size_t idx = (size_t)(row + r) * N + col;
                    if (addsrc) v += addsrc[idx];
                    if (Cb) Cb[idx] = f2bf(v);
                    else    Cf[idx] = v;
                }
            }
        }
}

// ---------------- GEMM BM=64, BN=128, double-buffered (N=1024 outputs: grid 32x8) ----------------
__global__ __launch_bounds__(256) void gemm_tn64(const unsigned short* __restrict__ A, int lda,
                                                 const unsigned short* __restrict__ Bt,
                                                 float* __restrict__ Cf,
                                                 const float* __restrict__ addsrc,
                                                 int N, int K) {
    __shared__ unsigned short As[2][64 * 64];
    __shared__ unsigned short Bs[2][128 * 64];
    int tid = threadIdx.x;
    int lane = tid & 63;
    int wid = tid >> 6;
    int lr = lane & 15, lg = lane >> 4;
    const int m0 = blockIdx.x * 64, n0 = blockIdx.y * 128;

    const int srow = tid >> 3;
    const int col8 = (((tid & 7) ^ ((tid >> 3) & 7)) * 8);
    const unsigned short* aG = A + (size_t)(m0 + srow) * lda + col8;
    const unsigned short* bG = Bt + (size_t)(n0 + srow) * K + col8;
    const int NT = K >> 6;

#define STG64(buf, k0) do {                                                   \
        gload16(aG + (k0), &As[buf][wid * 512]);                              \
        gload16(aG + (size_t)32 * lda + (k0), &As[buf][wid * 512 + 2048]);    \
        _Pragma("unroll")                                                     \
        for (int _i = 0; _i < 4; ++_i)                                        \
            gload16(bG + (size_t)(_i * 32) * K + (k0), &Bs[buf][wid * 512 + _i * 2048]); \
    } while (0)

    f32x4 acc[4][2] = {};
    STG64(0, 0);
    WAITV(0);
    BAR();

    for (int t = 0; t < NT; ++t) {
        int buf = t & 1;
        if (t + 1 < NT) STG64(buf ^ 1, (t + 1) * 64);
#pragma unroll
        for (int kk = 0; kk < 2; ++kk) {
            const int slot = ((kk * 4 + lg) ^ (lr & 7)) * 8;
            bf16x8 aF[4], bF[2];
#pragma unroll
            for (int mi = 0; mi < 4; ++mi)
                aF[mi] = *(const bf16x8*)&As[buf][(mi * 16 + lr) * 64 + slot];
#pragma unroll
            for (int ni = 0; ni < 2; ++ni)
                bF[ni] = *(const bf16x8*)&Bs[buf][(wid * 32 + ni * 16 + lr) * 64 + slot];
#pragma unroll
            for (int mi = 0; mi < 4; ++mi)
#pragma unroll
                for (int ni = 0; ni < 2; ++ni)
                    acc[mi][ni] = __builtin_amdgcn_mfma_f32_16x16x32_bf16(aF[mi], bF[ni], acc[mi][ni], 0, 0, 0);
        }
        if (t + 1 < NT) WAITV(0);
        BAR();
    }
#undef STG64

#pragma unroll
    for (int mi = 0; mi < 4; ++mi)
#pragma unroll
        for (int ni = 0; ni < 2; ++ni) {
            int row = m0 + mi * 16 + lg * 4;
            int col = n0 + wid * 32 + ni * 16 + lr;
#pragma unroll
            for (int r = 0; r < 4; ++r) {
                size_t idx = (size_t)(row + r) * N + col;
                float v = acc[mi][ni][r];
                if (addsrc) v += addsrc[idx];
                Cf[idx] = v;
            }
        }
}

// ---------------- GEMM 256^2 BK=32 2-phase prefetch (logits) ----------------
__global__ __launch_bounds__(512) void gemm8k32(const unsigned short* __restrict__ A,
                                                const unsigned short* __restrict__ Bt,
                                                float* __restrict__ Cf,
                                                int N, int K) {
    __shared__ unsigned short ldsbuf[32768];
    const int NT = K >> 5;
    int tid = threadIdx.x;
    int lane = tid & 63;
    int wid = tid >> 6;
    int wm = wid >> 2, wn = wid & 3;
    int lr = lane & 15, lg = lane >> 4;
    int wl = blockIdx.x * gridDim.y + blockIdx.y;
    const int m0 = (wl & 7) * 256, n0 = (wl >> 3) * 256;

    unsigned lds0 = (unsigned)(size_t)(__attribute__((address_space(3))) unsigned short*)ldsbuf;
    const unsigned xoff = (unsigned)((lg ^ ((lr >> 1) & 3)) * 16);
    const int gsw = (lane & 3) ^ ((lane >> 3) & 3);
    const int srow = wid * 16 + (lane >> 2);

#define STGA(t) do { \
        unsigned short* _l = ldsbuf + (((t) & 1) * 2 + 0) * 8192 + wid * 512; \
        const unsigned short* _g = A + (size_t)(m0 + srow) * K + (size_t)(t) * 32 + gsw * 8; \
        gload16(_g, _l); \
        gload16(_g + (size_t)128 * K, _l + 4096); \
    } while (0)
#define STGB(t) do { \
        unsigned short* _l = ldsbuf + (((t) & 1) * 2 + 1) * 8192 + wid * 512; \
        const unsigned short* _g = Bt + (size_t)(n0 + srow) * K + (size_t)(t) * 32 + gsw * 8; \
        gload16(_g, _l); \
        gload16(_g + (size_t)128 * K, _l + 4096); \
    } while (0)

    f32x4 acc[8][4] = {};

    STGA(0); STGB(0); STGB(1);
    WAITV(2);
    BAR();

    for (int t = 0; t < NT; ++t) {
        int buf = t & 1;
        unsigned aBase = lds0 + (unsigned)(buf * 32768) + (unsigned)((wm * 128 + lr) * 64) + xoff;
        unsigned bBase = lds0 + (unsigned)(buf * 32768 + 16384) + (unsigned)((wn * 64 + lr) * 64) + xoff;
        Frag aF[4], bF[4];
#pragma unroll
        for (int ni = 0; ni < 4; ++ni)
            bF[ni].f = lds_read_b128(bBase + (unsigned)(ni * 1024));
#pragma unroll
        for (int mi = 0; mi < 4; ++mi)
            aF[mi].f = lds_read_b128(aBase + (unsigned)(mi * 1024));
        if (t + 1 < NT) STGA(t + 1);
        BAR();
        LGKM0();
        __builtin_amdgcn_s_setprio(1);
#pragma unroll
        for (int mi = 0; mi < 4; ++mi)
#pragma unroll
            for (int ni = 0; ni < 4; ++ni)
                acc[mi][ni] = __builtin_amdgcn_mfma_f32_16x16x32_bf16(aF[mi].h, bF[ni].h, acc[mi][ni], 0, 0, 0);
        __builtin_amdgcn_s_setprio(0);
        BAR();
#pragma unroll
        for (int mi = 0; mi < 4; ++mi)
            aF[mi].f = lds_read_b128(aBase + (unsigned)(4096 + mi * 1024));
        if (t + 2 < NT) STGB(t + 2);
        BAR();
        LGKM0();
        __builtin_amdgcn_s_setprio(1);
#pragma unroll
        for (int mi = 0; mi < 4; ++mi)
#pragma unroll
            for (int ni = 0; ni < 4; ++ni)
                acc[4 + mi][ni] = __builtin_amdgcn_mfma_f32_16x16x32_bf16(aF[mi].h, bF[ni].h, acc[4 + mi][ni], 0, 0, 0);
        __builtin_amdgcn_s_setprio(0);
        if (t + 2 < NT)      { WAITV(2); }
        else if (t + 1 < NT) { WAITV(0); }
        BAR();
    }
#undef STGA
#undef STGB

#pragma unroll
    for (int mi = 0; mi < 8; ++mi)
#pragma unroll
        for (int ni = 0; ni < 4; ++ni) {
            int row = m0 + wm * 128 + mi * 16 + lg * 4;
            int col = n0 + wn * 64 + ni * 16 + lr;
#pragma unroll
            for (int r = 0; r < 4; ++r)
                Cf[(size_t)(row + r) * N + col] = acc[mi][ni][r];
        }
}

// ---------------- flash attention: 4-wave blocks, 32 q-rows, balanced big-first grid ----------------
__global__ __launch_bounds__(256) void attn_kernel(const unsigned short* __restrict__ qb,
                                                   const unsigned short* __restrict__ kb,
                                                   const unsigned short* __restrict__ vT,
                                                   unsigned short* __restrict__ yb) {
    __shared__ unsigned short Klds[2][4096];
    __shared__ unsigned short Vlds[2][4096];
    __shared__ unsigned short P[4][16 * 72];
    int kvh = blockIdx.x;
    int strip = 63 - blockIdx.y;
    int tid = threadIdx.x;
    int lane = tid & 63;
    int w = tid >> 6;
    int hq = w & 1, qsub = w >> 1;
    int h = kvh * 2 + hq;
    int lr = lane & 15, lg = lane >> 4;
    int qbase = strip * 32 + qsub * 16;
    int qrow = qbase + lr;

    const int sr = tid >> 3;
    const int scol8 = (((tid & 7) ^ (sr & 7)) * 8);
    const int NT = (strip >> 1) + 1;

#define STAGEKV(buf, kt) do { \
        gload16(&kb[(size_t)((kt) * 64 + sr) * 512 + kvh * 64 + scol8], &Klds[buf][w * 512]); \
        gload16(&kb[(size_t)((kt) * 64 + sr + 32) * 512 + kvh * 64 + scol8], &Klds[buf][2048 + w * 512]); \
        gload16(&vT[(size_t)(kvh * 64 + sr) * 2048 + (kt) * 64 + scol8], &Vlds[buf][w * 512]); \
        gload16(&vT[(size_t)(kvh * 64 + sr + 32) * 2048 + (kt) * 64 + scol8], &Vlds[buf][2048 + w * 512]); \
    } while (0)

    bf16x8 bq[2];
#pragma unroll
    for (int c = 0; c < 2; ++c)
        bq[c] = *(const bf16x8*)&qb[(size_t)qrow * (NH * HD) + h * HD + c * 32 + lg * 8];

    f32x4 O[4] = {};
    float mstate = -1e30f, lstate = 0.f;

    STAGEKV(0, 0);
    WAITV(0);
    BAR();

    for (int kt = 0; kt < NT; ++kt) {
        int buf = kt & 1;
        if (kt + 1 < NT) STAGEKV(buf ^ 1, kt + 1);
        f32x4 s[4];
#pragma unroll
        for (int kc = 0; kc < 4; ++kc) {
            int krl = kc * 16 + lr;
            const unsigned short* kp = &Klds[buf][krl * 64];
            bf16x8 ak0 = *(const bf16x8*)&kp[((lg ^ (lr & 7)) * 8)];
            bf16x8 ak1 = *(const bf16x8*)&kp[(((4 + lg) ^ (lr & 7)) * 8)];
            f32x4 z = {};
            z = __builtin_amdgcn_mfma_f32_16x16x32_bf16(ak0, bq[0], z, 0, 0, 0);
            z = __builtin_amdgcn_mfma_f32_16x16x32_bf16(ak1, bq[1], z, 0, 0, 0);
            s[kc] = z;
        }
        float tm = -1e30f;
#pragma unroll
        for (int kc = 0; kc < 4; ++kc)
#pragma unroll
            for (int r = 0; r < 4; ++r) {
                int key = kt * 64 + kc * 16 + lg * 4 + r;
                float val = s[kc][r] * 0.125f;
                if (key > qrow) val = -1e30f;
                s[kc][r] = val;
                tm = fmaxf(tm, val);
            }
        tm = fmaxf(tm, __shfl_xor(tm, 16));
        tm = fmaxf(tm, __shfl_xor(tm, 32));
        float mn = fmaxf(mstate, tm);
        float sc = __expf(mstate - mn);
        float rs = 0.f;
        ushort4v pk[4];
#pragma unroll
        for (int kc = 0; kc < 4; ++kc)
#pragma unroll
            for (int r = 0; r < 4; ++r) {
                float pf = __expf(s[kc][r] - mn);
                rs += pf;
                pk[kc][r] = f2bf(pf);
            }
        rs += __shfl_xor(rs, 16);
        rs += __shfl_xor(rs, 32);
        lstate = lstate * sc + rs;
        mstate = mn;
        float osc[4];
#pragma unroll
        for (int r = 0; r < 4; ++r)
            osc[r] = __shfl(sc, lg * 4 + r);
#pragma unroll
        for (int n = 0; n < 4; ++n)
#pragma unroll
            for (int r = 0; r < 4; ++r)
                O[n][r] *= osc[r];
#pragma unroll
        for (int kc = 0; kc < 4; ++kc)
            *(ushort4v*)&P[w][lr * 72 + kc * 16 + lg * 4] = pk[kc];
        bf16x8 pa[2];
#pragma unroll
        for (int g = 0; g < 2; ++g)
            pa[g] = *(const bf16x8*)&P[w][lr * 72 + g * 32 + lg * 8];
#pragma unroll
        for (int n = 0; n < 4; ++n) {
            const unsigned short* vp = &Vlds[buf][(n * 16 + lr) * 64];
#pragma unroll
            for (int g = 0; g < 2; ++g) {
                bf16x8 bv = *(const bf16x8*)&vp[(((g * 4 + lg) ^ (lr & 7)) * 8)];
                O[n] = __builtin_amdgcn_mfma_f32_16x16x32_bf16(pa[g], bv, O[n], 0, 0, 0);
            }
        }
        if (kt + 1 < NT) WAITV(0);
        LGKM0();
        BAR();
    }
#undef STAGEKV

    float linv[4];
#pragma unroll
    for (int r = 0; r < 4; ++r)
        linv[r] = 1.f / __shfl(lstate, lg * 4 + r);
#pragma unroll
    for (int n = 0; n < 4; ++n)
#pragma unroll
        for (int r = 0; r < 4; ++r) {
            int row = qbase + lg * 4 + r;
            yb[(size_t)row * (NH * HD) + h * HD + n * 16 + lr] = f2bf(O[n][r] * linv[r]);
        }
}

extern "C" void kernel_launch(void* const* d_in, const int* in_sizes, int n_in,
                              void* d_out, int out_size, void* d_ws, size_t ws_size,
                              hipStream_t stream) {
    const int* tokens = (const int*)d_in[0];
    const float* freqs_cos = (const float*)d_in[2];
    const float* freqs_sin = (const float*)d_in[3];
    const float* tok_emb = (const float*)d_in[4];
    const float* wq = (const float*)d_in[5];
    const float* wk = (const float*)d_in[6];
    const float* wv = (const float*)d_in[7];
    const float* wo = (const float*)d_in[8];
    const float* attn_norm_w = (const float*)d_in[9];
    const float* ffn_norm_w = (const float*)d_in[10];
    const float* w1 = (const float*)d_in[11];
    const float* w2 = (const float*)d_in[12];
    const float* w3 = (const float*)d_in[13];
    const float* final_norm_w = (const float*)d_in[14];
    const float* out_w = (const float*)d_in[15];
    float* out = (float*)d_out;

    const size_t SD = (size_t)S_LEN * DIM;
    const size_t SKV = (size_t)S_LEN * NKV * HD;

    char* p = (char*)d_ws;
    auto take = [&](size_t bytes) { char* r = p; p += (bytes + 255) & ~(size_t)255; return r; };
    float* h            = (float*)take(SD * 4);
    unsigned short* xnb = (unsigned short*)take(SD * 2);
    char* uni = p;
    unsigned short* qb    = (unsigned short*)uni;                       // 4 MB
    unsigned short* kb    = qb + SD;                                    // 2 MB
    unsigned short* vT    = kb + SKV;                                   // 2 MB
    unsigned short* ybv   = vT + SKV;                                   // 4 MB
    unsigned short* gu    = ybv + SD;                                   // 11.5 MB [S][2816]
    unsigned short* wTqkv = gu + (size_t)S_LEN * HID;                   // 4 MB   [2048][1024]
    unsigned short* wTo   = wTqkv + (size_t)2048 * DIM;                 // 2 MB   [1024][1024]
    unsigned short* wT13  = wTo + (size_t)DIM * DIM;                    // 11.5 MB [5632][1024]
    unsigned short* wT2   = wT13 + (size_t)2 * HID * DIM;               // 5.75 MB [1024][2816]
    unsigned short* owT   = (unsigned short*)uni;                       // 65.5 MB (final phase overlay)

    embed_kernel<<<S_LEN, 256, 0, stream>>>(tokens, tok_emb, h);
    for (int l = 0; l < 2; ++l) {
        rmsnorm_kernel<<<S_LEN, 256, 0, stream>>>(h, attn_norm_w + l * DIM, xnb);
        transpose_layer<<<2880, 256, 0, stream>>>(
            wq + (size_t)l * DIM * 1024, wk + (size_t)l * DIM * 512, wv + (size_t)l * DIM * 512,
            wo + (size_t)l * 1024 * DIM,
            w1 + (size_t)l * DIM * HID, w3 + (size_t)l * DIM * HID, w2 + (size_t)l * HID * 1024,
            wTqkv, wTo, wT13, wT2);
        gemm_qkv<<<dim3(16, 16), 256, 0, stream>>>(xnb, wTqkv, freqs_cos, freqs_sin,
                                                   qb, kb, vT, out, l);
        attn_kernel<<<dim3(NKV, 64), 256, 0, stream>>>(qb, kb, vT, ybv);
        gemm_tn64<<<dim3(32, 8), 256, 0, stream>>>(ybv, 1024, wTo, h, h, DIM, 1024);
        rmsnorm_kernel<<<S_LEN, 256, 0, stream>>>(h, ffn_norm_w + l * DIM, xnb);
        gemm_tn128<1><<<dim3(16, 44), 256, 0, stream>>>(xnb, DIM, wT13, nullptr, gu, nullptr, 5632, DIM);
        gemm_tn64<<<dim3(32, 8), 256, 0, stream>>>(gu, HID, wT2, h, h, DIM, HID);
    }
    rmsnorm_kernel<<<S_LEN, 256, 0, stream>>>(h, final_norm_w, xnb);
    transpose_w<<<dim3(500, 16), 256, 0, stream>>>(out_w, owT, DIM, 32000);
    gemm8k32<<<dim3(8, 125), 512, 0, stream>>>(xnb, owT, out, 32000, DIM);
}

// Round 12
// 631.258 us; speedup vs baseline: 1.5171x; 1.0009x over previous
//
#include <hip/hip_runtime.h>
#include <hip/hip_bf16.h>

typedef __bf16 bf16x8 __attribute__((ext_vector_type(8)));
typedef float f32x4 __attribute__((ext_vector_type(4)));
typedef unsigned short ushort4v __attribute__((ext_vector_type(4)));
typedef unsigned short ushort8v __attribute__((ext_vector_type(8)));

#define S_LEN 2048
#define DIM 1024
#define NH 16
#define NKV 8
#define HD 64
#define HID 2816
#define LOGITS ((size_t)S_LEN * 32000)

__device__ __forceinline__ unsigned short f2bf(float f) {
    union { float f; unsigned u; } v; v.f = f;
    unsigned r = v.u + 0x7fffu + ((v.u >> 16) & 1u);   // RNE
    return (unsigned short)(r >> 16);
}
__device__ __forceinline__ float bf2f(unsigned short u) {
    union { unsigned u; float f; } v; v.u = (unsigned)u << 16; return v.f;
}

__device__ __forceinline__ void gload16(const unsigned short* g, unsigned short* l) {
    __builtin_amdgcn_global_load_lds(
        (const __attribute__((address_space(1))) unsigned int*)g,
        (__attribute__((address_space(3))) unsigned int*)l,
        16, 0, 0);
}

union Frag { f32x4 f; bf16x8 h; };

__device__ __forceinline__ f32x4 lds_read_b128(unsigned addr) {
    f32x4 d;
    asm volatile("ds_read_b128 %0, %1" : "=v"(d) : "v"(addr));
    return d;
}

#define BAR()  asm volatile("s_barrier" ::: "memory")
#define WAITV(n) asm volatile("s_waitcnt vmcnt(" #n ")" ::: "memory")
#define LGKM0() do { asm volatile("s_waitcnt lgkmcnt(0)" ::: "memory"); __builtin_amdgcn_sched_barrier(0); } while (0)

// ---------------- embedding gather ----------------
__global__ __launch_bounds__(256) void embed_kernel(const int* __restrict__ tokens,
                                                    const float* __restrict__ emb,
                                                    float* __restrict__ h) {
    int s = blockIdx.x;
    int t = tokens[s];
    float4 v = *(const float4*)&emb[(size_t)t * DIM + threadIdx.x * 4];
    *(float4*)&h[(size_t)s * DIM + threadIdx.x * 4] = v;
}

// ---------------- rmsnorm: f32 in -> bf16 out ----------------
__global__ __launch_bounds__(256) void rmsnorm_kernel(const float* __restrict__ x,
                                                      const float* __restrict__ w,
                                                      unsigned short* __restrict__ out) {
    __shared__ float sred[4];
    int s = blockIdx.x;
    int tid = threadIdx.x;
    float4 v = *(const float4*)&x[(size_t)s * DIM + tid * 4];
    float ss = v.x * v.x + v.y * v.y + v.z * v.z + v.w * v.w;
#pragma unroll
    for (int off = 32; off; off >>= 1) ss += __shfl_down(ss, off);
    if ((tid & 63) == 0) sred[tid >> 6] = ss;
    __syncthreads();
    float tot = sred[0] + sred[1] + sred[2] + sred[3];
    float scale = rsqrtf(tot * (1.0f / DIM) + 1e-5f);
    float4 wv = *(const float4*)&w[tid * 4];
    ushort4v o;
    o[0] = f2bf(v.x * scale * wv.x); o[1] = f2bf(v.y * scale * wv.y);
    o[2] = f2bf(v.z * scale * wv.z); o[3] = f2bf(v.w * scale * wv.w);
    *(ushort4v*)&out[(size_t)s * DIM + tid * 4] = o;
}

// ---------------- transpose body: f32 [K][N] tile -> bf16 [rowMul*n+rowOff][K] ----------------
__device__ __forceinline__ void tpose_body(const float* __restrict__ in,
                                           unsigned short* __restrict__ out,
                                           int K, int N, int n0, int k0,
                                           int rowMul, int rowOff) {
    __shared__ unsigned short t[64][68];
    int tid = threadIdx.x;
    int tn = tid & 15, tk = tid >> 4;
#pragma unroll
    for (int p = 0; p < 4; ++p) {
        int k = tk + p * 16;
        float4 v = *(const float4*)&in[(size_t)(k0 + k) * N + n0 + tn * 4];
        t[tn * 4 + 0][k] = f2bf(v.x);
        t[tn * 4 + 1][k] = f2bf(v.y);
        t[tn * 4 + 2][k] = f2bf(v.z);
        t[tn * 4 + 3][k] = f2bf(v.w);
    }
    __syncthreads();
    int wk = tid & 15, wn = tid >> 4;
#pragma unroll
    for (int p = 0; p < 4; ++p) {
        int n = wn + p * 16;
        ushort4v v;
        v[0] = t[n][wk * 4]; v[1] = t[n][wk * 4 + 1];
        v[2] = t[n][wk * 4 + 2]; v[3] = t[n][wk * 4 + 3];
        *(ushort4v*)&out[(size_t)(rowMul * (n0 + n) + rowOff) * K + k0 + wk * 4] = v;
    }
}

__global__ __launch_bounds__(256) void transpose_w(const float* __restrict__ in,
                                                   unsigned short* __restrict__ out,
                                                   int K, int N) {
    tpose_body(in, out, K, N, blockIdx.x * 64, blockIdx.y * 64, 1, 0);
}

// ---------------- mega transpose: ALL weights of one layer in one dispatch (2880 blocks) ----------------
// sections: [0,256) wq | [256,384) wk | [384,512) wv | [512,768) wo
//           [768,1472) w1(interleave even) | [1472,2176) w3(odd) | [2176,2880) w2
__global__ __launch_bounds__(256) void transpose_layer(const float* __restrict__ wq,
                                                       const float* __restrict__ wk,
                                                       const float* __restrict__ wv,
                                                       const float* __restrict__ wo,
                                                       const float* __restrict__ w1,
                                                       const float* __restrict__ w3,
                                                       const float* __restrict__ w2,
                                                       unsigned short* __restrict__ wTqkv,
                                                       unsigned short* __restrict__ wTo,
                                                       unsigned short* __restrict__ wT13,
                                                       unsigned short* __restrict__ wT2) {
    int id = blockIdx.x;
    if (id < 256) {
        tpose_body(wq, wTqkv, 1024, 1024, (id & 15) * 64, (id >> 4) * 64, 1, 0);
    } else if (id < 384) {
        int i = id - 256;
        tpose_body(wk, wTqkv, 1024, 512, (i & 7) * 64, (i >> 3) * 64, 1, 1024);
    } else if (id < 512) {
        int i = id - 384;
        tpose_body(wv, wTqkv, 1024, 512, (i & 7) * 64, (i >> 3) * 64, 1, 1536);
    } else if (id < 768) {
        int i = id - 512;
        tpose_body(wo, wTo, 1024, 1024, (i & 15) * 64, (i >> 4) * 64, 1, 0);
    } else if (id < 1472) {
        int i = id - 768;
        tpose_body(w1, wT13, 1024, HID, (i % 44) * 64, (i / 44) * 64, 2, 0);
    } else if (id < 2176) {
        int i = id - 1472;
        tpose_body(w3, wT13, 1024, HID, (i % 44) * 64, (i / 44) * 64, 2, 1);
    } else {
        int i = id - 2176;
        tpose_body(w2, wT2, 2816, 1024, (i & 15) * 64, (i >> 4) * 64, 1, 0);
    }
}

// ---------------- qkv GEMM 128^2 double-buffered + fused RoPE/V-transpose/news epilogue ----------------
__global__ __launch_bounds__(256) void gemm_qkv(const unsigned short* __restrict__ A,
                                                const unsigned short* __restrict__ Bt,
                                                const float* __restrict__ fc,
                                                const float* __restrict__ fs,
                                                unsigned short* __restrict__ qb,
                                                unsigned short* __restrict__ kb,
                                                unsigned short* __restrict__ vT,
                                                float* __restrict__ out, int layer) {
    __shared__ unsigned short As[2][128 * 64];
    __shared__ unsigned short Bs[2][128 * 64];
    const int K = DIM, lda = DIM;
    int tid = threadIdx.x;
    int lane = tid & 63;
    int wid = tid >> 6;
    int wrow = wid >> 1, wcol = wid & 1;
    int lr = lane & 15, lg = lane >> 4;
    const int m0 = blockIdx.x * 128, n0 = blockIdx.y * 128;

    const int col8 = (((lane & 7) ^ ((lane >> 3) & 7)) * 8);
    const unsigned short* aG = A + (size_t)(m0 + wid * 32 + (lane >> 3)) * lda + col8;
    const unsigned short* bG = Bt + (size_t)(n0 + wid * 32 + (lane >> 3)) * K + col8;
    const int NT = K >> 6;

#define STG128(buf, k0) do {                                                  \
        unsigned short* _aL = &As[buf][wid * 2048];                           \
        unsigned short* _bL = &Bs[buf][wid * 2048];                           \
        _Pragma("unroll")                                                     \
        for (int _i = 0; _i < 4; ++_i) {                                      \
            gload16(aG + (size_t)(_i * 8) * lda + (k0), _aL + _i * 512);      \
            gload16(bG + (size_t)(_i * 8) * K + (k0), _bL + _i * 512);        \
        }                                                                     \
    } while (0)

    f32x4 acc[4][4] = {};
    STG128(0, 0);
    WAITV(0);
    BAR();

    for (int t = 0; t < NT; ++t) {
        int buf = t & 1;
        if (t + 1 < NT) STG128(buf ^ 1, (t + 1) * 64);
#pragma unroll
        for (int kk = 0; kk < 2; ++kk) {
            const int slot = ((kk * 4 + lg) ^ (lr & 7)) * 8;
            bf16x8 aF[4], bF[4];
#pragma unroll
            for (int mi = 0; mi < 4; ++mi)
                aF[mi] = *(const bf16x8*)&As[buf][(wrow * 64 + mi * 16 + lr) * 64 + slot];
#pragma unroll
            for (int ni = 0; ni < 4; ++ni)
                bF[ni] = *(const bf16x8*)&Bs[buf][(wcol * 64 + ni * 16 + lr) * 64 + slot];
#pragma unroll
            for (int mi = 0; mi < 4; ++mi)
#pragma unroll
                for (int ni = 0; ni < 4; ++ni)
                    acc[mi][ni] = __builtin_amdgcn_mfma_f32_16x16x32_bf16(aF[mi], bF[ni], acc[mi][ni], 0, 0, 0);
        }
        if (t + 1 < NT) WAITV(0);
        BAR();
    }
#undef STG128

    // fused epilogue: col<1024 q-rope, col<1536 k-rope(+k_news), else v-transpose(+v_news)
#pragma unroll
    for (int mi = 0; mi < 4; ++mi)
#pragma unroll
        for (int ni = 0; ni < 4; ++ni) {
            int col = n0 + wcol * 64 + ni * 16 + lr;
            int s0r = m0 + wrow * 64 + mi * 16 + lg * 4;
            if (col < 1536) {
                int p = (col & 63) >> 1;
                int odd = col & 1;
#pragma unroll
                for (int r = 0; r < 4; ++r) {
                    float v = acc[mi][ni][r];
                    float o = __shfl_xor(v, 1);
                    int s = s0r + r;
                    float c = fc[s * 32 + p], sn = fs[s * 32 + p];
                    float res = odd ? (o * sn + v * c) : (v * c - o * sn);
                    int dpos = (odd ? 32 : 0) + p;
                    if (col < 1024) {
                        qb[(size_t)s * 1024 + (col >> 6) * 64 + dpos] = f2bf(res);
                    } else {
                        int kcol = ((col >> 6) - 16) * 64 + dpos;
                        kb[(size_t)s * 512 + kcol] = f2bf(res);
                        if (s == S_LEN - 1)
                            out[LOGITS + (size_t)layer * 512 + kcol] = res;
                    }
                }
            } else {
                int d = col - 1536;
                ushort4v vv;
#pragma unroll
                for (int r = 0; r < 4; ++r) vv[r] = f2bf(acc[mi][ni][r]);
                *(ushort4v*)&vT[(size_t)d * 2048 + s0r] = vv;
                if (s0r + 3 == S_LEN - 1)
                    out[LOGITS + 2 * 512 + (size_t)layer * 512 + d] = acc[mi][ni][3];
            }
        }
}

// ---------------- GEMM 128^2 double-buffered; FUSE=1: silu(even)*odd -> bf16 [.][HID] ----------------
template<int FUSE>
__global__ __launch_bounds__(256) void gemm_tn128(const unsigned short* __restrict__ A, int lda,
                                                  const unsigned short* __restrict__ Bt,
                                                  float* __restrict__ Cf,
                                                  unsigned short* __restrict__ Cb,
                                                  const float* __restrict__ addsrc,
                                                  int N, int K) {
    __shared__ unsigned short As[2][128 * 64];
    __shared__ unsigned short Bs[2][128 * 64];
    int tid = threadIdx.x;
    int lane = tid & 63;
    int wid = tid >> 6;
    int wrow = wid >> 1, wcol = wid & 1;
    int lr = lane & 15, lg = lane >> 4;
    const int m0 = blockIdx.x * 128, n0 = blockIdx.y * 128;

    const int col8 = (((lane & 7) ^ ((lane >> 3) & 7)) * 8);
    const unsigned short* aG = A + (size_t)(m0 + wid * 32 + (lane >> 3)) * lda + col8;
    const unsigned short* bG = Bt + (size_t)(n0 + wid * 32 + (lane >> 3)) * K + col8;
    const int NT = K >> 6;

#define STG128(buf, k0) do {                                                  \
        unsigned short* _aL = &As[buf][wid * 2048];                           \
        unsigned short* _bL = &Bs[buf][wid * 2048];                           \
        _Pragma("unroll")                                                     \
        for (int _i = 0; _i < 4; ++_i) {                                      \
            gload16(aG + (size_t)(_i * 8) * lda + (k0), _aL + _i * 512);      \
            gload16(bG + (size_t)(_i * 8) * K + (k0), _bL + _i * 512);        \
        }                                                                     \
    } while (0)

    f32x4 acc[4][4] = {};
    STG128(0, 0);
    WAITV(0);
    BAR();

    for (int t = 0; t < NT; ++t) {
        int buf = t & 1;
        if (t + 1 < NT) STG128(buf ^ 1, (t + 1) * 64);
#pragma unroll
        for (int kk = 0; kk < 2; ++kk) {
            const int slot = ((kk * 4 + lg) ^ (lr & 7)) * 8;
            bf16x8 aF[4], bF[4];
#pragma unroll
            for (int mi = 0; mi < 4; ++mi)
                aF[mi] = *(const bf16x8*)&As[buf][(wrow * 64 + mi * 16 + lr) * 64 + slot];
#pragma unroll
            for (int ni = 0; ni < 4; ++ni)
                bF[ni] = *(const bf16x8*)&Bs[buf][(wcol * 64 + ni * 16 + lr) * 64 + slot];
#pragma unroll
            for (int mi = 0; mi < 4; ++mi)
#pragma unroll
                for (int ni = 0; ni < 4; ++ni)
                    acc[mi][ni] = __builtin_amdgcn_mfma_f32_16x16x32_bf16(aF[mi], bF[ni], acc[mi][ni], 0, 0, 0);
        }
        if (t + 1 < NT) WAITV(0);
        BAR();
    }
#undef STG128

#pragma unroll
    for (int mi = 0; mi < 4; ++mi)
#pragma unroll
        for (int ni = 0; ni < 4; ++ni) {
            int row = m0 + wrow * 64 + mi * 16 + lg * 4;
            int col = n0 + wcol * 64 + ni * 16 + lr;
#pragma unroll
            for (int r = 0; r < 4; ++r) {
                float v = acc[mi][ni][r];
                if (FUSE) {
                    float o = __shfl_xor(v, 1);
                    if (!(lr & 1))
                        Cb[(size_t)(row + r) * HID + (col >> 1)] = f2bf(v / (1.f + __expf(-v)) * o);
                } else {
                    size_t idx = (size_t)(row + r) * N + col;
                    if (addsrc) v += addsrc[idx];
                    if (Cb) Cb[idx] = f2bf(v);
                    else    Cf[idx] = v;
                }
            }
        }
}

// ---------------- GEMM BM=64, BN=128, double-buffered (N=1024 outputs: grid 32x8) ----------------
__global__ __launch_bounds__(256) void gemm_tn64(const unsigned short* __restrict__ A, int lda,
                                                 const unsigned short* __restrict__ Bt,
                                                 float* __restrict__ Cf,
                                                 const float* __restrict__ addsrc,
                                                 int N, int K) {
    __shared__ unsigned short As[2][64 * 64];
    __shared__ unsigned short Bs[2][128 * 64];
    int tid = threadIdx.x;
    int lane = tid & 63;
    int wid = tid >> 6;
    int lr = lane & 15, lg = lane >> 4;
    const int m0 = blockIdx.x * 64, n0 = blockIdx.y * 128;

    const int srow = tid >> 3;
    const int col8 = (((tid & 7) ^ ((tid >> 3) & 7)) * 8);
    const unsigned short* aG = A + (size_t)(m0 + srow) * lda + col8;
    const unsigned short* bG = Bt + (size_t)(n0 + srow) * K + col8;
    const int NT = K >> 6;

#define STG64(buf, k0) do {                                                   \
        gload16(aG + (k0), &As[buf][wid * 512]);                              \
        gload16(aG + (size_t)32 * lda + (k0), &As[buf][wid * 512 + 2048]);    \
        _Pragma("unroll")                                                     \
        for (int _i = 0; _i < 4; ++_i)                                        \
            gload16(bG + (size_t)(_i * 32) * K + (k0), &Bs[buf][wid * 512 + _i * 2048]); \
    } while (0)

    f32x4 acc[4][2] = {};
    STG64(0, 0);
    WAITV(0);
    BAR();

    for (int t = 0; t < NT; ++t) {
        int buf = t & 1;
        if (t + 1 < NT) STG64(buf ^ 1, (t + 1) * 64);
#pragma unroll
        for (int kk = 0; kk < 2; ++kk) {
            const int slot = ((kk * 4 + lg) ^ (lr & 7)) * 8;
            bf16x8 aF[4], bF[2];
#pragma unroll
            for (int mi = 0; mi < 4; ++mi)
                aF[mi] = *(const bf16x8*)&As[buf][(mi * 16 + lr) * 64 + slot];
#pragma unroll
            for (int ni = 0; ni < 2; ++ni)
                bF[ni] = *(const bf16x8*)&Bs[buf][(wid * 32 + ni * 16 + lr) * 64 + slot];
#pragma unroll
            for (int mi = 0; mi < 4; ++mi)
#pragma unroll
                for (int ni = 0; ni < 2; ++ni)
                    acc[mi][ni] = __builtin_amdgcn_mfma_f32_16x16x32_bf16(aF[mi], bF[ni], acc[mi][ni], 0, 0, 0);
        }
        if (t + 1 < NT) WAITV(0);
        BAR();
    }
#undef STG64

#pragma unroll
    for (int mi = 0; mi < 4; ++mi)
#pragma unroll
        for (int ni = 0; ni < 2; ++ni) {
            int row = m0 + mi * 16 + lg * 4;
            int col = n0 + wid * 32 + ni * 16 + lr;
#pragma unroll
            for (int r = 0; r < 4; ++r) {
                size_t idx = (size_t)(row + r) * N + col;
                float v = acc[mi][ni][r];
                if (addsrc) v += addsrc[idx];
                Cf[idx] = v;
            }
        }
}

// ---------------- GEMM 256^2 BK=32 2-phase prefetch (logits) ----------------
__global__ __launch_bounds__(512) void gemm8k32(const unsigned short* __restrict__ A,
                                                const unsigned short* __restrict__ Bt,
                                                float* __restrict__ Cf,
                                                int N, int K) {
    __shared__ unsigned short ldsbuf[32768];
    const int NT = K >> 5;
    int tid = threadIdx.x;
    int lane = tid & 63;
    int wid = tid >> 6;
    int wm = wid >> 2, wn = wid & 3;
    int lr = lane & 15, lg = lane >> 4;
    int wl = blockIdx.x * gridDim.y + blockIdx.y;
    const int m0 = (wl & 7) * 256, n0 = (wl >> 3) * 256;

    unsigned lds0 = (unsigned)(size_t)(__attribute__((address_space(3))) unsigned short*)ldsbuf;
    const unsigned xoff = (unsigned)((lg ^ ((lr >> 1) & 3)) * 16);
    const int gsw = (lane & 3) ^ ((lane >> 3) & 3);
    const int srow = wid * 16 + (lane >> 2);

#define STGA(t) do { \
        unsigned short* _l = ldsbuf + (((t) & 1) * 2 + 0) * 8192 + wid * 512; \
        const unsigned short* _g = A + (size_t)(m0 + srow) * K + (size_t)(t) * 32 + gsw * 8; \
        gload16(_g, _l); \
        gload16(_g + (size_t)128 * K, _l + 4096); \
    } while (0)
#define STGB(t) do { \
        unsigned short* _l = ldsbuf + (((t) & 1) * 2 + 1) * 8192 + wid * 512; \
        const unsigned short* _g = Bt + (size_t)(n0 + srow) * K + (size_t)(t) * 32 + gsw * 8; \
        gload16(_g, _l); \
        gload16(_g + (size_t)128 * K, _l + 4096); \
    } while (0)

    f32x4 acc[8][4] = {};

    STGA(0); STGB(0); STGB(1);
    WAITV(2);
    BAR();

    for (int t = 0; t < NT; ++t) {
        int buf = t & 1;
        unsigned aBase = lds0 + (unsigned)(buf * 32768) + (unsigned)((wm * 128 + lr) * 64) + xoff;
        unsigned bBase = lds0 + (unsigned)(buf * 32768 + 16384) + (unsigned)((wn * 64 + lr) * 64) + xoff;
        Frag aF[4], bF[4];
#pragma unroll
        for (int ni = 0; ni < 4; ++ni)
            bF[ni].f = lds_read_b128(bBase + (unsigned)(ni * 1024));
#pragma unroll
        for (int mi = 0; mi < 4; ++mi)
            aF[mi].f = lds_read_b128(aBase + (unsigned)(mi * 1024));
        if (t + 1 < NT) STGA(t + 1);
        BAR();
        LGKM0();
        __builtin_amdgcn_s_setprio(1);
#pragma unroll
        for (int mi = 0; mi < 4; ++mi)
#pragma unroll
            for (int ni = 0; ni < 4; ++ni)
                acc[mi][ni] = __builtin_amdgcn_mfma_f32_16x16x32_bf16(aF[mi].h, bF[ni].h, acc[mi][ni], 0, 0, 0);
        __builtin_amdgcn_s_setprio(0);
        BAR();
#pragma unroll
        for (int mi = 0; mi < 4; ++mi)
            aF[mi].f = lds_read_b128(aBase + (unsigned)(4096 + mi * 1024));
        if (t + 2 < NT) STGB(t + 2);
        BAR();
        LGKM0();
        __builtin_amdgcn_s_setprio(1);
#pragma unroll
        for (int mi = 0; mi < 4; ++mi)
#pragma unroll
            for (int ni = 0; ni < 4; ++ni)
                acc[4 + mi][ni] = __builtin_amdgcn_mfma_f32_16x16x32_bf16(aF[mi].h, bF[ni].h, acc[4 + mi][ni], 0, 0, 0);
        __builtin_amdgcn_s_setprio(0);
        if (t + 2 < NT)      { WAITV(2); }
        else if (t + 1 < NT) { WAITV(0); }
        BAR();
    }
#undef STGA
#undef STGB

#pragma unroll
    for (int mi = 0; mi < 8; ++mi)
#pragma unroll
        for (int ni = 0; ni < 4; ++ni) {
            int row = m0 + wm * 128 + mi * 16 + lg * 4;
            int col = n0 + wn * 64 + ni * 16 + lr;
#pragma unroll
            for (int r = 0; r < 4; ++r)
                Cf[(size_t)(row + r) * N + col] = acc[mi][ni][r];
        }
}

// ---------------- flash attention: 4-wave blocks, 32 q-rows, balanced big-first grid ----------------
__global__ __launch_bounds__(256) void attn_kernel(const unsigned short* __restrict__ qb,
                                                   const unsigned short* __restrict__ kb,
                                                   const unsigned short* __restrict__ vT,
                                                   unsigned short* __restrict__ yb) {
    __shared__ unsigned short Klds[2][4096];
    __shared__ unsigned short Vlds[2][4096];
    __shared__ unsigned short P[4][16 * 72];
    int kvh = blockIdx.x;
    int strip = 63 - blockIdx.y;
    int tid = threadIdx.x;
    int lane = tid & 63;
    int w = tid >> 6;
    int hq = w & 1, qsub = w >> 1;
    int h = kvh * 2 + hq;
    int lr = lane & 15, lg = lane >> 4;
    int qbase = strip * 32 + qsub * 16;
    int qrow = qbase + lr;

    const int sr = tid >> 3;
    const int scol8 = (((tid & 7) ^ (sr & 7)) * 8);
    const int NT = (strip >> 1) + 1;

#define STAGEKV(buf, kt) do { \
        gload16(&kb[(size_t)((kt) * 64 + sr) * 512 + kvh * 64 + scol8], &Klds[buf][w * 512]); \
        gload16(&kb[(size_t)((kt) * 64 + sr + 32) * 512 + kvh * 64 + scol8], &Klds[buf][2048 + w * 512]); \
        gload16(&vT[(size_t)(kvh * 64 + sr) * 2048 + (kt) * 64 + scol8], &Vlds[buf][w * 512]); \
        gload16(&vT[(size_t)(kvh * 64 + sr + 32) * 2048 + (kt) * 64 + scol8], &Vlds[buf][2048 + w * 512]); \
    } while (0)

    bf16x8 bq[2];
#pragma unroll
    for (int c = 0; c < 2; ++c)
        bq[c] = *(const bf16x8*)&qb[(size_t)qrow * (NH * HD) + h * HD + c * 32 + lg * 8];

    f32x4 O[4] = {};
    float mstate = -1e30f, lstate = 0.f;

    STAGEKV(0, 0);
    WAITV(0);
    BAR();

    for (int kt = 0; kt < NT; ++kt) {
        int buf = kt & 1;
        if (kt + 1 < NT) STAGEKV(buf ^ 1, kt + 1);
        f32x4 s[4];
#pragma unroll
        for (int kc = 0; kc < 4; ++kc) {
            int krl = kc * 16 + lr;
            const unsigned short* kp = &Klds[buf][krl * 64];
            bf16x8 ak0 = *(const bf16x8*)&kp[((lg ^ (lr & 7)) * 8)];
            bf16x8 ak1 = *(const bf16x8*)&kp[(((4 + lg) ^ (lr & 7)) * 8)];
            f32x4 z = {};
            z = __builtin_amdgcn_mfma_f32_16x16x32_bf16(ak0, bq[0], z, 0, 0, 0);
            z = __builtin_amdgcn_mfma_f32_16x16x32_bf16(ak1, bq[1], z, 0, 0, 0);
            s[kc] = z;
        }
        float tm = -1e30f;
#pragma unroll
        for (int kc = 0; kc < 4; ++kc)
#pragma unroll
            for (int r = 0; r < 4; ++r) {
                int key = kt * 64 + kc * 16 + lg * 4 + r;
                float val = s[kc][r] * 0.125f;
                if (key > qrow) val = -1e30f;
                s[kc][r] = val;
                tm = fmaxf(tm, val);
            }
        tm = fmaxf(tm, __shfl_xor(tm, 16));
        tm = fmaxf(tm, __shfl_xor(tm, 32));
        float mn = fmaxf(mstate, tm);
        float sc = __expf(mstate - mn);
        float rs = 0.f;
        ushort4v pk[4];
#pragma unroll
        for (int kc = 0; kc < 4; ++kc)
#pragma unroll
            for (int r = 0; r < 4; ++r) {
                float pf = __expf(s[kc][r] - mn);
                rs += pf;
                pk[kc][r] = f2bf(pf);
            }
        rs += __shfl_xor(rs, 16);
        rs += __shfl_xor(rs, 32);
        lstate = lstate * sc + rs;
        mstate = mn;
        float osc[4];
#pragma unroll
        for (int r = 0; r < 4; ++r)
            osc[r] = __shfl(sc, lg * 4 + r);
#pragma unroll
        for (int n = 0; n < 4; ++n)
#pragma unroll
            for (int r = 0; r < 4; ++r)
                O[n][r] *= osc[r];
#pragma unroll
        for (int kc = 0; kc < 4; ++kc)
            *(ushort4v*)&P[w][lr * 72 + kc * 16 + lg * 4] = pk[kc];
        bf16x8 pa[2];
#pragma unroll
        for (int g = 0; g < 2; ++g)
            pa[g] = *(const bf16x8*)&P[w][lr * 72 + g * 32 + lg * 8];
#pragma unroll
        for (int n = 0; n < 4; ++n) {
            const unsigned short* vp = &Vlds[buf][(n * 16 + lr) * 64];
#pragma unroll
            for (int g = 0; g < 2; ++g) {
                bf16x8 bv = *(const bf16x8*)&vp[(((g * 4 + lg) ^ (lr & 7)) * 8)];
                O[n] = __builtin_amdgcn_mfma_f32_16x16x32_bf16(pa[g], bv, O[n], 0, 0, 0);
            }
        }
        if (kt + 1 < NT) WAITV(0);
        LGKM0();
        BAR();
    }
#undef STAGEKV

    float linv[4];
#pragma unroll
    for (int r = 0; r < 4; ++r)
        linv[r] = 1.f / __shfl(lstate, lg * 4 + r);
#pragma unroll
    for (int n = 0; n < 4; ++n)
#pragma unroll
        for (int r = 0; r < 4; ++r) {
            int row = qbase + lg * 4 + r;
            yb[(size_t)row * (NH * HD) + h * HD + n * 16 + lr] = f2bf(O[n][r] * linv[r]);
        }
}

extern "C" void kernel_launch(void* const* d_in, const int* in_sizes, int n_in,
                              void* d_out, int out_size, void* d_ws, size_t ws_size,
                              hipStream_t stream) {
    const int* tokens = (const int*)d_in[0];
    const float* freqs_cos = (const float*)d_in[2];
    const float* freqs_sin = (const float*)d_in[3];
    const float* tok_emb = (const float*)d_in[4];
    const float* wq = (const float*)d_in[5];
    const float* wk = (const float*)d_in[6];
    const float* wv = (const float*)d_in[7];
    const float* wo = (const float*)d_in[8];
    const float* attn_norm_w = (const float*)d_in[9];
    const float* ffn_norm_w = (const float*)d_in[10];
    const float* w1 = (const float*)d_in[11];
    const float* w2 = (const float*)d_in[12];
    const float* w3 = (const float*)d_in[13];
    const float* final_norm_w = (const float*)d_in[14];
    const float* out_w = (const float*)d_in[15];
    float* out = (float*)d_out;

    const size_t SD = (size_t)S_LEN * DIM;
    const size_t SKV = (size_t)S_LEN * NKV * HD;

    char* p = (char*)d_ws;
    auto take = [&](size_t bytes) { char* r = p; p += (bytes + 255) & ~(size_t)255; return r; };
    float* h            = (float*)take(SD * 4);
    unsigned short* xnb = (unsigned short*)take(SD * 2);
    char* uni = p;
    unsigned short* qb    = (unsigned short*)uni;                       // 4 MB
    unsigned short* kb    = qb + SD;                                    // 2 MB
    unsigned short* vT    = kb + SKV;                                   // 2 MB
    unsigned short* ybv   = vT + SKV;                                   // 4 MB
    unsigned short* gu    = ybv + SD;                                   // 11.5 MB [S][2816]
    unsigned short* wTqkv = gu + (size_t)S_LEN * HID;                   // 4 MB   [2048][1024]
    unsigned short* wTo   = wTqkv + (size_t)2048 * DIM;                 // 2 MB   [1024][1024]
    unsigned short* wT13  = wTo + (size_t)DIM * DIM;                    // 11.5 MB [5632][1024]
    unsigned short* wT2   = wT13 + (size_t)2 * HID * DIM;               // 5.75 MB [1024][2816]
    unsigned short* owT   = (unsigned short*)uni;                       // 65.5 MB (final phase overlay)

    embed_kernel<<<S_LEN, 256, 0, stream>>>(tokens, tok_emb, h);
    for (int l = 0; l < 2; ++l) {
        rmsnorm_kernel<<<S_LEN, 256, 0, stream>>>(h, attn_norm_w + l * DIM, xnb);
        transpose_layer<<<2880, 256, 0, stream>>>(
            wq + (size_t)l * DIM * 1024, wk + (size_t)l * DIM * 512, wv + (size_t)l * DIM * 512,
            wo + (size_t)l * 1024 * DIM,
            w1 + (size_t)l * DIM * HID, w3 + (size_t)l * DIM * HID, w2 + (size_t)l * HID * 1024,
            wTqkv, wTo, wT13, wT2);
        gemm_qkv<<<dim3(16, 16), 256, 0, stream>>>(xnb, wTqkv, freqs_cos, freqs_sin,
                                                   qb, kb, vT, out, l);
        attn_kernel<<<dim3(NKV, 64), 256, 0, stream>>>(qb, kb, vT, ybv);
        gemm_tn64<<<dim3(32, 8), 256, 0, stream>>>(ybv, 1024, wTo, h, h, DIM, 1024);
        rmsnorm_kernel<<<S_LEN, 256, 0, stream>>>(h, ffn_norm_w + l * DIM, xnb);
        gemm_tn128<1><<<dim3(16, 44), 256, 0, stream>>>(xnb, DIM, wT13, nullptr, gu, nullptr, 5632, DIM);
        gemm_tn64<<<dim3(32, 8), 256, 0, stream>>>(gu, HID, wT2, h, h, DIM, HID);
    }
    rmsnorm_kernel<<<S_LEN, 256, 0, stream>>>(h, final_norm_w, xnb);
    transpose_w<<<dim3(500, 16), 256, 0, stream>>>(out_w, owT, DIM, 32000);
    gemm8k32<<<dim3(8, 125), 512, 0, stream>>>(xnb, owT, out, 32000, DIM);
}

// Round 13
// 608.591 us; speedup vs baseline: 1.5736x; 1.0372x over previous
//
#include <hip/hip_runtime.h>
#include <hip/hip_bf16.h>

typedef __bf16 bf16x8 __attribute__((ext_vector_type(8)));
typedef float f32x4 __attribute__((ext_vector_type(4)));
typedef unsigned short ushort4v __attribute__((ext_vector_type(4)));
typedef unsigned short ushort8v __attribute__((ext_vector_type(8)));

#define S_LEN 2048
#define DIM 1024
#define NH 16
#define NKV 8
#define HD 64
#define HID 2816
#define LOGITS ((size_t)S_LEN * 32000)

__device__ __forceinline__ unsigned short f2bf(float f) {
    union { float f; unsigned u; } v; v.f = f;
    unsigned r = v.u + 0x7fffu + ((v.u >> 16) & 1u);   // RNE
    return (unsigned short)(r >> 16);
}
__device__ __forceinline__ float bf2f(unsigned short u) {
    union { unsigned u; float f; } v; v.u = (unsigned)u << 16; return v.f;
}

__device__ __forceinline__ void gload16(const unsigned short* g, unsigned short* l) {
    __builtin_amdgcn_global_load_lds(
        (const __attribute__((address_space(1))) unsigned int*)g,
        (__attribute__((address_space(3))) unsigned int*)l,
        16, 0, 0);
}

union Frag { f32x4 f; bf16x8 h; };

__device__ __forceinline__ f32x4 lds_read_b128(unsigned addr) {
    f32x4 d;
    asm volatile("ds_read_b128 %0, %1" : "=v"(d) : "v"(addr));
    return d;
}

#define BAR()  asm volatile("s_barrier" ::: "memory")
#define WAITV(n) asm volatile("s_waitcnt vmcnt(" #n ")" ::: "memory")
#define LGKM0() do { asm volatile("s_waitcnt lgkmcnt(0)" ::: "memory"); __builtin_amdgcn_sched_barrier(0); } while (0)

// ---------------- embedding gather ----------------
__global__ __launch_bounds__(256) void embed_kernel(const int* __restrict__ tokens,
                                                    const float* __restrict__ emb,
                                                    float* __restrict__ h) {
    int s = blockIdx.x;
    int t = tokens[s];
    float4 v = *(const float4*)&emb[(size_t)t * DIM + threadIdx.x * 4];
    *(float4*)&h[(size_t)s * DIM + threadIdx.x * 4] = v;
}

// ---------------- rmsnorm body: f32 in -> bf16 out (one block per row) ----------------
__device__ __forceinline__ void rmsnorm_body(const float* __restrict__ x,
                                             const float* __restrict__ w,
                                             unsigned short* __restrict__ out, int s) {
    __shared__ float sred[4];
    int tid = threadIdx.x;
    float4 v = *(const float4*)&x[(size_t)s * DIM + tid * 4];
    float ss = v.x * v.x + v.y * v.y + v.z * v.z + v.w * v.w;
#pragma unroll
    for (int off = 32; off; off >>= 1) ss += __shfl_down(ss, off);
    if ((tid & 63) == 0) sred[tid >> 6] = ss;
    __syncthreads();
    float tot = sred[0] + sred[1] + sred[2] + sred[3];
    float scale = rsqrtf(tot * (1.0f / DIM) + 1e-5f);
    float4 wv = *(const float4*)&w[tid * 4];
    ushort4v o;
    o[0] = f2bf(v.x * scale * wv.x); o[1] = f2bf(v.y * scale * wv.y);
    o[2] = f2bf(v.z * scale * wv.z); o[3] = f2bf(v.w * scale * wv.w);
    *(ushort4v*)&out[(size_t)s * DIM + tid * 4] = o;
}

__global__ __launch_bounds__(256) void rmsnorm_kernel(const float* __restrict__ x,
                                                      const float* __restrict__ w,
                                                      unsigned short* __restrict__ out) {
    rmsnorm_body(x, w, out, blockIdx.x);
}

// ---------------- transpose body: f32 [K][N] tile -> bf16 [rowMul*n+rowOff][K] ----------------
__device__ __forceinline__ void tpose_body(const float* __restrict__ in,
                                           unsigned short* __restrict__ out,
                                           int K, int N, int n0, int k0,
                                           int rowMul, int rowOff) {
    __shared__ unsigned short t[64][68];
    int tid = threadIdx.x;
    int tn = tid & 15, tk = tid >> 4;
#pragma unroll
    for (int p = 0; p < 4; ++p) {
        int k = tk + p * 16;
        float4 v = *(const float4*)&in[(size_t)(k0 + k) * N + n0 + tn * 4];
        t[tn * 4 + 0][k] = f2bf(v.x);
        t[tn * 4 + 1][k] = f2bf(v.y);
        t[tn * 4 + 2][k] = f2bf(v.z);
        t[tn * 4 + 3][k] = f2bf(v.w);
    }
    __syncthreads();
    int wk = tid & 15, wn = tid >> 4;
#pragma unroll
    for (int p = 0; p < 4; ++p) {
        int n = wn + p * 16;
        ushort4v v;
        v[0] = t[n][wk * 4]; v[1] = t[n][wk * 4 + 1];
        v[2] = t[n][wk * 4 + 2]; v[3] = t[n][wk * 4 + 3];
        *(ushort4v*)&out[(size_t)(rowMul * (n0 + n) + rowOff) * K + k0 + wk * 4] = v;
    }
}

// mega layer-transpose body: 2880 tiles covering wq/wk/wv/wo/w1/w3/w2 of one layer
__device__ __forceinline__ void tposeL_body(int id,
                                            const float* wq, const float* wk, const float* wv,
                                            const float* wo, const float* w1, const float* w3,
                                            const float* w2,
                                            unsigned short* wTqkv, unsigned short* wTo,
                                            unsigned short* wT13, unsigned short* wT2) {
    if (id < 256) {
        tpose_body(wq, wTqkv, 1024, 1024, (id & 15) * 64, (id >> 4) * 64, 1, 0);
    } else if (id < 384) {
        int i = id - 256;
        tpose_body(wk, wTqkv, 1024, 512, (i & 7) * 64, (i >> 3) * 64, 1, 1024);
    } else if (id < 512) {
        int i = id - 384;
        tpose_body(wv, wTqkv, 1024, 512, (i & 7) * 64, (i >> 3) * 64, 1, 1536);
    } else if (id < 768) {
        int i = id - 512;
        tpose_body(wo, wTo, 1024, 1024, (i & 15) * 64, (i >> 4) * 64, 1, 0);
    } else if (id < 1472) {
        int i = id - 768;
        tpose_body(w1, wT13, 1024, HID, (i % 44) * 64, (i / 44) * 64, 2, 0);
    } else if (id < 2176) {
        int i = id - 1472;
        tpose_body(w3, wT13, 1024, HID, (i % 44) * 64, (i / 44) * 64, 2, 1);
    } else {
        int i = id - 2176;
        tpose_body(w2, wT2, 2816, 1024, (i & 15) * 64, (i >> 4) * 64, 1, 0);
    }
}

// ---------------- merged: rmsnorm (2048) + layer transpose (2880) ----------------
__global__ __launch_bounds__(256) void rms_tposeL(const float* __restrict__ x,
                                                  const float* __restrict__ nw,
                                                  unsigned short* __restrict__ xnb,
                                                  const float* wq, const float* wk, const float* wv,
                                                  const float* wo, const float* w1, const float* w3,
                                                  const float* w2,
                                                  unsigned short* wTqkv, unsigned short* wTo,
                                                  unsigned short* wT13, unsigned short* wT2) {
    int id = blockIdx.x;
    if (id < 2048) rmsnorm_body(x, nw, xnb, id);
    else tposeL_body(id - 2048, wq, wk, wv, wo, w1, w3, w2, wTqkv, wTo, wT13, wT2);
}

// ---------------- merged: rmsnorm final (2048) + out_w transpose (8000) ----------------
__global__ __launch_bounds__(256) void rms_tposeO(const float* __restrict__ x,
                                                  const float* __restrict__ nw,
                                                  unsigned short* __restrict__ xnb,
                                                  const float* __restrict__ out_w,
                                                  unsigned short* __restrict__ owT) {
    int id = blockIdx.x;
    if (id < 2048) { rmsnorm_body(x, nw, xnb, id); return; }
    int i = id - 2048;
    tpose_body(out_w, owT, 1024, 32000, (i % 500) * 64, (i / 500) * 64, 1, 0);
}

// ---------------- attention body: 4 waves, 32 q-rows, flat id (big-first) ----------------
__device__ __forceinline__ void attn_body(int id,
                                          const unsigned short* __restrict__ qb,
                                          const unsigned short* __restrict__ kb,
                                          const unsigned short* __restrict__ vT,
                                          unsigned short* __restrict__ yb) {
    __shared__ unsigned short Klds[2][4096];
    __shared__ unsigned short Vlds[2][4096];
    __shared__ unsigned short P[4][16 * 72];
    int kvh = id & 7;
    int strip = 63 - (id >> 3);
    int tid = threadIdx.x;
    int lane = tid & 63;
    int w = tid >> 6;
    int hq = w & 1, qsub = w >> 1;
    int h = kvh * 2 + hq;
    int lr = lane & 15, lg = lane >> 4;
    int qbase = strip * 32 + qsub * 16;
    int qrow = qbase + lr;

    const int sr = tid >> 3;
    const int scol8 = (((tid & 7) ^ (sr & 7)) * 8);
    const int NT = (strip >> 1) + 1;

#define STAGEKV(buf, kt) do { \
        gload16(&kb[(size_t)((kt) * 64 + sr) * 512 + kvh * 64 + scol8], &Klds[buf][w * 512]); \
        gload16(&kb[(size_t)((kt) * 64 + sr + 32) * 512 + kvh * 64 + scol8], &Klds[buf][2048 + w * 512]); \
        gload16(&vT[(size_t)(kvh * 64 + sr) * 2048 + (kt) * 64 + scol8], &Vlds[buf][w * 512]); \
        gload16(&vT[(size_t)(kvh * 64 + sr + 32) * 2048 + (kt) * 64 + scol8], &Vlds[buf][2048 + w * 512]); \
    } while (0)

    bf16x8 bq[2];
#pragma unroll
    for (int c = 0; c < 2; ++c)
        bq[c] = *(const bf16x8*)&qb[(size_t)qrow * (NH * HD) + h * HD + c * 32 + lg * 8];

    f32x4 O[4] = {};
    float mstate = -1e30f, lstate = 0.f;

    STAGEKV(0, 0);
    WAITV(0);
    BAR();

    for (int kt = 0; kt < NT; ++kt) {
        int buf = kt & 1;
        if (kt + 1 < NT) STAGEKV(buf ^ 1, kt + 1);
        f32x4 s[4];
#pragma unroll
        for (int kc = 0; kc < 4; ++kc) {
            int krl = kc * 16 + lr;
            const unsigned short* kp = &Klds[buf][krl * 64];
            bf16x8 ak0 = *(const bf16x8*)&kp[((lg ^ (lr & 7)) * 8)];
            bf16x8 ak1 = *(const bf16x8*)&kp[(((4 + lg) ^ (lr & 7)) * 8)];
            f32x4 z = {};
            z = __builtin_amdgcn_mfma_f32_16x16x32_bf16(ak0, bq[0], z, 0, 0, 0);
            z = __builtin_amdgcn_mfma_f32_16x16x32_bf16(ak1, bq[1], z, 0, 0, 0);
            s[kc] = z;
        }
        float tm = -1e30f;
#pragma unroll
        for (int kc = 0; kc < 4; ++kc)
#pragma unroll
            for (int r = 0; r < 4; ++r) {
                int key = kt * 64 + kc * 16 + lg * 4 + r;
                float val = s[kc][r] * 0.125f;
                if (key > qrow) val = -1e30f;
                s[kc][r] = val;
                tm = fmaxf(tm, val);
            }
        tm = fmaxf(tm, __shfl_xor(tm, 16));
        tm = fmaxf(tm, __shfl_xor(tm, 32));
        float mn = fmaxf(mstate, tm);
        float sc = __expf(mstate - mn);
        float rs = 0.f;
        ushort4v pk[4];
#pragma unroll
        for (int kc = 0; kc < 4; ++kc)
#pragma unroll
            for (int r = 0; r < 4; ++r) {
                float pf = __expf(s[kc][r] - mn);
                rs += pf;
                pk[kc][r] = f2bf(pf);
            }
        rs += __shfl_xor(rs, 16);
        rs += __shfl_xor(rs, 32);
        lstate = lstate * sc + rs;
        mstate = mn;
        float osc[4];
#pragma unroll
        for (int r = 0; r < 4; ++r)
            osc[r] = __shfl(sc, lg * 4 + r);
#pragma unroll
        for (int n = 0; n < 4; ++n)
#pragma unroll
            for (int r = 0; r < 4; ++r)
                O[n][r] *= osc[r];
#pragma unroll
        for (int kc = 0; kc < 4; ++kc)
            *(ushort4v*)&P[w][lr * 72 + kc * 16 + lg * 4] = pk[kc];
        bf16x8 pa[2];
#pragma unroll
        for (int g = 0; g < 2; ++g)
            pa[g] = *(const bf16x8*)&P[w][lr * 72 + g * 32 + lg * 8];
#pragma unroll
        for (int n = 0; n < 4; ++n) {
            const unsigned short* vp = &Vlds[buf][(n * 16 + lr) * 64];
#pragma unroll
            for (int g = 0; g < 2; ++g) {
                bf16x8 bv = *(const bf16x8*)&vp[(((g * 4 + lg) ^ (lr & 7)) * 8)];
                O[n] = __builtin_amdgcn_mfma_f32_16x16x32_bf16(pa[g], bv, O[n], 0, 0, 0);
            }
        }
        if (kt + 1 < NT) WAITV(0);
        LGKM0();
        BAR();
    }
#undef STAGEKV

    float linv[4];
#pragma unroll
    for (int r = 0; r < 4; ++r)
        linv[r] = 1.f / __shfl(lstate, lg * 4 + r);
#pragma unroll
    for (int n = 0; n < 4; ++n)
#pragma unroll
        for (int r = 0; r < 4; ++r) {
            int row = qbase + lg * 4 + r;
            yb[(size_t)row * (NH * HD) + h * HD + n * 16 + lr] = f2bf(O[n][r] * linv[r]);
        }
}

// ---------------- merged: attention (512) + next-layer transpose (0 or 2880) ----------------
__global__ __launch_bounds__(256) void attn_tposeL(const unsigned short* __restrict__ qb,
                                                   const unsigned short* __restrict__ kb,
                                                   const unsigned short* __restrict__ vT,
                                                   unsigned short* __restrict__ yb,
                                                   const float* wq, const float* wk, const float* wv,
                                                   const float* wo, const float* w1, const float* w3,
                                                   const float* w2,
                                                   unsigned short* wTqkv, unsigned short* wTo,
                                                   unsigned short* wT13, unsigned short* wT2) {
    int id = blockIdx.x;
    if (id < 512) attn_body(id, qb, kb, vT, yb);
    else tposeL_body(id - 512, wq, wk, wv, wo, w1, w3, w2, wTqkv, wTo, wT13, wT2);
}

// ---------------- qkv GEMM 128^2 double-buffered + fused RoPE/V-transpose/news epilogue ----------------
__global__ __launch_bounds__(256) void gemm_qkv(const unsigned short* __restrict__ A,
                                                const unsigned short* __restrict__ Bt,
                                                const float* __restrict__ fc,
                                                const float* __restrict__ fs,
                                                unsigned short* __restrict__ qb,
                                                unsigned short* __restrict__ kb,
                                                unsigned short* __restrict__ vT,
                                                float* __restrict__ out, int layer) {
    __shared__ unsigned short As[2][128 * 64];
    __shared__ unsigned short Bs[2][128 * 64];
    const int K = DIM, lda = DIM;
    int tid = threadIdx.x;
    int lane = tid & 63;
    int wid = tid >> 6;
    int wrow = wid >> 1, wcol = wid & 1;
    int lr = lane & 15, lg = lane >> 4;
    const int m0 = blockIdx.x * 128, n0 = blockIdx.y * 128;

    const int col8 = (((lane & 7) ^ ((lane >> 3) & 7)) * 8);
    const unsigned short* aG = A + (size_t)(m0 + wid * 32 + (lane >> 3)) * lda + col8;
    const unsigned short* bG = Bt + (size_t)(n0 + wid * 32 + (lane >> 3)) * K + col8;
    const int NT = K >> 6;

#define STG128(buf, k0) do {                                                  \
        unsigned short* _aL = &As[buf][wid * 2048];                           \
        unsigned short* _bL = &Bs[buf][wid * 2048];                           \
        _Pragma("unroll")                                                     \
        for (int _i = 0; _i < 4; ++_i) {                                      \
            gload16(aG + (size_t)(_i * 8) * lda + (k0), _aL + _i * 512);      \
            gload16(bG + (size_t)(_i * 8) * K + (k0), _bL + _i * 512);        \
        }                                                                     \
    } while (0)

    f32x4 acc[4][4] = {};
    STG128(0, 0);
    WAITV(0);
    BAR();

    for (int t = 0; t < NT; ++t) {
        int buf = t & 1;
        if (t + 1 < NT) STG128(buf ^ 1, (t + 1) * 64);
#pragma unroll
        for (int kk = 0; kk < 2; ++kk) {
            const int slot = ((kk * 4 + lg) ^ (lr & 7)) * 8;
            bf16x8 aF[4], bF[4];
#pragma unroll
            for (int mi = 0; mi < 4; ++mi)
                aF[mi] = *(const bf16x8*)&As[buf][(wrow * 64 + mi * 16 + lr) * 64 + slot];
#pragma unroll
            for (int ni = 0; ni < 4; ++ni)
                bF[ni] = *(const bf16x8*)&Bs[buf][(wcol * 64 + ni * 16 + lr) * 64 + slot];
#pragma unroll
            for (int mi = 0; mi < 4; ++mi)
#pragma unroll
                for (int ni = 0; ni < 4; ++ni)
                    acc[mi][ni] = __builtin_amdgcn_mfma_f32_16x16x32_bf16(aF[mi], bF[ni], acc[mi][ni], 0, 0, 0);
        }
        if (t + 1 < NT) WAITV(0);
        BAR();
    }
#undef STG128

#pragma unroll
    for (int mi = 0; mi < 4; ++mi)
#pragma unroll
        for (int ni = 0; ni < 4; ++ni) {
            int col = n0 + wcol * 64 + ni * 16 + lr;
            int s0r = m0 + wrow * 64 + mi * 16 + lg * 4;
            if (col < 1536) {
                int p = (col & 63) >> 1;
                int odd = col & 1;
#pragma unroll
                for (int r = 0; r < 4; ++r) {
                    float v = acc[mi][ni][r];
                    float o = __shfl_xor(v, 1);
                    int s = s0r + r;
                    float c = fc[s * 32 + p], sn = fs[s * 32 + p];
                    float res = odd ? (o * sn + v * c) : (v * c - o * sn);
                    int dpos = (odd ? 32 : 0) + p;
                    if (col < 1024) {
                        qb[(size_t)s * 1024 + (col >> 6) * 64 + dpos] = f2bf(res);
                    } else {
                        int kcol = ((col >> 6) - 16) * 64 + dpos;
                        kb[(size_t)s * 512 + kcol] = f2bf(res);
                        if (s == S_LEN - 1)
                            out[LOGITS + (size_t)layer * 512 + kcol] = res;
                    }
                }
            } else {
                int d = col - 1536;
                ushort4v vv;
#pragma unroll
                for (int r = 0; r < 4; ++r) vv[r] = f2bf(acc[mi][ni][r]);
                *(ushort4v*)&vT[(size_t)d * 2048 + s0r] = vv;
                if (s0r + 3 == S_LEN - 1)
                    out[LOGITS + 2 * 512 + (size_t)layer * 512 + d] = acc[mi][ni][3];
            }
        }
}

// ---------------- GEMM 128^2 double-buffered; FUSE=1: silu(even)*odd -> bf16 [.][HID] ----------------
template<int FUSE>
__global__ __launch_bounds__(256) void gemm_tn128(const unsigned short* __restrict__ A, int lda,
                                                  const unsigned short* __restrict__ Bt,
                                                  float* __restrict__ Cf,
                                                  unsigned short* __restrict__ Cb,
                                                  const float* __restrict__ addsrc,
                                                  int N, int K) {
    __shared__ unsigned short As[2][128 * 64];
    __shared__ unsigned short Bs[2][128 * 64];
    int tid = threadIdx.x;
    int lane = tid & 63;
    int wid = tid >> 6;
    int wrow = wid >> 1, wcol = wid & 1;
    int lr = lane & 15, lg = lane >> 4;
    const int m0 = blockIdx.x * 128, n0 = blockIdx.y * 128;

    const int col8 = (((lane & 7) ^ ((lane >> 3) & 7)) * 8);
    const unsigned short* aG = A + (size_t)(m0 + wid * 32 + (lane >> 3)) * lda + col8;
    const unsigned short* bG = Bt + (size_t)(n0 + wid * 32 + (lane >> 3)) * K + col8;
    const int NT = K >> 6;

#define STG128(buf, k0) do {                                                  \
        unsigned short* _aL = &As[buf][wid * 2048];                           \
        unsigned short* _bL = &Bs[buf][wid * 2048];                           \
        _Pragma("unroll")                                                     \
        for (int _i = 0; _i < 4; ++_i) {                                      \
            gload16(aG + (size_t)(_i * 8) * lda + (k0), _aL + _i * 512);      \
            gload16(bG + (size_t)(_i * 8) * K + (k0), _bL + _i * 512);        \
        }                                                                     \
    } while (0)

    f32x4 acc[4][4] = {};
    STG128(0, 0);
    WAITV(0);
    BAR();

    for (int t = 0; t < NT; ++t) {
        int buf = t & 1;
        if (t + 1 < NT) STG128(buf ^ 1, (t + 1) * 64);
#pragma unroll
        for (int kk = 0; kk < 2; ++kk) {
            const int slot = ((kk * 4 + lg) ^ (lr & 7)) * 8;
            bf16x8 aF[4], bF[4];
#pragma unroll
            for (int mi = 0; mi < 4; ++mi)
                aF[mi] = *(const bf16x8*)&As[buf][(wrow * 64 + mi * 16 + lr) * 64 + slot];
#pragma unroll
            for (int ni = 0; ni < 4; ++ni)
                bF[ni] = *(const bf16x8*)&Bs[buf][(wcol * 64 + ni * 16 + lr) * 64 + slot];
#pragma unroll
            for (int mi = 0; mi < 4; ++mi)
#pragma unroll
                for (int ni = 0; ni < 4; ++ni)
                    acc[mi][ni] = __builtin_amdgcn_mfma_f32_16x16x32_bf16(aF[mi], bF[ni], acc[mi][ni], 0, 0, 0);
        }
        if (t + 1 < NT) WAITV(0);
        BAR();
    }
#undef STG128

#pragma unroll
    for (int mi = 0; mi < 4; ++mi)
#pragma unroll
        for (int ni = 0; ni < 4; ++ni) {
            int row = m0 + wrow * 64 + mi * 16 + lg * 4;
            int col = n0 + wcol * 64 + ni * 16 + lr;
#pragma unroll
            for (int r = 0; r < 4; ++r) {
                float v = acc[mi][ni][r];
                if (FUSE) {
                    float o = __shfl_xor(v, 1);
                    if (!(lr & 1))
                        Cb[(size_t)(row + r) * HID + (col >> 1)] = f2bf(v / (1.f + __expf(-v)) * o);
                } else {
                    size_t idx = (size_t)(row + r) * N + col;
                    if (addsrc) v += addsrc[idx];
                    if (Cb) Cb[idx] = f2bf(v);
                    else    Cf[idx] = v;
                }
            }
        }
}

// ---------------- GEMM BM=64, BN=128, double-buffered (N=1024 outputs: grid 32x8) ----------------
__global__ __launch_bounds__(256) void gemm_tn64(const unsigned short* __restrict__ A, int lda,
                                                 const unsigned short* __restrict__ Bt,
                                                 float* __restrict__ Cf,
                                                 const float* __restrict__ addsrc,
                                                 int N, int K) {
    __shared__ unsigned short As[2][64 * 64];
    __shared__ unsigned short Bs[2][128 * 64];
    int tid = threadIdx.x;
    int lane = tid & 63;
    int wid = tid >> 6;
    int lr = lane & 15, lg = lane >> 4;
    const int m0 = blockIdx.x * 64, n0 = blockIdx.y * 128;

    const int srow = tid >> 3;
    const int col8 = (((tid & 7) ^ ((tid >> 3) & 7)) * 8);
    const unsigned short* aG = A + (size_t)(m0 + srow) * lda + col8;
    const unsigned short* bG = Bt + (size_t)(n0 + srow) * K + col8;
    const int NT = K >> 6;

#define STG64(buf, k0) do {                                                   \
        gload16(aG + (k0), &As[buf][wid * 512]);                              \
        gload16(aG + (size_t)32 * lda + (k0), &As[buf][wid * 512 + 2048]);    \
        _Pragma("unroll")                                                     \
        for (int _i = 0; _i < 4; ++_i)                                        \
            gload16(bG + (size_t)(_i * 32) * K + (k0), &Bs[buf][wid * 512 + _i * 2048]); \
    } while (0)

    f32x4 acc[4][2] = {};
    STG64(0, 0);
    WAITV(0);
    BAR();

    for (int t = 0; t < NT; ++t) {
        int buf = t & 1;
        if (t + 1 < NT) STG64(buf ^ 1, (t + 1) * 64);
#pragma unroll
        for (int kk = 0; kk < 2; ++kk) {
            const int slot = ((kk * 4 + lg) ^ (lr & 7)) * 8;
            bf16x8 aF[4], bF[2];
#pragma unroll
            for (int mi = 0; mi < 4; ++mi)
                aF[mi] = *(const bf16x8*)&As[buf][(mi * 16 + lr) * 64 + slot];
#pragma unroll
            for (int ni = 0; ni < 2; ++ni)
                bF[ni] = *(const bf16x8*)&Bs[buf][(wid * 32 + ni * 16 + lr) * 64 + slot];
#pragma unroll
            for (int mi = 0; mi < 4; ++mi)
#pragma unroll
                for (int ni = 0; ni < 2; ++ni)
                    acc[mi][ni] = __builtin_amdgcn_mfma_f32_16x16x32_bf16(aF[mi], bF[ni], acc[mi][ni], 0, 0, 0);
        }
        if (t + 1 < NT) WAITV(0);
        BAR();
    }
#undef STG64

#pragma unroll
    for (int mi = 0; mi < 4; ++mi)
#pragma unroll
        for (int ni = 0; ni < 2; ++ni) {
            int row = m0 + mi * 16 + lg * 4;
            int col = n0 + wid * 32 + ni * 16 + lr;
#pragma unroll
            for (int r = 0; r < 4; ++r) {
                size_t idx = (size_t)(row + r) * N + col;
                float v = acc[mi][ni][r];
                if (addsrc) v += addsrc[idx];
                Cf[idx] = v;
            }
        }
}

// ---------------- GEMM 256^2 BK=32 2-phase prefetch (logits) ----------------
__global__ __launch_bounds__(512) void gemm8k32(const unsigned short* __restrict__ A,
                                                const unsigned short* __restrict__ Bt,
                                                float* __restrict__ Cf,
                                                int N, int K) {
    __shared__ unsigned short ldsbuf[32768];
    const int NT = K >> 5;
    int tid = threadIdx.x;
    int lane = tid & 63;
    int wid = tid >> 6;
    int wm = wid >> 2, wn = wid & 3;
    int lr = lane & 15, lg = lane >> 4;
    int wl = blockIdx.x * gridDim.y + blockIdx.y;
    const int m0 = (wl & 7) * 256, n0 = (wl >> 3) * 256;

    unsigned lds0 = (unsigned)(size_t)(__attribute__((address_space(3))) unsigned short*)ldsbuf;
    const unsigned xoff = (unsigned)((lg ^ ((lr >> 1) & 3)) * 16);
    const int gsw = (lane & 3) ^ ((lane >> 3) & 3);
    const int srow = wid * 16 + (lane >> 2);

#define STGA(t) do { \
        unsigned short* _l = ldsbuf + (((t) & 1) * 2 + 0) * 8192 + wid * 512; \
        const unsigned short* _g = A + (size_t)(m0 + srow) * K + (size_t)(t) * 32 + gsw * 8; \
        gload16(_g, _l); \
        gload16(_g + (size_t)128 * K, _l + 4096); \
    } while (0)
#define STGB(t) do { \
        unsigned short* _l = ldsbuf + (((t) & 1) * 2 + 1) * 8192 + wid * 512; \
        const unsigned short* _g = Bt + (size_t)(n0 + srow) * K + (size_t)(t) * 32 + gsw * 8; \
        gload16(_g, _l); \
        gload16(_g + (size_t)128 * K, _l + 4096); \
    } while (0)

    f32x4 acc[8][4] = {};

    STGA(0); STGB(0); STGB(1);
    WAITV(2);
    BAR();

    for (int t = 0; t < NT; ++t) {
        int buf = t & 1;
        unsigned aBase = lds0 + (unsigned)(buf * 32768) + (unsigned)((wm * 128 + lr) * 64) + xoff;
        unsigned bBase = lds0 + (unsigned)(buf * 32768 + 16384) + (unsigned)((wn * 64 + lr) * 64) + xoff;
        Frag aF[4], bF[4];
#pragma unroll
        for (int ni = 0; ni < 4; ++ni)
            bF[ni].f = lds_read_b128(bBase + (unsigned)(ni * 1024));
#pragma unroll
        for (int mi = 0; mi < 4; ++mi)
            aF[mi].f = lds_read_b128(aBase + (unsigned)(mi * 1024));
        if (t + 1 < NT) STGA(t + 1);
        BAR();
        LGKM0();
        __builtin_amdgcn_s_setprio(1);
#pragma unroll
        for (int mi = 0; mi < 4; ++mi)
#pragma unroll
            for (int ni = 0; ni < 4; ++ni)
                acc[mi][ni] = __builtin_amdgcn_mfma_f32_16x16x32_bf16(aF[mi].h, bF[ni].h, acc[mi][ni], 0, 0, 0);
        __builtin_amdgcn_s_setprio(0);
        BAR();
#pragma unroll
        for (int mi = 0; mi < 4; ++mi)
            aF[mi].f = lds_read_b128(aBase + (unsigned)(4096 + mi * 1024));
        if (t + 2 < NT) STGB(t + 2);
        BAR();
        LGKM0();
        __builtin_amdgcn_s_setprio(1);
#pragma unroll
        for (int mi = 0; mi < 4; ++mi)
#pragma unroll
            for (int ni = 0; ni < 4; ++ni)
                acc[4 + mi][ni] = __builtin_amdgcn_mfma_f32_16x16x32_bf16(aF[mi].h, bF[ni].h, acc[4 + mi][ni], 0, 0, 0);
        __builtin_amdgcn_s_setprio(0);
        if (t + 2 < NT)      { WAITV(2); }
        else if (t + 1 < NT) { WAITV(0); }
        BAR();
    }
#undef STGA
#undef STGB

#pragma unroll
    for (int mi = 0; mi < 8; ++mi)
#pragma unroll
        for (int ni = 0; ni < 4; ++ni) {
            int row = m0 + wm * 128 + mi * 16 + lg * 4;
            int col = n0 + wn * 64 + ni * 16 + lr;
#pragma unroll
            for (int r = 0; r < 4; ++r)
                Cf[(size_t)(row + r) * N + col] = acc[mi][ni][r];
        }
}

extern "C" void kernel_launch(void* const* d_in, const int* in_sizes, int n_in,
                              void* d_out, int out_size, void* d_ws, size_t ws_size,
                              hipStream_t stream) {
    const int* tokens = (const int*)d_in[0];
    const float* freqs_cos = (const float*)d_in[2];
    const float* freqs_sin = (const float*)d_in[3];
    const float* tok_emb = (const float*)d_in[4];
    const float* wq = (const float*)d_in[5];
    const float* wk = (const float*)d_in[6];
    const float* wv = (const float*)d_in[7];
    const float* wo = (const float*)d_in[8];
    const float* attn_norm_w = (const float*)d_in[9];
    const float* ffn_norm_w = (const float*)d_in[10];
    const float* w1 = (const float*)d_in[11];
    const float* w2 = (const float*)d_in[12];
    const float* w3 = (const float*)d_in[13];
    const float* final_norm_w = (const float*)d_in[14];
    const float* out_w = (const float*)d_in[15];
    float* out = (float*)d_out;

    const size_t SD = (size_t)S_LEN * DIM;
    const size_t SKV = (size_t)S_LEN * NKV * HD;

    char* p = (char*)d_ws;
    auto take = [&](size_t bytes) { char* r = p; p += (bytes + 255) & ~(size_t)255; return r; };
    float* h            = (float*)take(SD * 4);
    unsigned short* xnb = (unsigned short*)take(SD * 2);
    char* uni = p;
    unsigned short* qb    = (unsigned short*)uni;                       // 4 MB
    unsigned short* kb    = qb + SD;                                    // 2 MB
    unsigned short* vT    = kb + SKV;                                   // 2 MB
    unsigned short* ybv   = vT + SKV;                                   // 4 MB
    unsigned short* gu    = ybv + SD;                                   // 11.5 MB [S][2816]
    // double-buffered per-layer weight sets
    unsigned short* wTqkv0 = gu + (size_t)S_LEN * HID;                  // 4 MB
    unsigned short* wTo0   = wTqkv0 + (size_t)2048 * DIM;               // 2 MB
    unsigned short* wT13_0 = wTo0 + (size_t)DIM * DIM;                  // 11.5 MB
    unsigned short* wT2_0  = wT13_0 + (size_t)2 * HID * DIM;            // 5.75 MB
    unsigned short* wTqkv1 = wT2_0 + (size_t)DIM * HID;                 // 4 MB
    unsigned short* wTo1   = wTqkv1 + (size_t)2048 * DIM;               // 2 MB
    unsigned short* wT13_1 = wTo1 + (size_t)DIM * DIM;                  // 11.5 MB
    unsigned short* wT2_1  = wT13_1 + (size_t)2 * HID * DIM;            // 5.75 MB
    unsigned short* owT    = (unsigned short*)uni;                      // 65.5 MB (final overlay)

    embed_kernel<<<S_LEN, 256, 0, stream>>>(tokens, tok_emb, h);
    // layer 0: rmsnorm || transpose(layer-0 weights)
    rms_tposeL<<<2048 + 2880, 256, 0, stream>>>(h, attn_norm_w, xnb,
        wq, wk, wv, wo, w1, w3, w2, wTqkv0, wTo0, wT13_0, wT2_0);
    gemm_qkv<<<dim3(16, 16), 256, 0, stream>>>(xnb, wTqkv0, freqs_cos, freqs_sin, qb, kb, vT, out, 0);
    // attn(0) || transpose(layer-1 weights)
    attn_tposeL<<<512 + 2880, 256, 0, stream>>>(qb, kb, vT, ybv,
        wq + (size_t)DIM * 1024, wk + (size_t)DIM * 512, wv + (size_t)DIM * 512,
        wo + (size_t)1024 * DIM, w1 + (size_t)DIM * HID, w3 + (size_t)DIM * HID,
        w2 + (size_t)HID * 1024, wTqkv1, wTo1, wT13_1, wT2_1);
    gemm_tn64<<<dim3(32, 8), 256, 0, stream>>>(ybv, 1024, wTo0, h, h, DIM, 1024);
    rmsnorm_kernel<<<S_LEN, 256, 0, stream>>>(h, ffn_norm_w, xnb);
    gemm_tn128<1><<<dim3(16, 44), 256, 0, stream>>>(xnb, DIM, wT13_0, nullptr, gu, nullptr, 5632, DIM);
    gemm_tn64<<<dim3(32, 8), 256, 0, stream>>>(gu, HID, wT2_0, h, h, DIM, HID);
    // layer 1
    rmsnorm_kernel<<<S_LEN, 256, 0, stream>>>(h, attn_norm_w + DIM, xnb);
    gemm_qkv<<<dim3(16, 16), 256, 0, stream>>>(xnb, wTqkv1, freqs_cos, freqs_sin, qb, kb, vT, out, 1);
    attn_tposeL<<<512, 256, 0, stream>>>(qb, kb, vT, ybv,
        nullptr, nullptr, nullptr, nullptr, nullptr, nullptr, nullptr,
        nullptr, nullptr, nullptr, nullptr);
    gemm_tn64<<<dim3(32, 8), 256, 0, stream>>>(ybv, 1024, wTo1, h, h, DIM, 1024);
    rmsnorm_kernel<<<S_LEN, 256, 0, stream>>>(h, ffn_norm_w + DIM, xnb);
    gemm_tn128<1><<<dim3(16, 44), 256, 0, stream>>>(xnb, DIM, wT13_1, nullptr, gu, nullptr, 5632, DIM);
    gemm_tn64<<<dim3(32, 8), 256, 0, stream>>>(gu, HID, wT2_1, h, h, DIM, HID);
    // final: rmsnorm || out_w transpose (activations + wT sets all dead -> owT overlays uni)
    rms_tposeO<<<2048 + 8000, 256, 0, stream>>>(h, final_norm_w, xnb, out_w, owT);
    gemm8k32<<<dim3(8, 125), 512, 0, stream>>>(xnb, owT, out, 32000, DIM);
}

// Round 14
// 608.266 us; speedup vs baseline: 1.5744x; 1.0005x over previous
//
#include <hip/hip_runtime.h>
#include <hip/hip_bf16.h>

typedef __bf16 bf16x8 __attribute__((ext_vector_type(8)));
typedef float f32x4 __attribute__((ext_vector_type(4)));
typedef unsigned short ushort4v __attribute__((ext_vector_type(4)));
typedef unsigned short ushort8v __attribute__((ext_vector_type(8)));

#define S_LEN 2048
#define DIM 1024
#define NH 16
#define NKV 8
#define HD 64
#define HID 2816
#define LOGITS ((size_t)S_LEN * 32000)

__device__ __forceinline__ unsigned short f2bf(float f) {
    union { float f; unsigned u; } v; v.f = f;
    unsigned r = v.u + 0x7fffu + ((v.u >> 16) & 1u);   // RNE
    return (unsigned short)(r >> 16);
}
__device__ __forceinline__ float bf2f(unsigned short u) {
    union { unsigned u; float f; } v; v.u = (unsigned)u << 16; return v.f;
}

__device__ __forceinline__ void gload16(const unsigned short* g, unsigned short* l) {
    __builtin_amdgcn_global_load_lds(
        (const __attribute__((address_space(1))) unsigned int*)g,
        (__attribute__((address_space(3))) unsigned int*)l,
        16, 0, 0);
}

union Frag { f32x4 f; bf16x8 h; };

__device__ __forceinline__ f32x4 lds_read_b128(unsigned addr) {
    f32x4 d;
    asm volatile("ds_read_b128 %0, %1" : "=v"(d) : "v"(addr));
    return d;
}

#define BAR()  asm volatile("s_barrier" ::: "memory")
#define WAITV(n) asm volatile("s_waitcnt vmcnt(" #n ")" ::: "memory")
#define LGKM0() do { asm volatile("s_waitcnt lgkmcnt(0)" ::: "memory"); __builtin_amdgcn_sched_barrier(0); } while (0)

// ---------------- embedding gather ----------------
__global__ __launch_bounds__(256) void embed_kernel(const int* __restrict__ tokens,
                                                    const float* __restrict__ emb,
                                                    float* __restrict__ h) {
    int s = blockIdx.x;
    int t = tokens[s];
    float4 v = *(const float4*)&emb[(size_t)t * DIM + threadIdx.x * 4];
    *(float4*)&h[(size_t)s * DIM + threadIdx.x * 4] = v;
}

// ---------------- rmsnorm body: f32 in -> bf16 out (one block per row) ----------------
__device__ __forceinline__ void rmsnorm_body(const float* __restrict__ x,
                                             const float* __restrict__ w,
                                             unsigned short* __restrict__ out, int s) {
    __shared__ float sred[4];
    int tid = threadIdx.x;
    float4 v = *(const float4*)&x[(size_t)s * DIM + tid * 4];
    float ss = v.x * v.x + v.y * v.y + v.z * v.z + v.w * v.w;
#pragma unroll
    for (int off = 32; off; off >>= 1) ss += __shfl_down(ss, off);
    if ((tid & 63) == 0) sred[tid >> 6] = ss;
    __syncthreads();
    float tot = sred[0] + sred[1] + sred[2] + sred[3];
    float scale = rsqrtf(tot * (1.0f / DIM) + 1e-5f);
    float4 wv = *(const float4*)&w[tid * 4];
    ushort4v o;
    o[0] = f2bf(v.x * scale * wv.x); o[1] = f2bf(v.y * scale * wv.y);
    o[2] = f2bf(v.z * scale * wv.z); o[3] = f2bf(v.w * scale * wv.w);
    *(ushort4v*)&out[(size_t)s * DIM + tid * 4] = o;
}

__global__ __launch_bounds__(256) void rmsnorm_kernel(const float* __restrict__ x,
                                                      const float* __restrict__ w,
                                                      unsigned short* __restrict__ out) {
    rmsnorm_body(x, w, out, blockIdx.x);
}

// ---------------- transpose body: f32 [K][N] tile -> bf16 [rowMul*n+rowOff][K] ----------------
__device__ __forceinline__ void tpose_body(const float* __restrict__ in,
                                           unsigned short* __restrict__ out,
                                           int K, int N, int n0, int k0,
                                           int rowMul, int rowOff) {
    __shared__ unsigned short t[64][68];
    int tid = threadIdx.x;
    int tn = tid & 15, tk = tid >> 4;
#pragma unroll
    for (int p = 0; p < 4; ++p) {
        int k = tk + p * 16;
        float4 v = *(const float4*)&in[(size_t)(k0 + k) * N + n0 + tn * 4];
        t[tn * 4 + 0][k] = f2bf(v.x);
        t[tn * 4 + 1][k] = f2bf(v.y);
        t[tn * 4 + 2][k] = f2bf(v.z);
        t[tn * 4 + 3][k] = f2bf(v.w);
    }
    __syncthreads();
    int wk = tid & 15, wn = tid >> 4;
#pragma unroll
    for (int p = 0; p < 4; ++p) {
        int n = wn + p * 16;
        ushort4v v;
        v[0] = t[n][wk * 4]; v[1] = t[n][wk * 4 + 1];
        v[2] = t[n][wk * 4 + 2]; v[3] = t[n][wk * 4 + 3];
        *(ushort4v*)&out[(size_t)(rowMul * (n0 + n) + rowOff) * K + k0 + wk * 4] = v;
    }
}

// mega layer-transpose body: 2880 tiles covering wq/wk/wv/wo/w1/w3/w2 of one layer
__device__ __forceinline__ void tposeL_body(int id,
                                            const float* wq, const float* wk, const float* wv,
                                            const float* wo, const float* w1, const float* w3,
                                            const float* w2,
                                            unsigned short* wTqkv, unsigned short* wTo,
                                            unsigned short* wT13, unsigned short* wT2) {
    if (id < 256) {
        tpose_body(wq, wTqkv, 1024, 1024, (id & 15) * 64, (id >> 4) * 64, 1, 0);
    } else if (id < 384) {
        int i = id - 256;
        tpose_body(wk, wTqkv, 1024, 512, (i & 7) * 64, (i >> 3) * 64, 1, 1024);
    } else if (id < 512) {
        int i = id - 384;
        tpose_body(wv, wTqkv, 1024, 512, (i & 7) * 64, (i >> 3) * 64, 1, 1536);
    } else if (id < 768) {
        int i = id - 512;
        tpose_body(wo, wTo, 1024, 1024, (i & 15) * 64, (i >> 4) * 64, 1, 0);
    } else if (id < 1472) {
        int i = id - 768;
        tpose_body(w1, wT13, 1024, HID, (i % 44) * 64, (i / 44) * 64, 2, 0);
    } else if (id < 2176) {
        int i = id - 1472;
        tpose_body(w3, wT13, 1024, HID, (i % 44) * 64, (i / 44) * 64, 2, 1);
    } else {
        int i = id - 2176;
        tpose_body(w2, wT2, 2816, 1024, (i & 15) * 64, (i >> 4) * 64, 1, 0);
    }
}

// ---------------- merged: rmsnorm (2048) + layer transpose (2880) ----------------
__global__ __launch_bounds__(256) void rms_tposeL(const float* __restrict__ x,
                                                  const float* __restrict__ nw,
                                                  unsigned short* __restrict__ xnb,
                                                  const float* wq, const float* wk, const float* wv,
                                                  const float* wo, const float* w1, const float* w3,
                                                  const float* w2,
                                                  unsigned short* wTqkv, unsigned short* wTo,
                                                  unsigned short* wT13, unsigned short* wT2) {
    int id = blockIdx.x;
    if (id < 2048) rmsnorm_body(x, nw, xnb, id);
    else tposeL_body(id - 2048, wq, wk, wv, wo, w1, w3, w2, wTqkv, wTo, wT13, wT2);
}

// ---------------- merged: rmsnorm final (2048) + out_w transpose (8000) ----------------
__global__ __launch_bounds__(256) void rms_tposeO(const float* __restrict__ x,
                                                  const float* __restrict__ nw,
                                                  unsigned short* __restrict__ xnb,
                                                  const float* __restrict__ out_w,
                                                  unsigned short* __restrict__ owT) {
    int id = blockIdx.x;
    if (id < 2048) { rmsnorm_body(x, nw, xnb, id); return; }
    int i = id - 2048;
    tpose_body(out_w, owT, 1024, 32000, (i % 500) * 64, (i / 500) * 64, 1, 0);
}

// ---------------- attention body: 4 waves, 32 q-rows, flat id (big-first) ----------------
__device__ __forceinline__ void attn_body(int id,
                                          const unsigned short* __restrict__ qb,
                                          const unsigned short* __restrict__ kb,
                                          const unsigned short* __restrict__ vT,
                                          unsigned short* __restrict__ yb) {
    __shared__ unsigned short Klds[2][4096];
    __shared__ unsigned short Vlds[2][4096];
    __shared__ unsigned short P[4][16 * 72];
    int kvh = id & 7;
    int strip = 63 - (id >> 3);
    int tid = threadIdx.x;
    int lane = tid & 63;
    int w = tid >> 6;
    int hq = w & 1, qsub = w >> 1;
    int h = kvh * 2 + hq;
    int lr = lane & 15, lg = lane >> 4;
    int qbase = strip * 32 + qsub * 16;
    int qrow = qbase + lr;

    const int sr = tid >> 3;
    const int scol8 = (((tid & 7) ^ (sr & 7)) * 8);
    const int NT = (strip >> 1) + 1;

#define STAGEKV(buf, kt) do { \
        gload16(&kb[(size_t)((kt) * 64 + sr) * 512 + kvh * 64 + scol8], &Klds[buf][w * 512]); \
        gload16(&kb[(size_t)((kt) * 64 + sr + 32) * 512 + kvh * 64 + scol8], &Klds[buf][2048 + w * 512]); \
        gload16(&vT[(size_t)(kvh * 64 + sr) * 2048 + (kt) * 64 + scol8], &Vlds[buf][w * 512]); \
        gload16(&vT[(size_t)(kvh * 64 + sr + 32) * 2048 + (kt) * 64 + scol8], &Vlds[buf][2048 + w * 512]); \
    } while (0)

    bf16x8 bq[2];
#pragma unroll
    for (int c = 0; c < 2; ++c)
        bq[c] = *(const bf16x8*)&qb[(size_t)qrow * (NH * HD) + h * HD + c * 32 + lg * 8];

    f32x4 O[4] = {};
    float mstate = -1e30f, lstate = 0.f;

    STAGEKV(0, 0);
    WAITV(0);
    BAR();

    for (int kt = 0; kt < NT; ++kt) {
        int buf = kt & 1;
        if (kt + 1 < NT) STAGEKV(buf ^ 1, kt + 1);
        f32x4 s[4];
#pragma unroll
        for (int kc = 0; kc < 4; ++kc) {
            int krl = kc * 16 + lr;
            const unsigned short* kp = &Klds[buf][krl * 64];
            bf16x8 ak0 = *(const bf16x8*)&kp[((lg ^ (lr & 7)) * 8)];
            bf16x8 ak1 = *(const bf16x8*)&kp[(((4 + lg) ^ (lr & 7)) * 8)];
            f32x4 z = {};
            z = __builtin_amdgcn_mfma_f32_16x16x32_bf16(ak0, bq[0], z, 0, 0, 0);
            z = __builtin_amdgcn_mfma_f32_16x16x32_bf16(ak1, bq[1], z, 0, 0, 0);
            s[kc] = z;
        }
        float tm = -1e30f;
#pragma unroll
        for (int kc = 0; kc < 4; ++kc)
#pragma unroll
            for (int r = 0; r < 4; ++r) {
                int key = kt * 64 + kc * 16 + lg * 4 + r;
                float val = s[kc][r] * 0.125f;
                if (key > qrow) val = -1e30f;
                s[kc][r] = val;
                tm = fmaxf(tm, val);
            }
        tm = fmaxf(tm, __shfl_xor(tm, 16));
        tm = fmaxf(tm, __shfl_xor(tm, 32));
        float mn = fmaxf(mstate, tm);
        float sc = __expf(mstate - mn);
        float rs = 0.f;
        ushort4v pk[4];
#pragma unroll
        for (int kc = 0; kc < 4; ++kc)
#pragma unroll
            for (int r = 0; r < 4; ++r) {
                float pf = __expf(s[kc][r] - mn);
                rs += pf;
                pk[kc][r] = f2bf(pf);
            }
        rs += __shfl_xor(rs, 16);
        rs += __shfl_xor(rs, 32);
        lstate = lstate * sc + rs;
        mstate = mn;
        float osc[4];
#pragma unroll
        for (int r = 0; r < 4; ++r)
            osc[r] = __shfl(sc, lg * 4 + r);
#pragma unroll
        for (int n = 0; n < 4; ++n)
#pragma unroll
            for (int r = 0; r < 4; ++r)
                O[n][r] *= osc[r];
#pragma unroll
        for (int kc = 0; kc < 4; ++kc)
            *(ushort4v*)&P[w][lr * 72 + kc * 16 + lg * 4] = pk[kc];
        bf16x8 pa[2];
#pragma unroll
        for (int g = 0; g < 2; ++g)
            pa[g] = *(const bf16x8*)&P[w][lr * 72 + g * 32 + lg * 8];
#pragma unroll
        for (int n = 0; n < 4; ++n) {
            const unsigned short* vp = &Vlds[buf][(n * 16 + lr) * 64];
#pragma unroll
            for (int g = 0; g < 2; ++g) {
                bf16x8 bv = *(const bf16x8*)&vp[(((g * 4 + lg) ^ (lr & 7)) * 8)];
                O[n] = __builtin_amdgcn_mfma_f32_16x16x32_bf16(pa[g], bv, O[n], 0, 0, 0);
            }
        }
        if (kt + 1 < NT) WAITV(0);
        LGKM0();
        BAR();
    }
#undef STAGEKV

    float linv[4];
#pragma unroll
    for (int r = 0; r < 4; ++r)
        linv[r] = 1.f / __shfl(lstate, lg * 4 + r);
#pragma unroll
    for (int n = 0; n < 4; ++n)
#pragma unroll
        for (int r = 0; r < 4; ++r) {
            int row = qbase + lg * 4 + r;
            yb[(size_t)row * (NH * HD) + h * HD + n * 16 + lr] = f2bf(O[n][r] * linv[r]);
        }
}

// ---------------- merged: attention (512) + next-layer transpose (0 or 2880) ----------------
__global__ __launch_bounds__(256) void attn_tposeL(const unsigned short* __restrict__ qb,
                                                   const unsigned short* __restrict__ kb,
                                                   const unsigned short* __restrict__ vT,
                                                   unsigned short* __restrict__ yb,
                                                   const float* wq, const float* wk, const float* wv,
                                                   const float* wo, const float* w1, const float* w3,
                                                   const float* w2,
                                                   unsigned short* wTqkv, unsigned short* wTo,
                                                   unsigned short* wT13, unsigned short* wT2) {
    int id = blockIdx.x;
    if (id < 512) attn_body(id, qb, kb, vT, yb);
    else tposeL_body(id - 512, wq, wk, wv, wo, w1, w3, w2, wTqkv, wTo, wT13, wT2);
}

// ---------------- qkv GEMM 128^2 double-buffered + fused RoPE/V-transpose/news epilogue ----------------
__global__ __launch_bounds__(256) void gemm_qkv(const unsigned short* __restrict__ A,
                                                const unsigned short* __restrict__ Bt,
                                                const float* __restrict__ fc,
                                                const float* __restrict__ fs,
                                                unsigned short* __restrict__ qb,
                                                unsigned short* __restrict__ kb,
                                                unsigned short* __restrict__ vT,
                                                float* __restrict__ out, int layer) {
    __shared__ unsigned short As[2][128 * 64];
    __shared__ unsigned short Bs[2][128 * 64];
    const int K = DIM, lda = DIM;
    int tid = threadIdx.x;
    int lane = tid & 63;
    int wid = tid >> 6;
    int wrow = wid >> 1, wcol = wid & 1;
    int lr = lane & 15, lg = lane >> 4;
    const int m0 = blockIdx.x * 128, n0 = blockIdx.y * 128;

    const int col8 = (((lane & 7) ^ ((lane >> 3) & 7)) * 8);
    const unsigned short* aG = A + (size_t)(m0 + wid * 32 + (lane >> 3)) * lda + col8;
    const unsigned short* bG = Bt + (size_t)(n0 + wid * 32 + (lane >> 3)) * K + col8;
    const int NT = K >> 6;

#define STG128(buf, k0) do {                                                  \
        unsigned short* _aL = &As[buf][wid * 2048];                           \
        unsigned short* _bL = &Bs[buf][wid * 2048];                           \
        _Pragma("unroll")                                                     \
        for (int _i = 0; _i < 4; ++_i) {                                      \
            gload16(aG + (size_t)(_i * 8) * lda + (k0), _aL + _i * 512);      \
            gload16(bG + (size_t)(_i * 8) * K + (k0), _bL + _i * 512);        \
        }                                                                     \
    } while (0)

    f32x4 acc[4][4] = {};
    STG128(0, 0);
    WAITV(0);
    BAR();

    for (int t = 0; t < NT; ++t) {
        int buf = t & 1;
        if (t + 1 < NT) STG128(buf ^ 1, (t + 1) * 64);
#pragma unroll
        for (int kk = 0; kk < 2; ++kk) {
            const int slot = ((kk * 4 + lg) ^ (lr & 7)) * 8;
            bf16x8 aF[4], bF[4];
#pragma unroll
            for (int mi = 0; mi < 4; ++mi)
                aF[mi] = *(const bf16x8*)&As[buf][(wrow * 64 + mi * 16 + lr) * 64 + slot];
#pragma unroll
            for (int ni = 0; ni < 4; ++ni)
                bF[ni] = *(const bf16x8*)&Bs[buf][(wcol * 64 + ni * 16 + lr) * 64 + slot];
#pragma unroll
            for (int mi = 0; mi < 4; ++mi)
#pragma unroll
                for (int ni = 0; ni < 4; ++ni)
                    acc[mi][ni] = __builtin_amdgcn_mfma_f32_16x16x32_bf16(aF[mi], bF[ni], acc[mi][ni], 0, 0, 0);
        }
        if (t + 1 < NT) WAITV(0);
        BAR();
    }
#undef STG128

#pragma unroll
    for (int mi = 0; mi < 4; ++mi)
#pragma unroll
        for (int ni = 0; ni < 4; ++ni) {
            int col = n0 + wcol * 64 + ni * 16 + lr;
            int s0r = m0 + wrow * 64 + mi * 16 + lg * 4;
            if (col < 1536) {
                int p = (col & 63) >> 1;
                int odd = col & 1;
#pragma unroll
                for (int r = 0; r < 4; ++r) {
                    float v = acc[mi][ni][r];
                    float o = __shfl_xor(v, 1);
                    int s = s0r + r;
                    float c = fc[s * 32 + p], sn = fs[s * 32 + p];
                    float res = odd ? (o * sn + v * c) : (v * c - o * sn);
                    int dpos = (odd ? 32 : 0) + p;
                    if (col < 1024) {
                        qb[(size_t)s * 1024 + (col >> 6) * 64 + dpos] = f2bf(res);
                    } else {
                        int kcol = ((col >> 6) - 16) * 64 + dpos;
                        kb[(size_t)s * 512 + kcol] = f2bf(res);
                        if (s == S_LEN - 1)
                            out[LOGITS + (size_t)layer * 512 + kcol] = res;
                    }
                }
            } else {
                int d = col - 1536;
                ushort4v vv;
#pragma unroll
                for (int r = 0; r < 4; ++r) vv[r] = f2bf(acc[mi][ni][r]);
                *(ushort4v*)&vT[(size_t)d * 2048 + s0r] = vv;
                if (s0r + 3 == S_LEN - 1)
                    out[LOGITS + 2 * 512 + (size_t)layer * 512 + d] = acc[mi][ni][3];
            }
        }
}

// ---------------- GEMM 128^2 double-buffered; FUSE=1: silu(even)*odd -> bf16 [.][HID] ----------------
template<int FUSE>
__global__ __launch_bounds__(256) void gemm_tn128(const unsigned short* __restrict__ A, int lda,
                                                  const unsigned short* __restrict__ Bt,
                                                  float* __restrict__ Cf,
                                                  unsigned short* __restrict__ Cb,
                                                  const float* __restrict__ addsrc,
                                                  int N, int K) {
    __shared__ unsigned short As[2][128 * 64];
    __shared__ unsigned short Bs[2][128 * 64];
    int tid = threadIdx.x;
    int lane = tid & 63;
    int wid = tid >> 6;
    int wrow = wid >> 1, wcol = wid & 1;
    int lr = lane & 15, lg = lane >> 4;
    const int m0 = blockIdx.x * 128, n0 = blockIdx.y * 128;

    const int col8 = (((lane & 7) ^ ((lane >> 3) & 7)) * 8);
    const unsigned short* aG = A + (size_t)(m0 + wid * 32 + (lane >> 3)) * lda + col8;
    const unsigned short* bG = Bt + (size_t)(n0 + wid * 32 + (lane >> 3)) * K + col8;
    const int NT = K >> 6;

#define STG128(buf, k0) do {                                                  \
        unsigned short* _aL = &As[buf][wid * 2048];                           \
        unsigned short* _bL = &Bs[buf][wid * 2048];                           \
        _Pragma("unroll")                                                     \
        for (int _i = 0; _i < 4; ++_i) {                                      \
            gload16(aG + (size_t)(_i * 8) * lda + (k0), _aL + _i * 512);      \
            gload16(bG + (size_t)(_i * 8) * K + (k0), _bL + _i * 512);        \
        }                                                                     \
    } while (0)

    f32x4 acc[4][4] = {};
    STG128(0, 0);
    WAITV(0);
    BAR();

    for (int t = 0; t < NT; ++t) {
        int buf = t & 1;
        if (t + 1 < NT) STG128(buf ^ 1, (t + 1) * 64);
#pragma unroll
        for (int kk = 0; kk < 2; ++kk) {
            const int slot = ((kk * 4 + lg) ^ (lr & 7)) * 8;
            bf16x8 aF[4], bF[4];
#pragma unroll
            for (int mi = 0; mi < 4; ++mi)
                aF[mi] = *(const bf16x8*)&As[buf][(wrow * 64 + mi * 16 + lr) * 64 + slot];
#pragma unroll
            for (int ni = 0; ni < 4; ++ni)
                bF[ni] = *(const bf16x8*)&Bs[buf][(wcol * 64 + ni * 16 + lr) * 64 + slot];
#pragma unroll
            for (int mi = 0; mi < 4; ++mi)
#pragma unroll
                for (int ni = 0; ni < 4; ++ni)
                    acc[mi][ni] = __builtin_amdgcn_mfma_f32_16x16x32_bf16(aF[mi], bF[ni], acc[mi][ni], 0, 0, 0);
        }
        if (t + 1 < NT) WAITV(0);
        BAR();
    }
#undef STG128

#pragma unroll
    for (int mi = 0; mi < 4; ++mi)
#pragma unroll
        for (int ni = 0; ni < 4; ++ni) {
            int row = m0 + wrow * 64 + mi * 16 + lg * 4;
            int col = n0 + wcol * 64 + ni * 16 + lr;
#pragma unroll
            for (int r = 0; r < 4; ++r) {
                float v = acc[mi][ni][r];
                if (FUSE) {
                    float o = __shfl_xor(v, 1);
                    if (!(lr & 1))
                        Cb[(size_t)(row + r) * HID + (col >> 1)] = f2bf(v / (1.f + __expf(-v)) * o);
                } else {
                    size_t idx = (size_t)(row + r) * N + col;
                    if (addsrc) v += addsrc[idx];
                    if (Cb) Cb[idx] = f2bf(v);
                    else    Cf[idx] = v;
                }
            }
        }
}

// ---------------- GEMM BM=64, BN=128, double-buffered (N=1024 outputs: grid 32x8) ----------------
__global__ __launch_bounds__(256) void gemm_tn64(const unsigned short* __restrict__ A, int lda,
                                                 const unsigned short* __restrict__ Bt,
                                                 float* __restrict__ Cf,
                                                 const float* __restrict__ addsrc,
                                                 int N, int K) {
    __shared__ unsigned short As[2][64 * 64];
    __shared__ unsigned short Bs[2][128 * 64];
    int tid = threadIdx.x;
    int lane = tid & 63;
    int wid = tid >> 6;
    int lr = lane & 15, lg = lane >> 4;
    const int m0 = blockIdx.x * 64, n0 = blockIdx.y * 128;

    const int srow = tid >> 3;
    const int col8 = (((tid & 7) ^ ((tid >> 3) & 7)) * 8);
    const unsigned short* aG = A + (size_t)(m0 + srow) * lda + col8;
    const unsigned short* bG = Bt + (size_t)(n0 + srow) * K + col8;
    const int NT = K >> 6;

#define STG64(buf, k0) do {                                                   \
        gload16(aG + (k0), &As[buf][wid * 512]);                              \
        gload16(aG + (size_t)32 * lda + (k0), &As[buf][wid * 512 + 2048]);    \
        _Pragma("unroll")                                                     \
        for (int _i = 0; _i < 4; ++_i)                                        \
            gload16(bG + (size_t)(_i * 32) * K + (k0), &Bs[buf][wid * 512 + _i * 2048]); \
    } while (0)

    f32x4 acc[4][2] = {};
    STG64(0, 0);
    WAITV(0);
    BAR();

    for (int t = 0; t < NT; ++t) {
        int buf = t & 1;
        if (t + 1 < NT) STG64(buf ^ 1, (t + 1) * 64);
#pragma unroll
        for (int kk = 0; kk < 2; ++kk) {
            const int slot = ((kk * 4 + lg) ^ (lr & 7)) * 8;
            bf16x8 aF[4], bF[2];
#pragma unroll
            for (int mi = 0; mi < 4; ++mi)
                aF[mi] = *(const bf16x8*)&As[buf][(mi * 16 + lr) * 64 + slot];
#pragma unroll
            for (int ni = 0; ni < 2; ++ni)
                bF[ni] = *(const bf16x8*)&Bs[buf][(wid * 32 + ni * 16 + lr) * 64 + slot];
#pragma unroll
            for (int mi = 0; mi < 4; ++mi)
#pragma unroll
                for (int ni = 0; ni < 2; ++ni)
                    acc[mi][ni] = __builtin_amdgcn_mfma_f32_16x16x32_bf16(aF[mi], bF[ni], acc[mi][ni], 0, 0, 0);
        }
        if (t + 1 < NT) WAITV(0);
        BAR();
    }
#undef STG64

#pragma unroll
    for (int mi = 0; mi < 4; ++mi)
#pragma unroll
        for (int ni = 0; ni < 2; ++ni) {
            int row = m0 + mi * 16 + lg * 4;
            int col = n0 + wid * 32 + ni * 16 + lr;
#pragma unroll
            for (int r = 0; r < 4; ++r) {
                size_t idx = (size_t)(row + r) * N + col;
                float v = acc[mi][ni][r];
                if (addsrc) v += addsrc[idx];
                Cf[idx] = v;
            }
        }
}

// ---------------- GEMM 256^2 BK=32 2-phase prefetch (logits) ----------------
__global__ __launch_bounds__(512) void gemm8k32(const unsigned short* __restrict__ A,
                                                const unsigned short* __restrict__ Bt,
                                                float* __restrict__ Cf,
                                                int N, int K) {
    __shared__ unsigned short ldsbuf[32768];
    const int NT = K >> 5;
    int tid = threadIdx.x;
    int lane = tid & 63;
    int wid = tid >> 6;
    int wm = wid >> 2, wn = wid & 3;
    int lr = lane & 15, lg = lane >> 4;
    int wl = blockIdx.x * gridDim.y + blockIdx.y;
    const int m0 = (wl & 7) * 256, n0 = (wl >> 3) * 256;

    unsigned lds0 = (unsigned)(size_t)(__attribute__((address_space(3))) unsigned short*)ldsbuf;
    const unsigned xoff = (unsigned)((lg ^ ((lr >> 1) & 3)) * 16);
    const int gsw = (lane & 3) ^ ((lane >> 3) & 3);
    const int srow = wid * 16 + (lane >> 2);

#define STGA(t) do { \
        unsigned short* _l = ldsbuf + (((t) & 1) * 2 + 0) * 8192 + wid * 512; \
        const unsigned short* _g = A + (size_t)(m0 + srow) * K + (size_t)(t) * 32 + gsw * 8; \
        gload16(_g, _l); \
        gload16(_g + (size_t)128 * K, _l + 4096); \
    } while (0)
#define STGB(t) do { \
        unsigned short* _l = ldsbuf + (((t) & 1) * 2 + 1) * 8192 + wid * 512; \
        const unsigned short* _g = Bt + (size_t)(n0 + srow) * K + (size_t)(t) * 32 + gsw * 8; \
        gload16(_g, _l); \
        gload16(_g + (size_t)128 * K, _l + 4096); \
    } while (0)

    f32x4 acc[8][4] = {};

    STGA(0); STGB(0); STGB(1);
    WAITV(2);
    BAR();

    for (int t = 0; t < NT; ++t) {
        int buf = t & 1;
        unsigned aBase = lds0 + (unsigned)(buf * 32768) + (unsigned)((wm * 128 + lr) * 64) + xoff;
        unsigned bBase = lds0 + (unsigned)(buf * 32768 + 16384) + (unsigned)((wn * 64 + lr) * 64) + xoff;
        Frag aF[4], bF[4];
#pragma unroll
        for (int ni = 0; ni < 4; ++ni)
            bF[ni].f = lds_read_b128(bBase + (unsigned)(ni * 1024));
#pragma unroll
        for (int mi = 0; mi < 4; ++mi)
            aF[mi].f = lds_read_b128(aBase + (unsigned)(mi * 1024));
        if (t + 1 < NT) STGA(t + 1);
        BAR();
        LGKM0();
        __builtin_amdgcn_s_setprio(1);
#pragma unroll
        for (int mi = 0; mi < 4; ++mi)
#pragma unroll
            for (int ni = 0; ni < 4; ++ni)
                acc[mi][ni] = __builtin_amdgcn_mfma_f32_16x16x32_bf16(aF[mi].h, bF[ni].h, acc[mi][ni], 0, 0, 0);
        __builtin_amdgcn_s_setprio(0);
        BAR();
#pragma unroll
        for (int mi = 0; mi < 4; ++mi)
            aF[mi].f = lds_read_b128(aBase + (unsigned)(4096 + mi * 1024));
        if (t + 2 < NT) STGB(t + 2);
        BAR();
        LGKM0();
        __builtin_amdgcn_s_setprio(1);
#pragma unroll
        for (int mi = 0; mi < 4; ++mi)
#pragma unroll
            for (int ni = 0; ni < 4; ++ni)
                acc[4 + mi][ni] = __builtin_amdgcn_mfma_f32_16x16x32_bf16(aF[mi].h, bF[ni].h, acc[4 + mi][ni], 0, 0, 0);
        __builtin_amdgcn_s_setprio(0);
        if (t + 2 < NT)      { WAITV(2); }
        else if (t + 1 < NT) { WAITV(0); }
        BAR();
    }
#undef STGA
#undef STGB

#pragma unroll
    for (int mi = 0; mi < 8; ++mi)
#pragma unroll
        for (int ni = 0; ni < 4; ++ni) {
            int row = m0 + wm * 128 + mi * 16 + lg * 4;
            int col = n0 + wn * 64 + ni * 16 + lr;
#pragma unroll
            for (int r = 0; r < 4; ++r)
                Cf[(size_t)(row + r) * N + col] = acc[mi][ni][r];
        }
}

extern "C" void kernel_launch(void* const* d_in, const int* in_sizes, int n_in,
                              void* d_out, int out_size, void* d_ws, size_t ws_size,
                              hipStream_t stream) {
    const int* tokens = (const int*)d_in[0];
    const float* freqs_cos = (const float*)d_in[2];
    const float* freqs_sin = (const float*)d_in[3];
    const float* tok_emb = (const float*)d_in[4];
    const float* wq = (const float*)d_in[5];
    const float* wk = (const float*)d_in[6];
    const float* wv = (const float*)d_in[7];
    const float* wo = (const float*)d_in[8];
    const float* attn_norm_w = (const float*)d_in[9];
    const float* ffn_norm_w = (const float*)d_in[10];
    const float* w1 = (const float*)d_in[11];
    const float* w2 = (const float*)d_in[12];
    const float* w3 = (const float*)d_in[13];
    const float* final_norm_w = (const float*)d_in[14];
    const float* out_w = (const float*)d_in[15];
    float* out = (float*)d_out;

    const size_t SD = (size_t)S_LEN * DIM;
    const size_t SKV = (size_t)S_LEN * NKV * HD;

    char* p = (char*)d_ws;
    auto take = [&](size_t bytes) { char* r = p; p += (bytes + 255) & ~(size_t)255; return r; };
    float* h            = (float*)take(SD * 4);
    unsigned short* xnb = (unsigned short*)take(SD * 2);
    char* uni = p;
    unsigned short* qb    = (unsigned short*)uni;                       // 4 MB
    unsigned short* kb    = qb + SD;                                    // 2 MB
    unsigned short* vT    = kb + SKV;                                   // 2 MB
    unsigned short* ybv   = vT + SKV;                                   // 4 MB
    unsigned short* gu    = ybv + SD;                                   // 11.5 MB [S][2816]
    // double-buffered per-layer weight sets
    unsigned short* wTqkv0 = gu + (size_t)S_LEN * HID;                  // 4 MB
    unsigned short* wTo0   = wTqkv0 + (size_t)2048 * DIM;               // 2 MB
    unsigned short* wT13_0 = wTo0 + (size_t)DIM * DIM;                  // 11.5 MB
    unsigned short* wT2_0  = wT13_0 + (size_t)2 * HID * DIM;            // 5.75 MB
    unsigned short* wTqkv1 = wT2_0 + (size_t)DIM * HID;                 // 4 MB
    unsigned short* wTo1   = wTqkv1 + (size_t)2048 * DIM;               // 2 MB
    unsigned short* wT13_1 = wTo1 + (size_t)DIM * DIM;                  // 11.5 MB
    unsigned short* wT2_1  = wT13_1 + (size_t)2 * HID * DIM;            // 5.75 MB
    unsigned short* owT    = (unsigned short*)uni;                      // 65.5 MB (final overlay)

    embed_kernel<<<S_LEN, 256, 0, stream>>>(tokens, tok_emb, h);
    // layer 0: rmsnorm || transpose(layer-0 weights)
    rms_tposeL<<<2048 + 2880, 256, 0, stream>>>(h, attn_norm_w, xnb,
        wq, wk, wv, wo, w1, w3, w2, wTqkv0, wTo0, wT13_0, wT2_0);
    gemm_qkv<<<dim3(16, 16), 256, 0, stream>>>(xnb, wTqkv0, freqs_cos, freqs_sin, qb, kb, vT, out, 0);
    // attn(0) || transpose(layer-1 weights)
    attn_tposeL<<<512 + 2880, 256, 0, stream>>>(qb, kb, vT, ybv,
        wq + (size_t)DIM * 1024, wk + (size_t)DIM * 512, wv + (size_t)DIM * 512,
        wo + (size_t)1024 * DIM, w1 + (size_t)DIM * HID, w3 + (size_t)DIM * HID,
        w2 + (size_t)HID * 1024, wTqkv1, wTo1, wT13_1, wT2_1);
    gemm_tn64<<<dim3(32, 8), 256, 0, stream>>>(ybv, 1024, wTo0, h, h, DIM, 1024);
    rmsnorm_kernel<<<S_LEN, 256, 0, stream>>>(h, ffn_norm_w, xnb);
    gemm_tn128<1><<<dim3(16, 44), 256, 0, stream>>>(xnb, DIM, wT13_0, nullptr, gu, nullptr, 5632, DIM);
    gemm_tn64<<<dim3(32, 8), 256, 0, stream>>>(gu, HID, wT2_0, h, h, DIM, HID);
    // layer 1
    rmsnorm_kernel<<<S_LEN, 256, 0, stream>>>(h, attn_norm_w + DIM, xnb);
    gemm_qkv<<<dim3(16, 16), 256, 0, stream>>>(xnb, wTqkv1, freqs_cos, freqs_sin, qb, kb, vT, out, 1);
    attn_tposeL<<<512, 256, 0, stream>>>(qb, kb, vT, ybv,
        nullptr, nullptr, nullptr, nullptr, nullptr, nullptr, nullptr,
        nullptr, nullptr, nullptr, nullptr);
    gemm_tn64<<<dim3(32, 8), 256, 0, stream>>>(ybv, 1024, wTo1, h, h, DIM, 1024);
    rmsnorm_kernel<<<S_LEN, 256, 0, stream>>>(h, ffn_norm_w + DIM, xnb);
    gemm_tn128<1><<<dim3(16, 44), 256, 0, stream>>>(xnb, DIM, wT13_1, nullptr, gu, nullptr, 5632, DIM);
    gemm_tn64<<<dim3(32, 8), 256, 0, stream>>>(gu, HID, wT2_1, h, h, DIM, HID);
    // final: rmsnorm || out_w transpose (activations + wT sets all dead -> owT overlays uni)
    rms_tposeO<<<2048 + 8000, 256, 0, stream>>>(h, final_norm_w, xnb, out_w, owT);
    gemm8k32<<<dim3(8, 125), 512, 0, stream>>>(xnb, owT, out, 32000, DIM);
}